// Round 15
// baseline (1058.335 us; speedup 1.0000x reference)
//
#include <hip/hip_runtime.h>
#include <math.h>

#define NN 2048
#define NE 12288
#define NCO 49
#define NRr 29
#define CD 128
#define NG 16
#define NJOBS 21
#define VCH_E 6144   // edges per V chunk (permuted positions)

typedef unsigned short u16;
typedef short bhalf8 __attribute__((ext_vector_type(8)));
typedef float fvec4 __attribute__((ext_vector_type(4)));

// RESTRICT: indices k (0..48) with |m|<=2.
__constant__ int c_res[29] = {0,1,2,3,4,5,6,7,8,10,11,12,13,14,18,19,20,21,22,28,29,30,31,32,40,41,42,43,44};
__constant__ int c_rinv[49] = {0,1,2,3,4,5,6,7,8,-1,9,10,11,12,13,-1,-1,-1,14,15,16,17,18,-1,-1,-1,-1,-1,19,20,21,22,23,-1,-1,-1,-1,-1,-1,-1,24,25,26,27,28,-1,-1,-1,-1};
__device__ constexpr int d_RES[29] = {0,1,2,3,4,5,6,7,8,10,11,12,13,14,18,19,20,21,22,28,29,30,31,32,40,41,42,43,44};

__device__ __forceinline__ constexpr int deg_of(int k){
  return (k<1)?0:(k<4)?1:(k<9)?2:(k<16)?3:(k<25)?4:(k<36)?5:6;
}
__device__ __forceinline__ float siluf(float x){ return x / (1.f + expf(-x)); }
__device__ __forceinline__ u16 f2bf(float f){
  unsigned int u = __float_as_uint(f);
  unsigned int r = (u + 0x7FFFu + ((u >> 16) & 1u)) >> 16;
  return (u16)r;
}
__device__ __forceinline__ float bf2f(u16 b){
  return __uint_as_float(((unsigned int)b) << 16);
}
__device__ __forceinline__ unsigned int pk(u16 lo, u16 hi){ return (unsigned int)lo | ((unsigned int)hi << 16); }

// ---------------- CSR build (deterministic, parallel) ----------------
__global__ __launch_bounds__(1024) void k_hist4(const int* __restrict__ dst, int* __restrict__ cnt,
                                                int* __restrict__ CH){
  __shared__ int h[4*NN];
  for (int i = threadIdx.x; i < 4*NN; i += 1024) h[i] = 0;
  __syncthreads();
  const int QE = NE/4;
  for (int e = threadIdx.x; e < NE; e += 1024){
    int q = e / QE;
    atomicAdd(&h[q*NN + dst[e]], 1);
  }
  __syncthreads();
  for (int n = threadIdx.x; n < NN; n += 1024){
    int s = 0;
    #pragma unroll
    for (int q = 0; q < 4; q++){ int v = h[q*NN + n]; CH[q*NN + n] = v; s += v; }
    cnt[n] = s;
  }
}
__global__ __launch_bounds__(1024) void k_scan2(const int* __restrict__ cnt, int* __restrict__ rowptr){
  __shared__ int a[NN], b[NN];
  int t = threadIdx.x;
  for (int i = t; i < NN; i += 1024) a[i] = cnt[i];
  __syncthreads();
  int* pin = a; int* pout = b;
  for (int off = 1; off < NN; off <<= 1){
    for (int i = t; i < NN; i += 1024)
      pout[i] = pin[i] + ((i >= off) ? pin[i - off] : 0);
    __syncthreads();
    int* tmp = pin; pin = pout; pout = tmp;
  }
  for (int i = t; i < NN; i += 1024) rowptr[i + 1] = pin[i];
  if (t == 0) rowptr[0] = 0;
}
__global__ __launch_bounds__(256) void k_fillw4(const int* __restrict__ dst, const int* __restrict__ rowptr,
                                                const int* __restrict__ CH, int* __restrict__ eid){
  int q = threadIdx.x >> 6, lane = threadIdx.x & 63;
  int n = blockIdx.x;
  int base = rowptr[n];
  for (int qq = 0; qq < q; qq++) base += CH[qq*NN + n];
  const int QE = NE/4;
  for (int e0 = q*QE; e0 < (q+1)*QE; e0 += 64){
    int e = e0 + lane;
    bool m = (dst[e] == n);
    unsigned long long mask = __ballot(m);
    if (m) eid[base + __popcll(mask & ((1ull << lane) - 1ull))] = e;
    base += __popcll(mask);
  }
}
__global__ void k_gstart(const int* __restrict__ batch, int* __restrict__ gs){
  int g = threadIdx.x;
  if (g > NG) return;
  int lo = 0, hi = NN;
  while (lo < hi){ int mid = (lo + hi) >> 1; if (batch[mid] < g) lo = mid + 1; else hi = mid; }
  gs[g] = lo;
}

// ---------------- all weight casts in one launch: [K][N] f32 -> [N][K] bf16 ----------------
struct CastJobs {
  const float* src[NJOBS];
  u16* dst[NJOBS];
  int K[NJOBS], N[NJOBS];
  int start[NJOBS + 1];
  int total;
};
__global__ void k_castall(CastJobs J){
  int i = blockIdx.x*blockDim.x + threadIdx.x;
  if (i >= J.total) return;
  int j = 0;
  while (i >= J.start[j + 1]) j++;
  int local = i - J.start[j];
  int K = J.K[j], N = J.N[j];
  int n = local / K, k = local - n*K;
  J.dst[j][local] = f2bf(J.src[j][(size_t)k*N + n]);
}

// ---------------- geometry ----------------
__global__ void k_geom(const float* __restrict__ ev, float* __restrict__ Y, float* __restrict__ dv){
  int e = blockIdx.x*blockDim.x + threadIdx.x;
  if (e >= NE) return;
  float x = ev[e*3+0], y = ev[e*3+1], z = ev[e*3+2];
  float r = sqrtf(x*x + y*y + z*z);
  dv[e] = r;
  float rn = fmaxf(r, 1e-8f);
  float ux = x/rn, uy = y/rn, uz = z/rn;
  float ct = fminf(fmaxf(uz, -1.f), 1.f);
  float st = sqrtf(fminf(fmaxf(1.f - ct*ct, 1e-12f), 1.f));
  float phi = atan2f(uy, ux);
  float P[7][7];
  P[0][0] = 1.f;
  #pragma unroll
  for (int m = 1; m <= 6; m++) P[m][m] = -(2.f*m - 1.f)*st*P[m-1][m-1];
  #pragma unroll
  for (int m = 0; m <= 5; m++) P[m+1][m] = (2.f*m + 1.f)*ct*P[m][m];
  #pragma unroll
  for (int m = 0; m <= 6; m++){
    #pragma unroll
    for (int l = m+2; l <= 6; l++)
      P[l][m] = ((2.f*l - 1.f)*ct*P[l-1][m] - (float)(l+m-1)*P[l-2][m]) / (float)(l-m);
  }
  float cmv[7], smv[7];
  #pragma unroll
  for (int m = 0; m <= 6; m++){ cmv[m] = cosf((float)m*phi); smv[m] = sinf((float)m*phi); }
  const double FOURPI = 12.566370614359172;
  int k = 0;
  #pragma unroll
  for (int l = 0; l <= 6; l++){
    #pragma unroll
    for (int mm = -l; mm <= l; mm++){
      int am = mm < 0 ? -mm : mm;
      double ratio = 1.0;
      for (int i = l-am+1; i <= l+am; i++) ratio /= (double)i;
      double nrm = sqrt((2.0*l + 1.0)/FOURPI*ratio);
      float v;
      if (mm == 0)      v = (float)nrm * P[l][0];
      else if (mm > 0)  v = (float)(1.4142135623730951*nrm) * P[l][am] * cmv[am];
      else              v = (float)(1.4142135623730951*nrm) * P[l][am] * smv[am];
      Y[(size_t)e*49 + k] = v; k++;
    }
  }
}

// ------------- layer-1 of radial MLPs (windowed gaussian, exact) -------------
__global__ __launch_bounds__(128) void k_rad1(const float* __restrict__ dv, const float* __restrict__ Wm,
                                              const float* __restrict__ bias, float* __restrict__ out){
  int e = blockIdx.x;
  int j = threadIdx.x;
  float d = dv[e];
  const float STEPF = (float)(5.0/599.0);
  const double step_d = (double)STEPF;
  const float GC = (float)(-0.5/((2.0*step_d)*(2.0*step_d)));
  __shared__ float g[64];
  int bc = (int)rintf(d / STEPF);
  int b0 = bc - 32;
  if (j < 64){
    int b = b0 + j;
    float gg = 0.f;
    if (b >= 0 && b < 600){
      float off = (float)((double)b * (5.0/599.0));
      float t = d - off;
      gg = expf(GC*t*t);
    }
    g[j] = gg;
  }
  __syncthreads();
  float acc = bias ? bias[j] : 0.f;
  #pragma unroll 8
  for (int i = 0; i < 64; i++){
    int b = b0 + i;
    if (b >= 0 && b < 600) acc += g[i]*Wm[b*CD + j];
  }
  out[(size_t)e*CD + j] = siluf(acc);
}

// ---------------- MFMA bf16 GEMM with NT column-tiles per block ----------------
// AMODE: 0 = f32 A (runtime lda); 2 = bf16 A (runtime lda);
//        3 = permuted fused-message A.
// EPI:   0 store(+bias); 1 silu(+bias); 2 accumulate; 3 scatter-accum into X;
//        4 sigmoid store; 5 gate-mul (P0=SG) then bf16 store; 6 bf16 store;
//        7 alpha-scale (ALp, permuted via eidp) then bf16 store (VS).
template<int AMODE, int EPI, int NT>
__global__ __launch_bounds__(256) void k_mgemm(
    const void* __restrict__ Av, const u16* __restrict__ Bt,
    const float* __restrict__ bias, void* __restrict__ Cv,
    int M, int N, int K, int lda,
    const float* __restrict__ P0,
    const int* __restrict__ src, const int* __restrict__ dstp,
    const int* __restrict__ eidp, const float* __restrict__ ALp, int e0)
{
  __shared__ __align__(16) u16 Asl[64*64];
  __shared__ __align__(16) u16 Bsl[NT][64*64];
  int tid = threadIdx.x;
  int bm = blockIdx.y*64;
  int bn0 = blockIdx.x*NT*64;
  int wid = tid >> 6, lane = tid & 63;
  int wr = wid >> 1, wc = wid & 1;
  int lr = lane & 15, lk = lane >> 4;
  fvec4 acc[NT][2][2] = {};
  for (int k0 = 0; k0 < K; k0 += 64){
    #pragma unroll
    for (int h = 0; h < 2; h++){
      int lin = tid + h*256;          // 0..511: 64 rows x 8 k-groups
      int row = lin >> 3, kg = lin & 7;
      uint4 q;
      if (AMODE == 3){
        int gr = bm + row;
        int el = gr / 29, kq = gr - el*29;
        int p = e0 + el;
        int e = eidp[p];
        int s = src[e], t = dstp[e];
        const u16* xst = (const u16*)P0;
        uint4 xs8 = *(const uint4*)&xst[((size_t)s*29 + kq)*256 + k0 + kg*8];
        uint4 xt8 = *(const uint4*)&xst[((size_t)t*29 + kq)*256 + 128 + k0 + kg*8];
        const float* rd = (const float*)Av + (size_t)e*128 + k0 + kg*8;
        const u16* xsp = (const u16*)&xs8;
        const u16* xtp = (const u16*)&xt8;
        u16 ov[8];
        #pragma unroll
        for (int j = 0; j < 8; j++)
          ov[j] = f2bf((bf2f(xsp[j]) + bf2f(xtp[j])) * rd[j]);
        q.x = pk(ov[0], ov[1]); q.y = pk(ov[2], ov[3]);
        q.z = pk(ov[4], ov[5]); q.w = pk(ov[6], ov[7]);
      } else if (AMODE == 2){
        const u16* ap = (const u16*)Av + (size_t)(bm + row)*lda + k0 + kg*8;
        q = *(const uint4*)ap;
      } else {
        const float* ap = (const float*)Av + (size_t)(bm + row)*lda + k0 + kg*8;
        float v[8];
        #pragma unroll
        for (int j = 0; j < 8; j++) v[j] = ap[j];
        q.x = pk(f2bf(v[0]), f2bf(v[1]));
        q.y = pk(f2bf(v[2]), f2bf(v[3]));
        q.z = pk(f2bf(v[4]), f2bf(v[5]));
        q.w = pk(f2bf(v[6]), f2bf(v[7]));
      }
      *(uint4*)&Asl[row*64 + ((kg*8) ^ ((row & 7)*8))] = q;
    }
    #pragma unroll
    for (int t = 0; t < NT; t++){
      #pragma unroll
      for (int h = 0; h < 2; h++){
        int lin = tid + h*256;
        int row = lin >> 3, kg = lin & 7;
        const u16* bp = Bt + (size_t)(bn0 + t*64 + row)*K + k0 + kg*8;
        *(uint4*)&Bsl[t][row*64 + ((kg*8) ^ ((row & 7)*8))] = *(const uint4*)bp;
      }
    }
    __syncthreads();
    #pragma unroll
    for (int ks = 0; ks < 2; ks++){
      int kg = ks*4 + lk;
      bhalf8 af[2];
      #pragma unroll
      for (int mi = 0; mi < 2; mi++){
        int ar = wr*32 + mi*16 + lr;
        af[mi] = *(const bhalf8*)&Asl[ar*64 + ((kg*8) ^ ((ar & 7)*8))];
      }
      #pragma unroll
      for (int t = 0; t < NT; t++){
        bhalf8 bfr[2];
        #pragma unroll
        for (int ni = 0; ni < 2; ni++){
          int br = wc*32 + ni*16 + lr;
          bfr[ni] = *(const bhalf8*)&Bsl[t][br*64 + ((kg*8) ^ ((br & 7)*8))];
        }
        #pragma unroll
        for (int mi = 0; mi < 2; mi++)
          #pragma unroll
          for (int ni = 0; ni < 2; ni++)
            acc[t][mi][ni] = __builtin_amdgcn_mfma_f32_16x16x32_bf16(af[mi], bfr[ni], acc[t][mi][ni], 0, 0, 0);
      }
    }
    __syncthreads();
  }
  #pragma unroll
  for (int t = 0; t < NT; t++){
    #pragma unroll
    for (int mi = 0; mi < 2; mi++){
      #pragma unroll
      for (int ni = 0; ni < 2; ni++){
        #pragma unroll
        for (int j = 0; j < 4; j++){
          int row = bm + wr*32 + mi*16 + lk*4 + j;
          int col = bn0 + t*64 + wc*32 + ni*16 + lr;
          float v = acc[t][mi][ni][j];
          if (EPI == 0){
            if (bias) v += bias[col];
            ((float*)Cv)[(size_t)row*N + col] = v;
          } else if (EPI == 1){
            if (bias) v += bias[col];
            ((float*)Cv)[(size_t)row*N + col] = siluf(v);
          } else if (EPI == 2){
            ((float*)Cv)[(size_t)row*N + col] += v;
          } else if (EPI == 3){
            int n = row / 29, kr = row - n*29;
            ((float*)Cv)[((size_t)n*49 + c_res[kr])*128 + col] += v;
          } else if (EPI == 4){
            ((float*)Cv)[(size_t)row*N + col] = 1.f/(1.f + expf(-v));
          } else if (EPI == 5){
            float g = P0[(size_t)(row/49)*N + col];
            ((u16*)Cv)[(size_t)row*N + col] = f2bf(v*g);
          } else if (EPI == 6){
            ((u16*)Cv)[(size_t)row*N + col] = f2bf(v);
          } else {
            int p = e0 + row/29;
            int e = eidp[p];
            float a = ALp[e*8 + (col >> 4)];
            ((u16*)Cv)[(size_t)row*N + col] = f2bf(v*a);
          }
        }
      }
    }
  }
}

// ---------------- fused FFN: X += ((bf16(A@W1) * gate) @ W2), hidden in LDS, weights from L2 ----------------
// A: Hbw [NN*49][128] bf16. W1: [512][128] bf16 ([h][k]). W2: [128][512] bf16 ([c][h]). SG: [NN][512] f32.
// Bit-identical to the two-GEMM chain: same MFMA K-slice order, same f2bf(v*g) rounding.
__global__ __launch_bounds__(256) void k_ffn(
    const u16* __restrict__ A, const u16* __restrict__ W1, const u16* __restrict__ W2,
    const float* __restrict__ SGp, float* __restrict__ Xp)
{
  __shared__ __align__(16) u16 Asl[64*128];   // 16 KB
  __shared__ __align__(16) u16 Hs[64*64];     // 8 KB
  int tid = threadIdx.x;
  int bm = blockIdx.x*64;
  int wid = tid >> 6, lane = tid & 63;
  int wr = wid >> 1, wc = wid & 1;
  int lr = lane & 15, lk = lane >> 4;
  for (int g = tid; g < 1024; g += 256){
    int row = g >> 4, kg = g & 15;
    *(uint4*)&Asl[row*128 + ((kg*8) ^ ((row & 7)*16))] = *(const uint4*)&A[(size_t)(bm + row)*128 + kg*8];
  }
  __syncthreads();
  fvec4 o[2][4] = {};
  for (int h0 = 0; h0 < 512; h0 += 64){
    // GEMM1: 64x64 hidden tile (K=128); W1 fragments straight from L2
    fvec4 hid[2][2] = {};
    #pragma unroll
    for (int kk = 0; kk < 4; kk++){
      int kg = kk*4 + lk;
      bhalf8 af[2], bf[2];
      #pragma unroll
      for (int mi = 0; mi < 2; mi++){
        int ar = wr*32 + mi*16 + lr;
        af[mi] = *(const bhalf8*)&Asl[ar*128 + ((kg*8) ^ ((ar & 7)*16))];
      }
      #pragma unroll
      for (int ni = 0; ni < 2; ni++){
        int br = wc*32 + ni*16 + lr;
        bf[ni] = *(const bhalf8*)&W1[(size_t)(h0 + br)*128 + kg*8];
      }
      #pragma unroll
      for (int mi = 0; mi < 2; mi++)
        #pragma unroll
        for (int ni = 0; ni < 2; ni++)
          hid[mi][ni] = __builtin_amdgcn_mfma_f32_16x16x32_bf16(af[mi], bf[ni], hid[mi][ni], 0, 0, 0);
    }
    // gate + bf16 round -> Hs
    #pragma unroll
    for (int mi = 0; mi < 2; mi++){
      #pragma unroll
      for (int j = 0; j < 4; j++){
        int row = wr*32 + mi*16 + lk*4 + j;
        int node = (bm + row)/49;
        const float* sgrow = &SGp[(size_t)node*512 + h0];
        #pragma unroll
        for (int ni = 0; ni < 2; ni++){
          int col = wc*32 + ni*16 + lr;
          Hs[row*64 + (col ^ ((row & 7)*8))] = f2bf(hid[mi][ni][j]*sgrow[col]);
        }
      }
    }
    __syncthreads();
    // GEMM2: out 64x128 accumulate (K=64 this chunk); W2 fragments straight from L2
    #pragma unroll
    for (int kk2 = 0; kk2 < 2; kk2++){
      int kg = kk2*4 + lk;
      bhalf8 af2[2], bf2[4];
      #pragma unroll
      for (int mi = 0; mi < 2; mi++){
        int ar = wr*32 + mi*16 + lr;
        af2[mi] = *(const bhalf8*)&Hs[ar*64 + ((kg*8) ^ ((ar & 7)*8))];
      }
      #pragma unroll
      for (int ni = 0; ni < 4; ni++){
        int br = wc*64 + ni*16 + lr;
        bf2[ni] = *(const bhalf8*)&W2[(size_t)br*512 + h0 + kg*8];
      }
      #pragma unroll
      for (int mi = 0; mi < 2; mi++)
        #pragma unroll
        for (int ni = 0; ni < 4; ni++)
          o[mi][ni] = __builtin_amdgcn_mfma_f32_16x16x32_bf16(af2[mi], bf2[ni], o[mi][ni], 0, 0, 0);
    }
    __syncthreads();
  }
  #pragma unroll
  for (int mi = 0; mi < 2; mi++)
    #pragma unroll
    for (int ni = 0; ni < 4; ni++)
      #pragma unroll
      for (int j = 0; j < 4; j++){
        int row = bm + wr*32 + mi*16 + lk*4 + j;
        int col = wc*64 + ni*16 + lr;
        Xp[(size_t)row*128 + col] += o[mi][ni][j];
      }
}

// ---------------- contiguous segment-sum of permuted VS rows (vectorized) ----------------
__global__ __launch_bounds__(256) void k_aggseg(const u16* __restrict__ VS, const int* __restrict__ rowptr,
                                                int p0, int p1, int first, float* __restrict__ agg){
  int n = blockIdx.x;
  int a = rowptr[n], b = rowptr[n+1];
  if (a < p0) a = p0;
  if (b > p1) b = p1;
  int tid = threadIdx.x;
  for (int g = tid; g < 464; g += 256){          // 29*128/8 = 464 groups of 8
    size_t obase = (size_t)n*29*128 + (size_t)g*8;
    float s[8];
    if (first){
      #pragma unroll
      for (int j = 0; j < 8; j++) s[j] = 0.f;
    } else {
      float4 lo = *(const float4*)&agg[obase];
      float4 hi = *(const float4*)&agg[obase + 4];
      s[0]=lo.x; s[1]=lo.y; s[2]=lo.z; s[3]=lo.w;
      s[4]=hi.x; s[5]=hi.y; s[6]=hi.z; s[7]=hi.w;
    }
    for (int p = a; p < b; p++){
      uint4 q = *(const uint4*)&VS[(size_t)(p - p0)*3712 + (size_t)g*8];
      const u16* qp = (const u16*)&q;
      #pragma unroll
      for (int j = 0; j < 8; j++) s[j] += bf2f(qp[j]);
    }
    float4 lo, hi;
    lo.x=s[0]; lo.y=s[1]; lo.z=s[2]; lo.w=s[3];
    hi.x=s[4]; hi.y=s[5]; hi.z=s[6]; hi.w=s[7];
    *(float4*)&agg[obase] = lo;
    *(float4*)&agg[obase + 4] = hi;
  }
}

// ---------------- node init ----------------
__global__ __launch_bounds__(128) void k_init(const float* __restrict__ pos, const float* __restrict__ table,
                                              const float* __restrict__ Yb, const float* __restrict__ radd,
                                              const int* __restrict__ rowptr, const int* __restrict__ eid,
                                              float* __restrict__ x){
  int n = blockIdx.x;
  int c = threadIdx.x;
  const float DLO = -3.26267f;
  const float DRG = (float)(3.295396 - (-3.26267));
  float p0 = pos[n*3+0], p1 = pos[n*3+1], p2 = pos[n*3+2];
  int t0 = min(127, max(0, (int)rintf((p0 - DLO)/DRG*128.f - 0.5f)));
  int t1 = min(127, max(0, (int)rintf((p1 - DLO)/DRG*128.f - 0.5f)));
  int t2 = min(127, max(0, (int)rintf((p2 - DLO)/DRG*128.f - 0.5f)));
  float emb = table[t0*CD + c] + table[t1*CD + c] + table[t2*CD + c];
  __shared__ float Yl[49];
  __shared__ float rl[896];
  float acc[NCO];
  #pragma unroll
  for (int k = 0; k < NCO; k++) acc[k] = 0.f;
  int pA = rowptr[n], pB = rowptr[n+1];
  for (int p = pA; p < pB; p++){
    int e = eid[p];
    if (c < 49) Yl[c] = Yb[(size_t)e*49 + c];
    #pragma unroll
    for (int q = 0; q < 7; q++) rl[q*128 + c] = radd[(size_t)e*896 + q*128 + c];
    __syncthreads();
    #pragma unroll
    for (int k = 0; k < NCO; k++){
      acc[k] += Yl[k]*rl[deg_of(k)*128 + c];
    }
    __syncthreads();
  }
  size_t base = (size_t)n*NCO*CD;
  x[base + c] = emb + acc[0]*(1.f/3.f);
  #pragma unroll
  for (int k = 1; k < NCO; k++) x[base + k*CD + c] = acc[k]*(1.f/3.f);
}

// ---------------- degree-grouped RMS norm, bf16 out (full 49 rows, for FFN) ----------------
__global__ __launch_bounds__(128) void k_rmsnorm(const float* __restrict__ x, const float* __restrict__ w,
                                                 u16* __restrict__ out){
  int n = blockIdx.x;
  int c = threadIdx.x;
  const float* xb = x + (size_t)n*NCO*CD;
  float vals[NCO];
  float ss[7] = {0,0,0,0,0,0,0};
  #pragma unroll
  for (int k = 0; k < NCO; k++){
    float v = xb[k*CD + c];
    vals[k] = v;
    ss[deg_of(k)] += v*v;
  }
  __shared__ float red[7][128];
  #pragma unroll
  for (int l = 0; l < 7; l++) red[l][c] = ss[l];
  __syncthreads();
  __shared__ float inv[7];
  if (c < 7){
    float s = 0.f;
    for (int i = 0; i < 128; i++) s += red[c][i];
    float ms = s / ((float)(2*c + 1)*128.f);
    inv[c] = 1.f / sqrtf(ms + 1e-6f);
  }
  __syncthreads();
  size_t base = (size_t)n*NCO*CD;
  #pragma unroll
  for (int k = 0; k < NCO; k++){
    int l = deg_of(k);
    out[base + k*CD + c] = f2bf(vals[k]*inv[l]*w[l*CD + c]);
  }
}

// ---------------- RMS norm writing restricted 29 rows, bf16 out ----------------
__global__ __launch_bounds__(128) void k_rmsnormR(const float* __restrict__ x, const float* __restrict__ w,
                                                  u16* __restrict__ hr){
  int n = blockIdx.x;
  int c = threadIdx.x;
  const float* xb = x + (size_t)n*NCO*CD;
  float vals[NCO];
  float ss[7] = {0,0,0,0,0,0,0};
  #pragma unroll
  for (int k = 0; k < NCO; k++){
    float v = xb[k*CD + c];
    vals[k] = v;
    ss[deg_of(k)] += v*v;
  }
  __shared__ float red[7][128];
  #pragma unroll
  for (int l = 0; l < 7; l++) red[l][c] = ss[l];
  __syncthreads();
  __shared__ float inv[7];
  if (c < 7){
    float s = 0.f;
    for (int i = 0; i < 128; i++) s += red[c][i];
    float ms = s / ((float)(2*c + 1)*128.f);
    inv[c] = 1.f / sqrtf(ms + 1e-6f);
  }
  __syncthreads();
  size_t base = (size_t)n*NRr*CD;
  #pragma unroll
  for (int kr = 0; kr < NRr; kr++){
    int k = d_RES[kr];
    int l = deg_of(k);
    hr[base + kr*CD + c] = f2bf(vals[k]*inv[l]*w[l*CD + c]);
  }
}

// ---------------- fused attention: logits + segment softmax + alpha ----------------
__global__ __launch_bounds__(256) void k_attn(
    const u16* __restrict__ XST, const float* __restrict__ rad, const float* __restrict__ avec,
    const int* __restrict__ src, const int* __restrict__ rowptr, const int* __restrict__ eid,
    float* __restrict__ AL)
{
  int n = blockIdx.x;
  int p0 = rowptr[n], p1 = rowptr[n+1];
  int deg = p1 - p0;
  if (deg == 0) return;
  __shared__ float lgs[64][8];
  __shared__ float xt0[128];
  __shared__ float av[128];
  __shared__ float mxs[8], dens[8];
  int tid = threadIdx.x;
  if (tid < 128){
    xt0[tid] = bf2f(XST[(size_t)n*NRr*256 + 128 + tid]);
    av[tid] = avec[tid];
  }
  __syncthreads();
  for (int pair = tid; pair < deg*8; pair += 256){
    int pl = pair >> 3, h = pair & 7;
    int e = eid[p0 + pl];
    int s = src[e];
    const u16* xs = &XST[(size_t)s*NRr*256 + h*16];
    uint4 q0 = *(const uint4*)xs;
    uint4 q1 = *(const uint4*)(xs + 8);
    const u16* x0 = (const u16*)&q0;
    const u16* x1 = (const u16*)&q1;
    const float* rd = &rad[(size_t)e*128 + h*16];
    float4 r0 = *(const float4*)(rd + 0);
    float4 r1 = *(const float4*)(rd + 4);
    float4 r2 = *(const float4*)(rd + 8);
    float4 r3 = *(const float4*)(rd + 12);
    float rr[16] = {r0.x,r0.y,r0.z,r0.w, r1.x,r1.y,r1.z,r1.w,
                    r2.x,r2.y,r2.z,r2.w, r3.x,r3.y,r3.z,r3.w};
    float acc = 0.f;
    #pragma unroll
    for (int d = 0; d < 8; d++){
      float m = (bf2f(x0[d]) + xt0[h*16 + d]) * rr[d];
      acc += siluf(m) * av[h*16 + d];
    }
    #pragma unroll
    for (int d = 0; d < 8; d++){
      float m = (bf2f(x1[d]) + xt0[h*16 + 8 + d]) * rr[8 + d];
      acc += siluf(m) * av[h*16 + 8 + d];
    }
    lgs[pl][h] = acc;
  }
  __syncthreads();
  if (tid < 8){
    float m = -1e30f;
    for (int pl = 0; pl < deg; pl++) m = fmaxf(m, lgs[pl][tid]);
    float sden = 0.f;
    for (int pl = 0; pl < deg; pl++) sden += expf(lgs[pl][tid] - m);
    mxs[tid] = m; dens[tid] = sden;
  }
  __syncthreads();
  for (int pair = tid; pair < deg*8; pair += 256){
    int pl = pair >> 3, h = pair & 7;
    int e = eid[p0 + pl];
    AL[e*8 + h] = expf(lgs[pl][h] - mxs[h]) / fmaxf(dens[h], 1e-9f);
  }
}

// ---------------- pooling ----------------
__global__ void k_pool(const float* __restrict__ orr, const int* __restrict__ gs, float* __restrict__ out){
  int i = blockIdx.x*blockDim.x + threadIdx.x;
  if (i >= NG*NCO*CD) return;
  int c = i & 127;
  int k = (i >> 7) % 49;
  int g = i / (49*128);
  int kr = c_rinv[k];
  float v = 0.f;
  if (kr >= 0){
    int a = gs[g], b = gs[g+1];
    float s = 0.f;
    for (int n = a; n < b; n++) s += orr[((size_t)n*29 + kr)*128 + c];
    int cnt = b - a;
    v = s / (float)(cnt > 0 ? cnt : 1);
  }
  out[i] = v;
}

extern "C" void kernel_launch(void* const* d_in, const int* in_sizes, int n_in,
                              void* d_out, int out_size, void* d_ws, size_t ws_size,
                              hipStream_t stream){
  const float* pos    = (const float*)d_in[0];
  const float* evec   = (const float*)d_in[1];
  const int*   eidx   = (const int*)  d_in[2];
  const int*   batch  = (const int*)  d_in[3];
  const float* table  = (const float*)d_in[4];
  const float* deg_w1 = (const float*)d_in[5];
  const float* deg_b1 = (const float*)d_in[6];
  const float* deg_w2 = (const float*)d_in[7];
  const float* deg_b2 = (const float*)d_in[8];
  const float* deg_w3 = (const float*)d_in[9];
  const float* attn_nw= (const float*)d_in[10];
  const float* w_src  = (const float*)d_in[11];
  const float* w_tgt  = (const float*)d_in[12];
  const float* rad_w1 = (const float*)d_in[13];
  const float* rad_b1 = (const float*)d_in[14];
  const float* rad_w2 = (const float*)d_in[15];
  const float* avec   = (const float*)d_in[16];
  const float* w_val  = (const float*)d_in[17];
  const float* w_proj = (const float*)d_in[18];
  const float* ffn_nw = (const float*)d_in[19];
  const float* ffn_w1 = (const float*)d_in[20];
  const float* ffn_w2 = (const float*)d_in[21];
  const float* fin_nw = (const float*)d_in[22];
  const float* lw_src = (const float*)d_in[23];
  const float* lw_tgt = (const float*)d_in[24];
  const float* lrad_w1= (const float*)d_in[25];
  const float* lrad_b1= (const float*)d_in[26];
  const float* lrad_w2= (const float*)d_in[27];
  const float* lavec  = (const float*)d_in[28];
  const float* lw_val = (const float*)d_in[29];
  const float* lw_proj= (const float*)d_in[30];

  const int* srcp = eidx;
  const int* dstp = eidx + NE;

  float* W = (float*)d_ws;
  size_t o = 0;
  float* X    = W + o; o += (size_t)NN*49*128;
  float* Hb   = W + o; o += (size_t)NN*49*128;   // RADD, VS chunks, latent proj out, FFN rmsnorm(bf16)
  float* HR   = W + o; o += (size_t)NN*29*128;   // rmsnormR(bf16) out, AG
  float* XSTf = W + o; o += (size_t)NN*29*256/2; // XST bf16 region (u16)
  float* R1   = W + o; o += (size_t)NE*128;
  float* R2   = W + o; o += (size_t)NE*128;
  float* Yb   = W + o; o += (size_t)NE*49;
  float* DV   = W + o; o += (size_t)NE;
  float* LG   = W + o; o += (size_t)NE*8;
  float* AL   = W + o; o += (size_t)NE*8;
  float* MX   = W + o; o += (size_t)NN*8;
  float* DEN  = W + o; o += (size_t)NN*8;
  float* SG   = W + o; o += (size_t)NN*512;
  int* CNT = (int*)(W + o); o += NN;
  int* RP  = (int*)(W + o); o += NN + 1;
  int* EID = (int*)(W + o); o += NE;
  int* GS  = (int*)(W + o); o += NG + 1;
  int* CH  = (int*)(W + o); o += 4*NN;
  // bf16 transposed weights
  u16* WB = (u16*)(W + o);
  size_t wo = 0;
  u16* T_degw2 = WB + wo; wo += 16384;
  u16* T_degw3 = WB + wo; wo += 114688;
  u16* T_wst[3]; u16* T_wv[3]; u16* T_wp[3]; u16* T_rw2[3];
  for (int i = 0; i < 3; i++){ T_wst[i] = WB + wo; wo += 32768; }   // [256][128]
  for (int i = 0; i < 3; i++){ T_wv[i] = WB + wo; wo += 16384; }
  for (int i = 0; i < 3; i++){ T_wp[i] = WB + wo; wo += 16384; }
  for (int i = 0; i < 3; i++){ T_rw2[i] = WB + wo; wo += 16384; }
  u16* T_f1[2]; u16* T_f2[2];
  for (int i = 0; i < 2; i++){ T_f1[i] = WB + wo; wo += 65536; }
  for (int i = 0; i < 2; i++){ T_f2[i] = WB + wo; wo += 65536; }
  (void)ws_size; (void)in_sizes; (void)n_in; (void)out_size; (void)LG; (void)MX; (void)DEN;

  u16*  XSTw = (u16*)XSTf;                        // [NN][29][256] bf16
  u16*  HRw  = (u16*)HR;                          // rmsnormR bf16 out
  u16*  Hbw  = (u16*)Hb;                          // FFN rmsnorm bf16 out (first half of Hb)
  float* RADD = Hb;                               // E*896 <= Hb; free before layers
  u16*  VS    = (u16*)Hb;                         // VCH_E*29*128 u16 <= Hb
  float* AG   = HR;
  float* OR_  = Hb;                               // latent proj out (after aggseg done)

  // ---- all weight casts in one launch ----
  {
    CastJobs J;
    int idx = 0, acc = 0;
    auto add = [&](const float* s, u16* d, int K, int N){
      J.src[idx] = s; J.dst[idx] = d; J.K[idx] = K; J.N[idx] = N; J.start[idx] = acc;
      acc += K*N; idx++;
    };
    add(deg_w2, T_degw2, 128, 128);
    add(deg_w3, T_degw3, 128, 896);
    for (int i = 0; i < 3; i++){
      add((i < 2) ? w_src  + (size_t)i*16384 : lw_src,  T_wst[i],          128, 128);
      add((i < 2) ? w_tgt  + (size_t)i*16384 : lw_tgt,  T_wst[i] + 16384,  128, 128);
      add((i < 2) ? w_val  + (size_t)i*16384 : lw_val,  T_wv[i], 128, 128);
      add((i < 2) ? w_proj + (size_t)i*16384 : lw_proj, T_wp[i], 128, 128);
      add((i < 2) ? rad_w2 + (size_t)i*16384 : lrad_w2, T_rw2[i], 128, 128);
    }
    for (int i = 0; i < 2; i++){
      add(ffn_w1 + (size_t)i*65536, T_f1[i], 128, 512);
      add(ffn_w2 + (size_t)i*65536, T_f2[i], 512, 128);
    }
    J.start[idx] = acc; J.total = acc;
    k_castall<<<(acc + 255)/256, 256, 0, stream>>>(J);
  }

  // CSR + groups
  k_hist4<<<1, 1024, 0, stream>>>(dstp, CNT, CH);
  k_scan2<<<1, 1024, 0, stream>>>(CNT, RP);
  k_fillw4<<<NN, 256, 0, stream>>>(dstp, RP, CH, EID);
  k_gstart<<<1, 32, 0, stream>>>(batch, GS);

  // geometry
  k_geom<<<48, 256, 0, stream>>>(evec, Yb, DV);

  // degree embedding MLP: 600->128 (silu) -> 128 (silu) -> 896
  k_rad1<<<NE, 128, 0, stream>>>(DV, deg_w1, deg_b1, R1);
  k_mgemm<0,1,2><<<dim3(1, NE/64), 256, 0, stream>>>(R1, T_degw2, deg_b2, R2, NE, 128, 128, 128,
                                                     nullptr, nullptr, nullptr, nullptr, nullptr, 0);
  k_mgemm<0,0,2><<<dim3(7, NE/64), 256, 0, stream>>>(R2, T_degw3, nullptr, RADD, NE, 896, 128, 128,
                                                     nullptr, nullptr, nullptr, nullptr, nullptr, 0);
  k_init<<<NN, 128, 0, stream>>>(pos, table, Yb, RADD, RP, EID, X);

  for (int i = 0; i < 3; i++){
    const float* nw  = (i < 2) ? attn_nw + (size_t)i*896   : fin_nw;
    const float* rw1 = (i < 2) ? rad_w1 + (size_t)i*76800 : lrad_w1;
    const float* rb1 = (i < 2) ? rad_b1 + (size_t)i*128   : lrad_b1;
    const float* av  = (i < 2) ? avec   + (size_t)i*128   : lavec;

    k_rmsnormR<<<NN, 128, 0, stream>>>(X, nw, HRw);
    // combined XS|XT projection, bf16 output
    k_mgemm<2,6,4><<<dim3(1, NN*NRr/64), 256, 0, stream>>>(HRw, T_wst[i], nullptr, XSTw, NN*NRr, 256, 128, 128,
                                                           nullptr, nullptr, nullptr, nullptr, nullptr, 0);
    k_rad1<<<NE, 128, 0, stream>>>(DV, rw1, rb1, R1);
    k_mgemm<0,0,2><<<dim3(1, NE/64), 256, 0, stream>>>(R1, T_rw2[i], nullptr, R2, NE, 128, 128, 128,
                                                       nullptr, nullptr, nullptr, nullptr, nullptr, 0);
    // fused logits + softmax + alpha
    k_attn<<<NN, 256, 0, stream>>>(XSTw, R2, av, srcp, RP, EID, AL);
    // V in CSR-permuted order, alpha-fused epilogue, then contiguous segment-sum
    for (int ch = 0; ch < NE/VCH_E; ch++){
      int p0 = ch*VCH_E;
      k_mgemm<3,7,2><<<dim3(1, VCH_E*NRr/64), 256, 0, stream>>>(R2, T_wv[i], nullptr, VS,
                                                                VCH_E*NRr, 128, 128, 128,
                                                                (const float*)XSTw, srcp, dstp, EID, AL, p0);
      k_aggseg<<<NN, 256, 0, stream>>>(VS, RP, p0, p0 + VCH_E, ch == 0, AG);
    }
    if (i < 2){
      // projection with fused scatter-accumulate into X
      k_mgemm<0,3,2><<<dim3(1, NN*NRr/64), 256, 0, stream>>>(AG, T_wp[i], nullptr, X, NN*NRr, 128, 128, 128,
                                                             nullptr, nullptr, nullptr, nullptr, nullptr, 0);
      // FFN: gate from row0, hidden kept in LDS (fused GEMM1+gate+GEMM2, weights from L2)
      k_rmsnorm<<<NN, 128, 0, stream>>>(X, ffn_nw + (size_t)i*896, Hbw);
      k_mgemm<2,4,1><<<dim3(8, NN/64), 256, 0, stream>>>(Hbw, T_f1[i], nullptr, SG, NN, 512, 128, NCO*CD,
                                                         nullptr, nullptr, nullptr, nullptr, nullptr, 0);
      k_ffn<<<NN*NCO/64, 256, 0, stream>>>(Hbw, T_f1[i], T_f2[i], SG, X);
    } else {
      k_mgemm<0,0,2><<<dim3(1, NN*NRr/64), 256, 0, stream>>>(AG, T_wp[i], nullptr, OR_, NN*NRr, 128, 128, 128,
                                                             nullptr, nullptr, nullptr, nullptr, nullptr, 0);
      k_pool<<<(NG*NCO*CD + 255)/256, 256, 0, stream>>>(OR_, GS, (float*)d_out);
    }
  }
}

// Round 16
// 1003.721 us; speedup vs baseline: 1.0544x; 1.0544x over previous
//
#include <hip/hip_runtime.h>
#include <math.h>

#define NN 2048
#define NE 12288
#define NCO 49
#define NRr 29
#define CD 128
#define NG 16
#define NJOBS 21
#define VCH_E 6144   // edges per V chunk (permuted positions)

typedef unsigned short u16;
typedef short bhalf8 __attribute__((ext_vector_type(8)));
typedef float fvec4 __attribute__((ext_vector_type(4)));

// RESTRICT: indices k (0..48) with |m|<=2.
__constant__ int c_res[29] = {0,1,2,3,4,5,6,7,8,10,11,12,13,14,18,19,20,21,22,28,29,30,31,32,40,41,42,43,44};
__constant__ int c_rinv[49] = {0,1,2,3,4,5,6,7,8,-1,9,10,11,12,13,-1,-1,-1,14,15,16,17,18,-1,-1,-1,-1,-1,19,20,21,22,23,-1,-1,-1,-1,-1,-1,-1,24,25,26,27,28,-1,-1,-1,-1};
__device__ constexpr int d_RES[29] = {0,1,2,3,4,5,6,7,8,10,11,12,13,14,18,19,20,21,22,28,29,30,31,32,40,41,42,43,44};

__device__ __forceinline__ constexpr int deg_of(int k){
  return (k<1)?0:(k<4)?1:(k<9)?2:(k<16)?3:(k<25)?4:(k<36)?5:6;
}
__device__ __forceinline__ float siluf(float x){ return x / (1.f + expf(-x)); }
__device__ __forceinline__ u16 f2bf(float f){
  unsigned int u = __float_as_uint(f);
  unsigned int r = (u + 0x7FFFu + ((u >> 16) & 1u)) >> 16;
  return (u16)r;
}
__device__ __forceinline__ float bf2f(u16 b){
  return __uint_as_float(((unsigned int)b) << 16);
}
__device__ __forceinline__ unsigned int pk(u16 lo, u16 hi){ return (unsigned int)lo | ((unsigned int)hi << 16); }

// ---------------- CSR build (deterministic, parallel) ----------------
__global__ __launch_bounds__(1024) void k_hist4(const int* __restrict__ dst, int* __restrict__ cnt,
                                                int* __restrict__ CH){
  __shared__ int h[4*NN];
  for (int i = threadIdx.x; i < 4*NN; i += 1024) h[i] = 0;
  __syncthreads();
  const int QE = NE/4;
  for (int e = threadIdx.x; e < NE; e += 1024){
    int q = e / QE;
    atomicAdd(&h[q*NN + dst[e]], 1);
  }
  __syncthreads();
  for (int n = threadIdx.x; n < NN; n += 1024){
    int s = 0;
    #pragma unroll
    for (int q = 0; q < 4; q++){ int v = h[q*NN + n]; CH[q*NN + n] = v; s += v; }
    cnt[n] = s;
  }
}
__global__ __launch_bounds__(1024) void k_scan2(const int* __restrict__ cnt, int* __restrict__ rowptr){
  __shared__ int a[NN], b[NN];
  int t = threadIdx.x;
  for (int i = t; i < NN; i += 1024) a[i] = cnt[i];
  __syncthreads();
  int* pin = a; int* pout = b;
  for (int off = 1; off < NN; off <<= 1){
    for (int i = t; i < NN; i += 1024)
      pout[i] = pin[i] + ((i >= off) ? pin[i - off] : 0);
    __syncthreads();
    int* tmp = pin; pin = pout; pout = tmp;
  }
  for (int i = t; i < NN; i += 1024) rowptr[i + 1] = pin[i];
  if (t == 0) rowptr[0] = 0;
}
__global__ __launch_bounds__(256) void k_fillw4(const int* __restrict__ dst, const int* __restrict__ rowptr,
                                                const int* __restrict__ CH, int* __restrict__ eid){
  int q = threadIdx.x >> 6, lane = threadIdx.x & 63;
  int n = blockIdx.x;
  int base = rowptr[n];
  for (int qq = 0; qq < q; qq++) base += CH[qq*NN + n];
  const int QE = NE/4;
  for (int e0 = q*QE; e0 < (q+1)*QE; e0 += 64){
    int e = e0 + lane;
    bool m = (dst[e] == n);
    unsigned long long mask = __ballot(m);
    if (m) eid[base + __popcll(mask & ((1ull << lane) - 1ull))] = e;
    base += __popcll(mask);
  }
}
__global__ void k_gstart(const int* __restrict__ batch, int* __restrict__ gs){
  int g = threadIdx.x;
  if (g > NG) return;
  int lo = 0, hi = NN;
  while (lo < hi){ int mid = (lo + hi) >> 1; if (batch[mid] < g) lo = mid + 1; else hi = mid; }
  gs[g] = lo;
}

// ---------------- all weight casts in one launch: [K][N] f32 -> [N][K] bf16 ----------------
struct CastJobs {
  const float* src[NJOBS];
  u16* dst[NJOBS];
  int K[NJOBS], N[NJOBS];
  int start[NJOBS + 1];
  int total;
};
__global__ void k_castall(CastJobs J){
  int i = blockIdx.x*blockDim.x + threadIdx.x;
  if (i >= J.total) return;
  int j = 0;
  while (i >= J.start[j + 1]) j++;
  int local = i - J.start[j];
  int K = J.K[j], N = J.N[j];
  int n = local / K, k = local - n*K;
  J.dst[j][local] = f2bf(J.src[j][(size_t)k*N + n]);
}

// ---------------- geometry ----------------
__global__ void k_geom(const float* __restrict__ ev, float* __restrict__ Y, float* __restrict__ dv){
  int e = blockIdx.x*blockDim.x + threadIdx.x;
  if (e >= NE) return;
  float x = ev[e*3+0], y = ev[e*3+1], z = ev[e*3+2];
  float r = sqrtf(x*x + y*y + z*z);
  dv[e] = r;
  float rn = fmaxf(r, 1e-8f);
  float ux = x/rn, uy = y/rn, uz = z/rn;
  float ct = fminf(fmaxf(uz, -1.f), 1.f);
  float st = sqrtf(fminf(fmaxf(1.f - ct*ct, 1e-12f), 1.f));
  float phi = atan2f(uy, ux);
  float P[7][7];
  P[0][0] = 1.f;
  #pragma unroll
  for (int m = 1; m <= 6; m++) P[m][m] = -(2.f*m - 1.f)*st*P[m-1][m-1];
  #pragma unroll
  for (int m = 0; m <= 5; m++) P[m+1][m] = (2.f*m + 1.f)*ct*P[m][m];
  #pragma unroll
  for (int m = 0; m <= 6; m++){
    #pragma unroll
    for (int l = m+2; l <= 6; l++)
      P[l][m] = ((2.f*l - 1.f)*ct*P[l-1][m] - (float)(l+m-1)*P[l-2][m]) / (float)(l-m);
  }
  float cmv[7], smv[7];
  #pragma unroll
  for (int m = 0; m <= 6; m++){ cmv[m] = cosf((float)m*phi); smv[m] = sinf((float)m*phi); }
  const double FOURPI = 12.566370614359172;
  int k = 0;
  #pragma unroll
  for (int l = 0; l <= 6; l++){
    #pragma unroll
    for (int mm = -l; mm <= l; mm++){
      int am = mm < 0 ? -mm : mm;
      double ratio = 1.0;
      for (int i = l-am+1; i <= l+am; i++) ratio /= (double)i;
      double nrm = sqrt((2.0*l + 1.0)/FOURPI*ratio);
      float v;
      if (mm == 0)      v = (float)nrm * P[l][0];
      else if (mm > 0)  v = (float)(1.4142135623730951*nrm) * P[l][am] * cmv[am];
      else              v = (float)(1.4142135623730951*nrm) * P[l][am] * smv[am];
      Y[(size_t)e*49 + k] = v; k++;
    }
  }
}

// ------------- layer-1 of radial MLPs (windowed gaussian, exact) -------------
__global__ __launch_bounds__(128) void k_rad1(const float* __restrict__ dv, const float* __restrict__ Wm,
                                              const float* __restrict__ bias, float* __restrict__ out){
  int e = blockIdx.x;
  int j = threadIdx.x;
  float d = dv[e];
  const float STEPF = (float)(5.0/599.0);
  const double step_d = (double)STEPF;
  const float GC = (float)(-0.5/((2.0*step_d)*(2.0*step_d)));
  __shared__ float g[64];
  int bc = (int)rintf(d / STEPF);
  int b0 = bc - 32;
  if (j < 64){
    int b = b0 + j;
    float gg = 0.f;
    if (b >= 0 && b < 600){
      float off = (float)((double)b * (5.0/599.0));
      float t = d - off;
      gg = expf(GC*t*t);
    }
    g[j] = gg;
  }
  __syncthreads();
  float acc = bias ? bias[j] : 0.f;
  #pragma unroll 8
  for (int i = 0; i < 64; i++){
    int b = b0 + i;
    if (b >= 0 && b < 600) acc += g[i]*Wm[b*CD + j];
  }
  out[(size_t)e*CD + j] = siluf(acc);
}

// ---------------- MFMA bf16 GEMM with NT column-tiles per block ----------------
// AMODE: 0 = f32 A (runtime lda); 2 = bf16 A (runtime lda);
//        3 = permuted fused-message A.
// EPI:   0 store(+bias); 1 silu(+bias); 2 accumulate; 3 scatter-accum into X;
//        4 sigmoid store; 5 gate-mul (P0=SG) then bf16 store; 6 bf16 store;
//        7 alpha-scale (ALp, permuted via eidp) then bf16 store (VS).
template<int AMODE, int EPI, int NT>
__global__ __launch_bounds__(256) void k_mgemm(
    const void* __restrict__ Av, const u16* __restrict__ Bt,
    const float* __restrict__ bias, void* __restrict__ Cv,
    int M, int N, int K, int lda,
    const float* __restrict__ P0,
    const int* __restrict__ src, const int* __restrict__ dstp,
    const int* __restrict__ eidp, const float* __restrict__ ALp, int e0)
{
  __shared__ __align__(16) u16 Asl[64*64];
  __shared__ __align__(16) u16 Bsl[NT][64*64];
  int tid = threadIdx.x;
  int bm = blockIdx.y*64;
  int bn0 = blockIdx.x*NT*64;
  int wid = tid >> 6, lane = tid & 63;
  int wr = wid >> 1, wc = wid & 1;
  int lr = lane & 15, lk = lane >> 4;
  fvec4 acc[NT][2][2] = {};
  for (int k0 = 0; k0 < K; k0 += 64){
    #pragma unroll
    for (int h = 0; h < 2; h++){
      int lin = tid + h*256;          // 0..511: 64 rows x 8 k-groups
      int row = lin >> 3, kg = lin & 7;
      uint4 q;
      if (AMODE == 3){
        int gr = bm + row;
        int el = gr / 29, kq = gr - el*29;
        int p = e0 + el;
        int e = eidp[p];
        int s = src[e], t = dstp[e];
        const u16* xst = (const u16*)P0;
        uint4 xs8 = *(const uint4*)&xst[((size_t)s*29 + kq)*256 + k0 + kg*8];
        uint4 xt8 = *(const uint4*)&xst[((size_t)t*29 + kq)*256 + 128 + k0 + kg*8];
        const float* rd = (const float*)Av + (size_t)e*128 + k0 + kg*8;
        const u16* xsp = (const u16*)&xs8;
        const u16* xtp = (const u16*)&xt8;
        u16 ov[8];
        #pragma unroll
        for (int j = 0; j < 8; j++)
          ov[j] = f2bf((bf2f(xsp[j]) + bf2f(xtp[j])) * rd[j]);
        q.x = pk(ov[0], ov[1]); q.y = pk(ov[2], ov[3]);
        q.z = pk(ov[4], ov[5]); q.w = pk(ov[6], ov[7]);
      } else if (AMODE == 2){
        const u16* ap = (const u16*)Av + (size_t)(bm + row)*lda + k0 + kg*8;
        q = *(const uint4*)ap;
      } else {
        const float* ap = (const float*)Av + (size_t)(bm + row)*lda + k0 + kg*8;
        float v[8];
        #pragma unroll
        for (int j = 0; j < 8; j++) v[j] = ap[j];
        q.x = pk(f2bf(v[0]), f2bf(v[1]));
        q.y = pk(f2bf(v[2]), f2bf(v[3]));
        q.z = pk(f2bf(v[4]), f2bf(v[5]));
        q.w = pk(f2bf(v[6]), f2bf(v[7]));
      }
      *(uint4*)&Asl[row*64 + ((kg*8) ^ ((row & 7)*8))] = q;
    }
    #pragma unroll
    for (int t = 0; t < NT; t++){
      #pragma unroll
      for (int h = 0; h < 2; h++){
        int lin = tid + h*256;
        int row = lin >> 3, kg = lin & 7;
        const u16* bp = Bt + (size_t)(bn0 + t*64 + row)*K + k0 + kg*8;
        *(uint4*)&Bsl[t][row*64 + ((kg*8) ^ ((row & 7)*8))] = *(const uint4*)bp;
      }
    }
    __syncthreads();
    #pragma unroll
    for (int ks = 0; ks < 2; ks++){
      int kg = ks*4 + lk;
      bhalf8 af[2];
      #pragma unroll
      for (int mi = 0; mi < 2; mi++){
        int ar = wr*32 + mi*16 + lr;
        af[mi] = *(const bhalf8*)&Asl[ar*64 + ((kg*8) ^ ((ar & 7)*8))];
      }
      #pragma unroll
      for (int t = 0; t < NT; t++){
        bhalf8 bfr[2];
        #pragma unroll
        for (int ni = 0; ni < 2; ni++){
          int br = wc*32 + ni*16 + lr;
          bfr[ni] = *(const bhalf8*)&Bsl[t][br*64 + ((kg*8) ^ ((br & 7)*8))];
        }
        #pragma unroll
        for (int mi = 0; mi < 2; mi++)
          #pragma unroll
          for (int ni = 0; ni < 2; ni++)
            acc[t][mi][ni] = __builtin_amdgcn_mfma_f32_16x16x32_bf16(af[mi], bfr[ni], acc[t][mi][ni], 0, 0, 0);
      }
    }
    __syncthreads();
  }
  #pragma unroll
  for (int t = 0; t < NT; t++){
    #pragma unroll
    for (int mi = 0; mi < 2; mi++){
      #pragma unroll
      for (int ni = 0; ni < 2; ni++){
        #pragma unroll
        for (int j = 0; j < 4; j++){
          int row = bm + wr*32 + mi*16 + lk*4 + j;
          int col = bn0 + t*64 + wc*32 + ni*16 + lr;
          float v = acc[t][mi][ni][j];
          if (EPI == 0){
            if (bias) v += bias[col];
            ((float*)Cv)[(size_t)row*N + col] = v;
          } else if (EPI == 1){
            if (bias) v += bias[col];
            ((float*)Cv)[(size_t)row*N + col] = siluf(v);
          } else if (EPI == 2){
            ((float*)Cv)[(size_t)row*N + col] += v;
          } else if (EPI == 3){
            int n = row / 29, kr = row - n*29;
            ((float*)Cv)[((size_t)n*49 + c_res[kr])*128 + col] += v;
          } else if (EPI == 4){
            ((float*)Cv)[(size_t)row*N + col] = 1.f/(1.f + expf(-v));
          } else if (EPI == 5){
            float g = P0[(size_t)(row/49)*N + col];
            ((u16*)Cv)[(size_t)row*N + col] = f2bf(v*g);
          } else if (EPI == 6){
            ((u16*)Cv)[(size_t)row*N + col] = f2bf(v);
          } else {
            int p = e0 + row/29;
            int e = eidp[p];
            float a = ALp[e*8 + (col >> 4)];
            ((u16*)Cv)[(size_t)row*N + col] = f2bf(v*a);
          }
        }
      }
    }
  }
}

// ---------------- fused FFN: X += ((bf16(A@W1)*gate)@W2), hidden in LDS, shared W buffer ----------------
// A: Hbw [NN*49][128] bf16. W1: [512][128] bf16. W2: [128][512] bf16. SG: [NN][512] f32.
// 40 KB LDS -> 4 blocks/CU. Bit-identical to the two-GEMM chain (same MFMA K-order, same rounding).
__global__ __launch_bounds__(256) void k_ffn(
    const u16* __restrict__ A, const u16* __restrict__ W1, const u16* __restrict__ W2,
    const float* __restrict__ SGp, float* __restrict__ Xp)
{
  __shared__ __align__(16) u16 Asl[64*128];   // 16 KB
  __shared__ __align__(16) u16 Ws[64*128];    // 16 KB, shared: W1 chunk then W2 chunk
  __shared__ __align__(16) u16 Hs[64*64];     // 8 KB
  int tid = threadIdx.x;
  int bm = blockIdx.x*64;
  int wid = tid >> 6, lane = tid & 63;
  int wr = wid >> 1, wc = wid & 1;
  int lr = lane & 15, lk = lane >> 4;
  for (int g = tid; g < 1024; g += 256){
    int row = g >> 4, kg = g & 15;
    *(uint4*)&Asl[row*128 + ((kg*8) ^ ((row & 7)*16))] = *(const uint4*)&A[(size_t)(bm + row)*128 + kg*8];
  }
  fvec4 o[2][4] = {};
  for (int h0 = 0; h0 < 512; h0 += 64){
    // stage W1 chunk [64][128] into Ws
    for (int g = tid; g < 1024; g += 256){
      int row = g >> 4, kg = g & 15;
      *(uint4*)&Ws[row*128 + ((kg*8) ^ ((row & 7)*16))] = *(const uint4*)&W1[(size_t)(h0 + row)*128 + kg*8];
    }
    __syncthreads();
    // GEMM1: 64x64 hidden tile (K=128)
    fvec4 hid[2][2] = {};
    #pragma unroll
    for (int kk = 0; kk < 4; kk++){
      int kg = kk*4 + lk;
      bhalf8 af[2], bf[2];
      #pragma unroll
      for (int mi = 0; mi < 2; mi++){
        int ar = wr*32 + mi*16 + lr;
        af[mi] = *(const bhalf8*)&Asl[ar*128 + ((kg*8) ^ ((ar & 7)*16))];
      }
      #pragma unroll
      for (int ni = 0; ni < 2; ni++){
        int br = wc*32 + ni*16 + lr;
        bf[ni] = *(const bhalf8*)&Ws[br*128 + ((kg*8) ^ ((br & 7)*16))];
      }
      #pragma unroll
      for (int mi = 0; mi < 2; mi++)
        #pragma unroll
        for (int ni = 0; ni < 2; ni++)
          hid[mi][ni] = __builtin_amdgcn_mfma_f32_16x16x32_bf16(af[mi], bf[ni], hid[mi][ni], 0, 0, 0);
    }
    // gate + bf16 round -> Hs
    #pragma unroll
    for (int mi = 0; mi < 2; mi++){
      #pragma unroll
      for (int j = 0; j < 4; j++){
        int row = wr*32 + mi*16 + lk*4 + j;
        int node = (bm + row)/49;
        const float* sgrow = &SGp[(size_t)node*512 + h0];
        #pragma unroll
        for (int ni = 0; ni < 2; ni++){
          int col = wc*32 + ni*16 + lr;
          Hs[row*64 + (col ^ ((row & 7)*8))] = f2bf(hid[mi][ni][j]*sgrow[col]);
        }
      }
    }
    __syncthreads();   // GEMM1 Ws reads done + Hs visible
    // stage W2 chunk [128][64] into Ws
    for (int g = tid; g < 1024; g += 256){
      int row = g >> 3, kg = g & 7;
      *(uint4*)&Ws[row*64 + ((kg*8) ^ ((row & 7)*8))] = *(const uint4*)&W2[(size_t)row*512 + h0 + kg*8];
    }
    __syncthreads();
    // GEMM2: out 64x128 accumulate (K=64 this chunk)
    #pragma unroll
    for (int kk2 = 0; kk2 < 2; kk2++){
      int kg = kk2*4 + lk;
      bhalf8 af2[2], bf2[4];
      #pragma unroll
      for (int mi = 0; mi < 2; mi++){
        int ar = wr*32 + mi*16 + lr;
        af2[mi] = *(const bhalf8*)&Hs[ar*64 + ((kg*8) ^ ((ar & 7)*8))];
      }
      #pragma unroll
      for (int ni = 0; ni < 4; ni++){
        int br = wc*64 + ni*16 + lr;
        bf2[ni] = *(const bhalf8*)&Ws[br*64 + ((kg*8) ^ ((br & 7)*8))];
      }
      #pragma unroll
      for (int mi = 0; mi < 2; mi++)
        #pragma unroll
        for (int ni = 0; ni < 4; ni++)
          o[mi][ni] = __builtin_amdgcn_mfma_f32_16x16x32_bf16(af2[mi], bf2[ni], o[mi][ni], 0, 0, 0);
    }
    __syncthreads();   // GEMM2 Ws/Hs reads done before next chunk overwrites
  }
  #pragma unroll
  for (int mi = 0; mi < 2; mi++)
    #pragma unroll
    for (int ni = 0; ni < 4; ni++)
      #pragma unroll
      for (int j = 0; j < 4; j++){
        int row = bm + wr*32 + mi*16 + lk*4 + j;
        int col = wc*64 + ni*16 + lr;
        Xp[(size_t)row*128 + col] += o[mi][ni][j];
      }
}

// ---------------- contiguous segment-sum of permuted VS rows (vectorized) ----------------
__global__ __launch_bounds__(256) void k_aggseg(const u16* __restrict__ VS, const int* __restrict__ rowptr,
                                                int p0, int p1, int first, float* __restrict__ agg){
  int n = blockIdx.x;
  int a = rowptr[n], b = rowptr[n+1];
  if (a < p0) a = p0;
  if (b > p1) b = p1;
  int tid = threadIdx.x;
  for (int g = tid; g < 464; g += 256){          // 29*128/8 = 464 groups of 8
    size_t obase = (size_t)n*29*128 + (size_t)g*8;
    float s[8];
    if (first){
      #pragma unroll
      for (int j = 0; j < 8; j++) s[j] = 0.f;
    } else {
      float4 lo = *(const float4*)&agg[obase];
      float4 hi = *(const float4*)&agg[obase + 4];
      s[0]=lo.x; s[1]=lo.y; s[2]=lo.z; s[3]=lo.w;
      s[4]=hi.x; s[5]=hi.y; s[6]=hi.z; s[7]=hi.w;
    }
    for (int p = a; p < b; p++){
      uint4 q = *(const uint4*)&VS[(size_t)(p - p0)*3712 + (size_t)g*8];
      const u16* qp = (const u16*)&q;
      #pragma unroll
      for (int j = 0; j < 8; j++) s[j] += bf2f(qp[j]);
    }
    float4 lo, hi;
    lo.x=s[0]; lo.y=s[1]; lo.z=s[2]; lo.w=s[3];
    hi.x=s[4]; hi.y=s[5]; hi.z=s[6]; hi.w=s[7];
    *(float4*)&agg[obase] = lo;
    *(float4*)&agg[obase + 4] = hi;
  }
}

// ---------------- node init ----------------
__global__ __launch_bounds__(128) void k_init(const float* __restrict__ pos, const float* __restrict__ table,
                                              const float* __restrict__ Yb, const float* __restrict__ radd,
                                              const int* __restrict__ rowptr, const int* __restrict__ eid,
                                              float* __restrict__ x){
  int n = blockIdx.x;
  int c = threadIdx.x;
  const float DLO = -3.26267f;
  const float DRG = (float)(3.295396 - (-3.26267));
  float p0 = pos[n*3+0], p1 = pos[n*3+1], p2 = pos[n*3+2];
  int t0 = min(127, max(0, (int)rintf((p0 - DLO)/DRG*128.f - 0.5f)));
  int t1 = min(127, max(0, (int)rintf((p1 - DLO)/DRG*128.f - 0.5f)));
  int t2 = min(127, max(0, (int)rintf((p2 - DLO)/DRG*128.f - 0.5f)));
  float emb = table[t0*CD + c] + table[t1*CD + c] + table[t2*CD + c];
  __shared__ float Yl[49];
  __shared__ float rl[896];
  float acc[NCO];
  #pragma unroll
  for (int k = 0; k < NCO; k++) acc[k] = 0.f;
  int pA = rowptr[n], pB = rowptr[n+1];
  for (int p = pA; p < pB; p++){
    int e = eid[p];
    if (c < 49) Yl[c] = Yb[(size_t)e*49 + c];
    #pragma unroll
    for (int q = 0; q < 7; q++) rl[q*128 + c] = radd[(size_t)e*896 + q*128 + c];
    __syncthreads();
    #pragma unroll
    for (int k = 0; k < NCO; k++){
      acc[k] += Yl[k]*rl[deg_of(k)*128 + c];
    }
    __syncthreads();
  }
  size_t base = (size_t)n*NCO*CD;
  x[base + c] = emb + acc[0]*(1.f/3.f);
  #pragma unroll
  for (int k = 1; k < NCO; k++) x[base + k*CD + c] = acc[k]*(1.f/3.f);
}

// ---------------- degree-grouped RMS norm, bf16 out (full 49 rows, for FFN) ----------------
__global__ __launch_bounds__(128) void k_rmsnorm(const float* __restrict__ x, const float* __restrict__ w,
                                                 u16* __restrict__ out){
  int n = blockIdx.x;
  int c = threadIdx.x;
  const float* xb = x + (size_t)n*NCO*CD;
  float vals[NCO];
  float ss[7] = {0,0,0,0,0,0,0};
  #pragma unroll
  for (int k = 0; k < NCO; k++){
    float v = xb[k*CD + c];
    vals[k] = v;
    ss[deg_of(k)] += v*v;
  }
  __shared__ float red[7][128];
  #pragma unroll
  for (int l = 0; l < 7; l++) red[l][c] = ss[l];
  __syncthreads();
  __shared__ float inv[7];
  if (c < 7){
    float s = 0.f;
    for (int i = 0; i < 128; i++) s += red[c][i];
    float ms = s / ((float)(2*c + 1)*128.f);
    inv[c] = 1.f / sqrtf(ms + 1e-6f);
  }
  __syncthreads();
  size_t base = (size_t)n*NCO*CD;
  #pragma unroll
  for (int k = 0; k < NCO; k++){
    int l = deg_of(k);
    out[base + k*CD + c] = f2bf(vals[k]*inv[l]*w[l*CD + c]);
  }
}

// ---------------- RMS norm writing restricted 29 rows, bf16 out ----------------
__global__ __launch_bounds__(128) void k_rmsnormR(const float* __restrict__ x, const float* __restrict__ w,
                                                  u16* __restrict__ hr){
  int n = blockIdx.x;
  int c = threadIdx.x;
  const float* xb = x + (size_t)n*NCO*CD;
  float vals[NCO];
  float ss[7] = {0,0,0,0,0,0,0};
  #pragma unroll
  for (int k = 0; k < NCO; k++){
    float v = xb[k*CD + c];
    vals[k] = v;
    ss[deg_of(k)] += v*v;
  }
  __shared__ float red[7][128];
  #pragma unroll
  for (int l = 0; l < 7; l++) red[l][c] = ss[l];
  __syncthreads();
  __shared__ float inv[7];
  if (c < 7){
    float s = 0.f;
    for (int i = 0; i < 128; i++) s += red[c][i];
    float ms = s / ((float)(2*c + 1)*128.f);
    inv[c] = 1.f / sqrtf(ms + 1e-6f);
  }
  __syncthreads();
  size_t base = (size_t)n*NRr*CD;
  #pragma unroll
  for (int kr = 0; kr < NRr; kr++){
    int k = d_RES[kr];
    int l = deg_of(k);
    hr[base + kr*CD + c] = f2bf(vals[k]*inv[l]*w[l*CD + c]);
  }
}

// ---------------- fused attention: logits + segment softmax + alpha ----------------
__global__ __launch_bounds__(256) void k_attn(
    const u16* __restrict__ XST, const float* __restrict__ rad, const float* __restrict__ avec,
    const int* __restrict__ src, const int* __restrict__ rowptr, const int* __restrict__ eid,
    float* __restrict__ AL)
{
  int n = blockIdx.x;
  int p0 = rowptr[n], p1 = rowptr[n+1];
  int deg = p1 - p0;
  if (deg == 0) return;
  __shared__ float lgs[64][8];
  __shared__ float xt0[128];
  __shared__ float av[128];
  __shared__ float mxs[8], dens[8];
  int tid = threadIdx.x;
  if (tid < 128){
    xt0[tid] = bf2f(XST[(size_t)n*NRr*256 + 128 + tid]);
    av[tid] = avec[tid];
  }
  __syncthreads();
  for (int pair = tid; pair < deg*8; pair += 256){
    int pl = pair >> 3, h = pair & 7;
    int e = eid[p0 + pl];
    int s = src[e];
    const u16* xs = &XST[(size_t)s*NRr*256 + h*16];
    uint4 q0 = *(const uint4*)xs;
    uint4 q1 = *(const uint4*)(xs + 8);
    const u16* x0 = (const u16*)&q0;
    const u16* x1 = (const u16*)&q1;
    const float* rd = &rad[(size_t)e*128 + h*16];
    float4 r0 = *(const float4*)(rd + 0);
    float4 r1 = *(const float4*)(rd + 4);
    float4 r2 = *(const float4*)(rd + 8);
    float4 r3 = *(const float4*)(rd + 12);
    float rr[16] = {r0.x,r0.y,r0.z,r0.w, r1.x,r1.y,r1.z,r1.w,
                    r2.x,r2.y,r2.z,r2.w, r3.x,r3.y,r3.z,r3.w};
    float acc = 0.f;
    #pragma unroll
    for (int d = 0; d < 8; d++){
      float m = (bf2f(x0[d]) + xt0[h*16 + d]) * rr[d];
      acc += siluf(m) * av[h*16 + d];
    }
    #pragma unroll
    for (int d = 0; d < 8; d++){
      float m = (bf2f(x1[d]) + xt0[h*16 + 8 + d]) * rr[8 + d];
      acc += siluf(m) * av[h*16 + 8 + d];
    }
    lgs[pl][h] = acc;
  }
  __syncthreads();
  if (tid < 8){
    float m = -1e30f;
    for (int pl = 0; pl < deg; pl++) m = fmaxf(m, lgs[pl][tid]);
    float sden = 0.f;
    for (int pl = 0; pl < deg; pl++) sden += expf(lgs[pl][tid] - m);
    mxs[tid] = m; dens[tid] = sden;
  }
  __syncthreads();
  for (int pair = tid; pair < deg*8; pair += 256){
    int pl = pair >> 3, h = pair & 7;
    int e = eid[p0 + pl];
    AL[e*8 + h] = expf(lgs[pl][h] - mxs[h]) / fmaxf(dens[h], 1e-9f);
  }
}

// ---------------- pooling ----------------
__global__ void k_pool(const float* __restrict__ orr, const int* __restrict__ gs, float* __restrict__ out){
  int i = blockIdx.x*blockDim.x + threadIdx.x;
  if (i >= NG*NCO*CD) return;
  int c = i & 127;
  int k = (i >> 7) % 49;
  int g = i / (49*128);
  int kr = c_rinv[k];
  float v = 0.f;
  if (kr >= 0){
    int a = gs[g], b = gs[g+1];
    float s = 0.f;
    for (int n = a; n < b; n++) s += orr[((size_t)n*29 + kr)*128 + c];
    int cnt = b - a;
    v = s / (float)(cnt > 0 ? cnt : 1);
  }
  out[i] = v;
}

extern "C" void kernel_launch(void* const* d_in, const int* in_sizes, int n_in,
                              void* d_out, int out_size, void* d_ws, size_t ws_size,
                              hipStream_t stream){
  const float* pos    = (const float*)d_in[0];
  const float* evec   = (const float*)d_in[1];
  const int*   eidx   = (const int*)  d_in[2];
  const int*   batch  = (const int*)  d_in[3];
  const float* table  = (const float*)d_in[4];
  const float* deg_w1 = (const float*)d_in[5];
  const float* deg_b1 = (const float*)d_in[6];
  const float* deg_w2 = (const float*)d_in[7];
  const float* deg_b2 = (const float*)d_in[8];
  const float* deg_w3 = (const float*)d_in[9];
  const float* attn_nw= (const float*)d_in[10];
  const float* w_src  = (const float*)d_in[11];
  const float* w_tgt  = (const float*)d_in[12];
  const float* rad_w1 = (const float*)d_in[13];
  const float* rad_b1 = (const float*)d_in[14];
  const float* rad_w2 = (const float*)d_in[15];
  const float* avec   = (const float*)d_in[16];
  const float* w_val  = (const float*)d_in[17];
  const float* w_proj = (const float*)d_in[18];
  const float* ffn_nw = (const float*)d_in[19];
  const float* ffn_w1 = (const float*)d_in[20];
  const float* ffn_w2 = (const float*)d_in[21];
  const float* fin_nw = (const float*)d_in[22];
  const float* lw_src = (const float*)d_in[23];
  const float* lw_tgt = (const float*)d_in[24];
  const float* lrad_w1= (const float*)d_in[25];
  const float* lrad_b1= (const float*)d_in[26];
  const float* lrad_w2= (const float*)d_in[27];
  const float* lavec  = (const float*)d_in[28];
  const float* lw_val = (const float*)d_in[29];
  const float* lw_proj= (const float*)d_in[30];

  const int* srcp = eidx;
  const int* dstp = eidx + NE;

  float* W = (float*)d_ws;
  size_t o = 0;
  float* X    = W + o; o += (size_t)NN*49*128;
  float* Hb   = W + o; o += (size_t)NN*49*128;   // RADD, VS chunks, latent proj out, FFN rmsnorm(bf16)
  float* HR   = W + o; o += (size_t)NN*29*128;   // rmsnormR(bf16) out, AG
  float* XSTf = W + o; o += (size_t)NN*29*256/2; // XST bf16 region (u16)
  float* R1   = W + o; o += (size_t)NE*128;
  float* R2   = W + o; o += (size_t)NE*128;
  float* Yb   = W + o; o += (size_t)NE*49;
  float* DV   = W + o; o += (size_t)NE;
  float* LG   = W + o; o += (size_t)NE*8;
  float* AL   = W + o; o += (size_t)NE*8;
  float* MX   = W + o; o += (size_t)NN*8;
  float* DEN  = W + o; o += (size_t)NN*8;
  float* SG   = W + o; o += (size_t)NN*512;
  int* CNT = (int*)(W + o); o += NN;
  int* RP  = (int*)(W + o); o += NN + 1;
  int* EID = (int*)(W + o); o += NE;
  int* GS  = (int*)(W + o); o += NG + 1;
  int* CH  = (int*)(W + o); o += 4*NN;
  // bf16 transposed weights
  u16* WB = (u16*)(W + o);
  size_t wo = 0;
  u16* T_degw2 = WB + wo; wo += 16384;
  u16* T_degw3 = WB + wo; wo += 114688;
  u16* T_wst[3]; u16* T_wv[3]; u16* T_wp[3]; u16* T_rw2[3];
  for (int i = 0; i < 3; i++){ T_wst[i] = WB + wo; wo += 32768; }   // [256][128]
  for (int i = 0; i < 3; i++){ T_wv[i] = WB + wo; wo += 16384; }
  for (int i = 0; i < 3; i++){ T_wp[i] = WB + wo; wo += 16384; }
  for (int i = 0; i < 3; i++){ T_rw2[i] = WB + wo; wo += 16384; }
  u16* T_f1[2]; u16* T_f2[2];
  for (int i = 0; i < 2; i++){ T_f1[i] = WB + wo; wo += 65536; }
  for (int i = 0; i < 2; i++){ T_f2[i] = WB + wo; wo += 65536; }
  (void)ws_size; (void)in_sizes; (void)n_in; (void)out_size; (void)LG; (void)MX; (void)DEN;

  u16*  XSTw = (u16*)XSTf;                        // [NN][29][256] bf16
  u16*  HRw  = (u16*)HR;                          // rmsnormR bf16 out
  u16*  Hbw  = (u16*)Hb;                          // FFN rmsnorm bf16 out (first half of Hb)
  float* RADD = Hb;                               // E*896 <= Hb; free before layers
  u16*  VS    = (u16*)Hb;                         // VCH_E*29*128 u16 <= Hb
  float* AG   = HR;
  float* OR_  = Hb;                               // latent proj out (after aggseg done)

  // ---- all weight casts in one launch ----
  {
    CastJobs J;
    int idx = 0, acc = 0;
    auto add = [&](const float* s, u16* d, int K, int N){
      J.src[idx] = s; J.dst[idx] = d; J.K[idx] = K; J.N[idx] = N; J.start[idx] = acc;
      acc += K*N; idx++;
    };
    add(deg_w2, T_degw2, 128, 128);
    add(deg_w3, T_degw3, 128, 896);
    for (int i = 0; i < 3; i++){
      add((i < 2) ? w_src  + (size_t)i*16384 : lw_src,  T_wst[i],          128, 128);
      add((i < 2) ? w_tgt  + (size_t)i*16384 : lw_tgt,  T_wst[i] + 16384,  128, 128);
      add((i < 2) ? w_val  + (size_t)i*16384 : lw_val,  T_wv[i], 128, 128);
      add((i < 2) ? w_proj + (size_t)i*16384 : lw_proj, T_wp[i], 128, 128);
      add((i < 2) ? rad_w2 + (size_t)i*16384 : lrad_w2, T_rw2[i], 128, 128);
    }
    for (int i = 0; i < 2; i++){
      add(ffn_w1 + (size_t)i*65536, T_f1[i], 128, 512);
      add(ffn_w2 + (size_t)i*65536, T_f2[i], 512, 128);
    }
    J.start[idx] = acc; J.total = acc;
    k_castall<<<(acc + 255)/256, 256, 0, stream>>>(J);
  }

  // CSR + groups
  k_hist4<<<1, 1024, 0, stream>>>(dstp, CNT, CH);
  k_scan2<<<1, 1024, 0, stream>>>(CNT, RP);
  k_fillw4<<<NN, 256, 0, stream>>>(dstp, RP, CH, EID);
  k_gstart<<<1, 32, 0, stream>>>(batch, GS);

  // geometry
  k_geom<<<48, 256, 0, stream>>>(evec, Yb, DV);

  // degree embedding MLP: 600->128 (silu) -> 128 (silu) -> 896
  k_rad1<<<NE, 128, 0, stream>>>(DV, deg_w1, deg_b1, R1);
  k_mgemm<0,1,2><<<dim3(1, NE/64), 256, 0, stream>>>(R1, T_degw2, deg_b2, R2, NE, 128, 128, 128,
                                                     nullptr, nullptr, nullptr, nullptr, nullptr, 0);
  k_mgemm<0,0,2><<<dim3(7, NE/64), 256, 0, stream>>>(R2, T_degw3, nullptr, RADD, NE, 896, 128, 128,
                                                     nullptr, nullptr, nullptr, nullptr, nullptr, 0);
  k_init<<<NN, 128, 0, stream>>>(pos, table, Yb, RADD, RP, EID, X);

  for (int i = 0; i < 3; i++){
    const float* nw  = (i < 2) ? attn_nw + (size_t)i*896   : fin_nw;
    const float* rw1 = (i < 2) ? rad_w1 + (size_t)i*76800 : lrad_w1;
    const float* rb1 = (i < 2) ? rad_b1 + (size_t)i*128   : lrad_b1;
    const float* av  = (i < 2) ? avec   + (size_t)i*128   : lavec;

    k_rmsnormR<<<NN, 128, 0, stream>>>(X, nw, HRw);
    // combined XS|XT projection, bf16 output
    k_mgemm<2,6,4><<<dim3(1, NN*NRr/64), 256, 0, stream>>>(HRw, T_wst[i], nullptr, XSTw, NN*NRr, 256, 128, 128,
                                                           nullptr, nullptr, nullptr, nullptr, nullptr, 0);
    k_rad1<<<NE, 128, 0, stream>>>(DV, rw1, rb1, R1);
    k_mgemm<0,0,2><<<dim3(1, NE/64), 256, 0, stream>>>(R1, T_rw2[i], nullptr, R2, NE, 128, 128, 128,
                                                       nullptr, nullptr, nullptr, nullptr, nullptr, 0);
    // fused logits + softmax + alpha
    k_attn<<<NN, 256, 0, stream>>>(XSTw, R2, av, srcp, RP, EID, AL);
    // V in CSR-permuted order, alpha-fused epilogue, then contiguous segment-sum
    for (int ch = 0; ch < NE/VCH_E; ch++){
      int p0 = ch*VCH_E;
      k_mgemm<3,7,2><<<dim3(1, VCH_E*NRr/64), 256, 0, stream>>>(R2, T_wv[i], nullptr, VS,
                                                                VCH_E*NRr, 128, 128, 128,
                                                                (const float*)XSTw, srcp, dstp, EID, AL, p0);
      k_aggseg<<<NN, 256, 0, stream>>>(VS, RP, p0, p0 + VCH_E, ch == 0, AG);
    }
    if (i < 2){
      // projection with fused scatter-accumulate into X
      k_mgemm<0,3,2><<<dim3(1, NN*NRr/64), 256, 0, stream>>>(AG, T_wp[i], nullptr, X, NN*NRr, 128, 128, 128,
                                                             nullptr, nullptr, nullptr, nullptr, nullptr, 0);
      // FFN: gate from row0, hidden kept in LDS (fused GEMM1+gate+GEMM2, shared W buffer)
      k_rmsnorm<<<NN, 128, 0, stream>>>(X, ffn_nw + (size_t)i*896, Hbw);
      k_mgemm<2,4,1><<<dim3(8, NN/64), 256, 0, stream>>>(Hbw, T_f1[i], nullptr, SG, NN, 512, 128, NCO*CD,
                                                         nullptr, nullptr, nullptr, nullptr, nullptr, 0);
      k_ffn<<<NN*NCO/64, 256, 0, stream>>>(Hbw, T_f1[i], T_f2[i], SG, X);
    } else {
      k_mgemm<0,0,2><<<dim3(1, NN*NRr/64), 256, 0, stream>>>(AG, T_wp[i], nullptr, OR_, NN*NRr, 128, 128, 128,
                                                             nullptr, nullptr, nullptr, nullptr, nullptr, 0);
      k_pool<<<(NG*NCO*CD + 255)/256, 256, 0, stream>>>(OR_, GS, (float*)d_out);
    }
  }
}

// Round 17
// 934.492 us; speedup vs baseline: 1.1325x; 1.0741x over previous
//
#include <hip/hip_runtime.h>
#include <math.h>

#define NN 2048
#define NE 12288
#define NCO 49
#define NRr 29
#define CD 128
#define NG 16
#define NJOBS 21
#define VCH_E 6144   // edges per V chunk (permuted positions)

typedef unsigned short u16;
typedef short bhalf8 __attribute__((ext_vector_type(8)));
typedef float fvec4 __attribute__((ext_vector_type(4)));

// RESTRICT: indices k (0..48) with |m|<=2.
__constant__ int c_res[29] = {0,1,2,3,4,5,6,7,8,10,11,12,13,14,18,19,20,21,22,28,29,30,31,32,40,41,42,43,44};
__constant__ int c_rinv[49] = {0,1,2,3,4,5,6,7,8,-1,9,10,11,12,13,-1,-1,-1,14,15,16,17,18,-1,-1,-1,-1,-1,19,20,21,22,23,-1,-1,-1,-1,-1,-1,-1,24,25,26,27,28,-1,-1,-1,-1};
__device__ constexpr int d_RES[29] = {0,1,2,3,4,5,6,7,8,10,11,12,13,14,18,19,20,21,22,28,29,30,31,32,40,41,42,43,44};

__device__ __forceinline__ constexpr int deg_of(int k){
  return (k<1)?0:(k<4)?1:(k<9)?2:(k<16)?3:(k<25)?4:(k<36)?5:6;
}
__device__ __forceinline__ float siluf(float x){ return x / (1.f + expf(-x)); }
__device__ __forceinline__ u16 f2bf(float f){
  unsigned int u = __float_as_uint(f);
  unsigned int r = (u + 0x7FFFu + ((u >> 16) & 1u)) >> 16;
  return (u16)r;
}
__device__ __forceinline__ float bf2f(u16 b){
  return __uint_as_float(((unsigned int)b) << 16);
}
__device__ __forceinline__ unsigned int pk(u16 lo, u16 hi){ return (unsigned int)lo | ((unsigned int)hi << 16); }

// ---------------- CSR build (deterministic, parallel) ----------------
__global__ __launch_bounds__(1024) void k_hist4(const int* __restrict__ dst, int* __restrict__ cnt,
                                                int* __restrict__ CH){
  __shared__ int h[4*NN];
  for (int i = threadIdx.x; i < 4*NN; i += 1024) h[i] = 0;
  __syncthreads();
  const int QE = NE/4;
  for (int e = threadIdx.x; e < NE; e += 1024){
    int q = e / QE;
    atomicAdd(&h[q*NN + dst[e]], 1);
  }
  __syncthreads();
  for (int n = threadIdx.x; n < NN; n += 1024){
    int s = 0;
    #pragma unroll
    for (int q = 0; q < 4; q++){ int v = h[q*NN + n]; CH[q*NN + n] = v; s += v; }
    cnt[n] = s;
  }
}
__global__ __launch_bounds__(1024) void k_scan2(const int* __restrict__ cnt, int* __restrict__ rowptr){
  __shared__ int a[NN], b[NN];
  int t = threadIdx.x;
  for (int i = t; i < NN; i += 1024) a[i] = cnt[i];
  __syncthreads();
  int* pin = a; int* pout = b;
  for (int off = 1; off < NN; off <<= 1){
    for (int i = t; i < NN; i += 1024)
      pout[i] = pin[i] + ((i >= off) ? pin[i - off] : 0);
    __syncthreads();
    int* tmp = pin; pin = pout; pout = tmp;
  }
  for (int i = t; i < NN; i += 1024) rowptr[i + 1] = pin[i];
  if (t == 0) rowptr[0] = 0;
}
__global__ __launch_bounds__(256) void k_fillw4(const int* __restrict__ dst, const int* __restrict__ rowptr,
                                                const int* __restrict__ CH, int* __restrict__ eid){
  int q = threadIdx.x >> 6, lane = threadIdx.x & 63;
  int n = blockIdx.x;
  int base = rowptr[n];
  for (int qq = 0; qq < q; qq++) base += CH[qq*NN + n];
  const int QE = NE/4;
  for (int e0 = q*QE; e0 < (q+1)*QE; e0 += 64){
    int e = e0 + lane;
    bool m = (dst[e] == n);
    unsigned long long mask = __ballot(m);
    if (m) eid[base + __popcll(mask & ((1ull << lane) - 1ull))] = e;
    base += __popcll(mask);
  }
}
__global__ void k_gstart(const int* __restrict__ batch, int* __restrict__ gs){
  int g = threadIdx.x;
  if (g > NG) return;
  int lo = 0, hi = NN;
  while (lo < hi){ int mid = (lo + hi) >> 1; if (batch[mid] < g) lo = mid + 1; else hi = mid; }
  gs[g] = lo;
}

// ---------------- all weight casts in one launch: [K][N] f32 -> [N][K] bf16 ----------------
struct CastJobs {
  const float* src[NJOBS];
  u16* dst[NJOBS];
  int K[NJOBS], N[NJOBS];
  int start[NJOBS + 1];
  int total;
};
__global__ void k_castall(CastJobs J){
  int i = blockIdx.x*blockDim.x + threadIdx.x;
  if (i >= J.total) return;
  int j = 0;
  while (i >= J.start[j + 1]) j++;
  int local = i - J.start[j];
  int K = J.K[j], N = J.N[j];
  int n = local / K, k = local - n*K;
  J.dst[j][local] = f2bf(J.src[j][(size_t)k*N + n]);
}

// ---------------- geometry ----------------
__global__ void k_geom(const float* __restrict__ ev, float* __restrict__ Y, float* __restrict__ dv){
  int e = blockIdx.x*blockDim.x + threadIdx.x;
  if (e >= NE) return;
  float x = ev[e*3+0], y = ev[e*3+1], z = ev[e*3+2];
  float r = sqrtf(x*x + y*y + z*z);
  dv[e] = r;
  float rn = fmaxf(r, 1e-8f);
  float ux = x/rn, uy = y/rn, uz = z/rn;
  float ct = fminf(fmaxf(uz, -1.f), 1.f);
  float st = sqrtf(fminf(fmaxf(1.f - ct*ct, 1e-12f), 1.f));
  float phi = atan2f(uy, ux);
  float P[7][7];
  P[0][0] = 1.f;
  #pragma unroll
  for (int m = 1; m <= 6; m++) P[m][m] = -(2.f*m - 1.f)*st*P[m-1][m-1];
  #pragma unroll
  for (int m = 0; m <= 5; m++) P[m+1][m] = (2.f*m + 1.f)*ct*P[m][m];
  #pragma unroll
  for (int m = 0; m <= 6; m++){
    #pragma unroll
    for (int l = m+2; l <= 6; l++)
      P[l][m] = ((2.f*l - 1.f)*ct*P[l-1][m] - (float)(l+m-1)*P[l-2][m]) / (float)(l-m);
  }
  float cmv[7], smv[7];
  #pragma unroll
  for (int m = 0; m <= 6; m++){ cmv[m] = cosf((float)m*phi); smv[m] = sinf((float)m*phi); }
  const double FOURPI = 12.566370614359172;
  int k = 0;
  #pragma unroll
  for (int l = 0; l <= 6; l++){
    #pragma unroll
    for (int mm = -l; mm <= l; mm++){
      int am = mm < 0 ? -mm : mm;
      double ratio = 1.0;
      for (int i = l-am+1; i <= l+am; i++) ratio /= (double)i;
      double nrm = sqrt((2.0*l + 1.0)/FOURPI*ratio);
      float v;
      if (mm == 0)      v = (float)nrm * P[l][0];
      else if (mm > 0)  v = (float)(1.4142135623730951*nrm) * P[l][am] * cmv[am];
      else              v = (float)(1.4142135623730951*nrm) * P[l][am] * smv[am];
      Y[(size_t)e*49 + k] = v; k++;
    }
  }
}

// ------------- layer-1 of radial MLPs (windowed gaussian, exact) -------------
__global__ __launch_bounds__(128) void k_rad1(const float* __restrict__ dv, const float* __restrict__ Wm,
                                              const float* __restrict__ bias, float* __restrict__ out){
  int e = blockIdx.x;
  int j = threadIdx.x;
  float d = dv[e];
  const float STEPF = (float)(5.0/599.0);
  const double step_d = (double)STEPF;
  const float GC = (float)(-0.5/((2.0*step_d)*(2.0*step_d)));
  __shared__ float g[64];
  int bc = (int)rintf(d / STEPF);
  int b0 = bc - 32;
  if (j < 64){
    int b = b0 + j;
    float gg = 0.f;
    if (b >= 0 && b < 600){
      float off = (float)((double)b * (5.0/599.0));
      float t = d - off;
      gg = expf(GC*t*t);
    }
    g[j] = gg;
  }
  __syncthreads();
  float acc = bias ? bias[j] : 0.f;
  #pragma unroll 8
  for (int i = 0; i < 64; i++){
    int b = b0 + i;
    if (b >= 0 && b < 600) acc += g[i]*Wm[b*CD + j];
  }
  out[(size_t)e*CD + j] = siluf(acc);
}

// ---------------- MFMA bf16 GEMM with NT column-tiles per block ----------------
// AMODE: 0 = f32 A (runtime lda); 2 = bf16 A (runtime lda);
//        3 = permuted fused-message A.
// EPI:   0 store(+bias); 1 silu(+bias); 2 accumulate; 3 scatter-accum into X;
//        4 sigmoid store; 5 gate-mul (P0=SG) then bf16 store; 6 bf16 store;
//        7 alpha-scale (ALp, permuted via eidp) then bf16 store (VS).
template<int AMODE, int EPI, int NT>
__global__ __launch_bounds__(256) void k_mgemm(
    const void* __restrict__ Av, const u16* __restrict__ Bt,
    const float* __restrict__ bias, void* __restrict__ Cv,
    int M, int N, int K, int lda,
    const float* __restrict__ P0,
    const int* __restrict__ src, const int* __restrict__ dstp,
    const int* __restrict__ eidp, const float* __restrict__ ALp, int e0)
{
  __shared__ __align__(16) u16 Asl[64*64];
  __shared__ __align__(16) u16 Bsl[NT][64*64];
  int tid = threadIdx.x;
  int bm = blockIdx.y*64;
  int bn0 = blockIdx.x*NT*64;
  int wid = tid >> 6, lane = tid & 63;
  int wr = wid >> 1, wc = wid & 1;
  int lr = lane & 15, lk = lane >> 4;
  fvec4 acc[NT][2][2] = {};
  for (int k0 = 0; k0 < K; k0 += 64){
    #pragma unroll
    for (int h = 0; h < 2; h++){
      int lin = tid + h*256;          // 0..511: 64 rows x 8 k-groups
      int row = lin >> 3, kg = lin & 7;
      uint4 q;
      if (AMODE == 3){
        int gr = bm + row;
        int el = gr / 29, kq = gr - el*29;
        int p = e0 + el;
        int e = eidp[p];
        int s = src[e], t = dstp[e];
        const u16* xst = (const u16*)P0;
        uint4 xs8 = *(const uint4*)&xst[((size_t)s*29 + kq)*256 + k0 + kg*8];
        uint4 xt8 = *(const uint4*)&xst[((size_t)t*29 + kq)*256 + 128 + k0 + kg*8];
        const float* rd = (const float*)Av + (size_t)e*128 + k0 + kg*8;
        const u16* xsp = (const u16*)&xs8;
        const u16* xtp = (const u16*)&xt8;
        u16 ov[8];
        #pragma unroll
        for (int j = 0; j < 8; j++)
          ov[j] = f2bf((bf2f(xsp[j]) + bf2f(xtp[j])) * rd[j]);
        q.x = pk(ov[0], ov[1]); q.y = pk(ov[2], ov[3]);
        q.z = pk(ov[4], ov[5]); q.w = pk(ov[6], ov[7]);
      } else if (AMODE == 2){
        const u16* ap = (const u16*)Av + (size_t)(bm + row)*lda + k0 + kg*8;
        q = *(const uint4*)ap;
      } else {
        const float* ap = (const float*)Av + (size_t)(bm + row)*lda + k0 + kg*8;
        float v[8];
        #pragma unroll
        for (int j = 0; j < 8; j++) v[j] = ap[j];
        q.x = pk(f2bf(v[0]), f2bf(v[1]));
        q.y = pk(f2bf(v[2]), f2bf(v[3]));
        q.z = pk(f2bf(v[4]), f2bf(v[5]));
        q.w = pk(f2bf(v[6]), f2bf(v[7]));
      }
      *(uint4*)&Asl[row*64 + ((kg*8) ^ ((row & 7)*8))] = q;
    }
    #pragma unroll
    for (int t = 0; t < NT; t++){
      #pragma unroll
      for (int h = 0; h < 2; h++){
        int lin = tid + h*256;
        int row = lin >> 3, kg = lin & 7;
        const u16* bp = Bt + (size_t)(bn0 + t*64 + row)*K + k0 + kg*8;
        *(uint4*)&Bsl[t][row*64 + ((kg*8) ^ ((row & 7)*8))] = *(const uint4*)bp;
      }
    }
    __syncthreads();
    #pragma unroll
    for (int ks = 0; ks < 2; ks++){
      int kg = ks*4 + lk;
      bhalf8 af[2];
      #pragma unroll
      for (int mi = 0; mi < 2; mi++){
        int ar = wr*32 + mi*16 + lr;
        af[mi] = *(const bhalf8*)&Asl[ar*64 + ((kg*8) ^ ((ar & 7)*8))];
      }
      #pragma unroll
      for (int t = 0; t < NT; t++){
        bhalf8 bfr[2];
        #pragma unroll
        for (int ni = 0; ni < 2; ni++){
          int br = wc*32 + ni*16 + lr;
          bfr[ni] = *(const bhalf8*)&Bsl[t][br*64 + ((kg*8) ^ ((br & 7)*8))];
        }
        #pragma unroll
        for (int mi = 0; mi < 2; mi++)
          #pragma unroll
          for (int ni = 0; ni < 2; ni++)
            acc[t][mi][ni] = __builtin_amdgcn_mfma_f32_16x16x32_bf16(af[mi], bfr[ni], acc[t][mi][ni], 0, 0, 0);
      }
    }
    __syncthreads();
  }
  #pragma unroll
  for (int t = 0; t < NT; t++){
    #pragma unroll
    for (int mi = 0; mi < 2; mi++){
      #pragma unroll
      for (int ni = 0; ni < 2; ni++){
        #pragma unroll
        for (int j = 0; j < 4; j++){
          int row = bm + wr*32 + mi*16 + lk*4 + j;
          int col = bn0 + t*64 + wc*32 + ni*16 + lr;
          float v = acc[t][mi][ni][j];
          if (EPI == 0){
            if (bias) v += bias[col];
            ((float*)Cv)[(size_t)row*N + col] = v;
          } else if (EPI == 1){
            if (bias) v += bias[col];
            ((float*)Cv)[(size_t)row*N + col] = siluf(v);
          } else if (EPI == 2){
            ((float*)Cv)[(size_t)row*N + col] += v;
          } else if (EPI == 3){
            int n = row / 29, kr = row - n*29;
            ((float*)Cv)[((size_t)n*49 + c_res[kr])*128 + col] += v;
          } else if (EPI == 4){
            ((float*)Cv)[(size_t)row*N + col] = 1.f/(1.f + expf(-v));
          } else if (EPI == 5){
            float g = P0[(size_t)(row/49)*N + col];
            ((u16*)Cv)[(size_t)row*N + col] = f2bf(v*g);
          } else if (EPI == 6){
            ((u16*)Cv)[(size_t)row*N + col] = f2bf(v);
          } else {
            int p = e0 + row/29;
            int e = eidp[p];
            float a = ALp[e*8 + (col >> 4)];
            ((u16*)Cv)[(size_t)row*N + col] = f2bf(v*a);
          }
        }
      }
    }
  }
}

// ---------------- fused FFN, 8-wave M=128: X += ((bf16(A@W1)*gate)@W2) ----------------
// A: Hbw [NN*49][128] bf16. W1: [512][128] bf16. W2: [128][512] bf16. SG: [NN][512] f32.
// 80 KB LDS, 512 threads -> 2 blocks/CU = 16 waves/CU. Bit-identical math to the
// two-GEMM chain (same chunk order, same per-element MFMA K-sequence, same rounding).
__global__ __launch_bounds__(512) void k_ffn(
    const u16* __restrict__ A, const u16* __restrict__ W1, const u16* __restrict__ W2,
    const float* __restrict__ SGp, float* __restrict__ Xp)
{
  __shared__ __align__(16) u16 Asl[128*128];  // 32 KB
  __shared__ __align__(16) u16 W1s[64*128];   // 16 KB
  __shared__ __align__(16) u16 W2s[128*64];   // 16 KB
  __shared__ __align__(16) u16 Hs[128*64];    // 16 KB
  int tid = threadIdx.x;
  int bm = blockIdx.x*128;
  int wid = tid >> 6, lane = tid & 63;
  int wr = wid >> 1, wc = wid & 1;           // wr 0..3 (rows), wc 0..1 (cols)
  int lr = lane & 15, lk = lane >> 4;
  for (int g = tid; g < 2048; g += 512){
    int row = g >> 4, kg = g & 15;
    *(uint4*)&Asl[row*128 + ((kg*8) ^ ((row & 7)*16))] = *(const uint4*)&A[(size_t)(bm + row)*128 + kg*8];
  }
  fvec4 o[2][4] = {};
  for (int h0 = 0; h0 < 512; h0 += 64){
    for (int g = tid; g < 1024; g += 512){
      int row = g >> 4, kg = g & 15;
      *(uint4*)&W1s[row*128 + ((kg*8) ^ ((row & 7)*16))] = *(const uint4*)&W1[(size_t)(h0 + row)*128 + kg*8];
    }
    for (int g = tid; g < 1024; g += 512){
      int row = g >> 3, kg = g & 7;
      *(uint4*)&W2s[row*64 + ((kg*8) ^ ((row & 7)*8))] = *(const uint4*)&W2[(size_t)row*512 + h0 + kg*8];
    }
    __syncthreads();
    // GEMM1: per wave 32 rows x 32 hidden cols, K=128
    fvec4 hid[2][2] = {};
    #pragma unroll
    for (int kk = 0; kk < 4; kk++){
      int kg = kk*4 + lk;
      bhalf8 af[2], bf[2];
      #pragma unroll
      for (int mi = 0; mi < 2; mi++){
        int ar = wr*32 + mi*16 + lr;
        af[mi] = *(const bhalf8*)&Asl[ar*128 + ((kg*8) ^ ((ar & 7)*16))];
      }
      #pragma unroll
      for (int ni = 0; ni < 2; ni++){
        int br = wc*32 + ni*16 + lr;
        bf[ni] = *(const bhalf8*)&W1s[br*128 + ((kg*8) ^ ((br & 7)*16))];
      }
      #pragma unroll
      for (int mi = 0; mi < 2; mi++)
        #pragma unroll
        for (int ni = 0; ni < 2; ni++)
          hid[mi][ni] = __builtin_amdgcn_mfma_f32_16x16x32_bf16(af[mi], bf[ni], hid[mi][ni], 0, 0, 0);
    }
    // gate + bf16 round -> Hs
    #pragma unroll
    for (int mi = 0; mi < 2; mi++){
      #pragma unroll
      for (int j = 0; j < 4; j++){
        int row = wr*32 + mi*16 + lk*4 + j;
        int node = (bm + row)/49;
        const float* sgrow = &SGp[(size_t)node*512 + h0];
        #pragma unroll
        for (int ni = 0; ni < 2; ni++){
          int col = wc*32 + ni*16 + lr;
          Hs[row*64 + (col ^ ((row & 7)*8))] = f2bf(hid[mi][ni][j]*sgrow[col]);
        }
      }
    }
    __syncthreads();
    // GEMM2: per wave 32 rows x 64 out cols, K=64 this chunk
    #pragma unroll
    for (int kk2 = 0; kk2 < 2; kk2++){
      int kg = kk2*4 + lk;
      bhalf8 af2[2], bf2[4];
      #pragma unroll
      for (int mi = 0; mi < 2; mi++){
        int ar = wr*32 + mi*16 + lr;
        af2[mi] = *(const bhalf8*)&Hs[ar*64 + ((kg*8) ^ ((ar & 7)*8))];
      }
      #pragma unroll
      for (int ni = 0; ni < 4; ni++){
        int br = wc*64 + ni*16 + lr;
        bf2[ni] = *(const bhalf8*)&W2s[br*64 + ((kg*8) ^ ((br & 7)*8))];
      }
      #pragma unroll
      for (int mi = 0; mi < 2; mi++)
        #pragma unroll
        for (int ni = 0; ni < 4; ni++)
          o[mi][ni] = __builtin_amdgcn_mfma_f32_16x16x32_bf16(af2[mi], bf2[ni], o[mi][ni], 0, 0, 0);
    }
    __syncthreads();
  }
  #pragma unroll
  for (int mi = 0; mi < 2; mi++)
    #pragma unroll
    for (int ni = 0; ni < 4; ni++)
      #pragma unroll
      for (int j = 0; j < 4; j++){
        int row = bm + wr*32 + mi*16 + lk*4 + j;
        int col = wc*64 + ni*16 + lr;
        Xp[(size_t)row*128 + col] += o[mi][ni][j];
      }
}

// ---------------- contiguous segment-sum of permuted VS rows (vectorized) ----------------
__global__ __launch_bounds__(256) void k_aggseg(const u16* __restrict__ VS, const int* __restrict__ rowptr,
                                                int p0, int p1, int first, float* __restrict__ agg){
  int n = blockIdx.x;
  int a = rowptr[n], b = rowptr[n+1];
  if (a < p0) a = p0;
  if (b > p1) b = p1;
  int tid = threadIdx.x;
  for (int g = tid; g < 464; g += 256){          // 29*128/8 = 464 groups of 8
    size_t obase = (size_t)n*29*128 + (size_t)g*8;
    float s[8];
    if (first){
      #pragma unroll
      for (int j = 0; j < 8; j++) s[j] = 0.f;
    } else {
      float4 lo = *(const float4*)&agg[obase];
      float4 hi = *(const float4*)&agg[obase + 4];
      s[0]=lo.x; s[1]=lo.y; s[2]=lo.z; s[3]=lo.w;
      s[4]=hi.x; s[5]=hi.y; s[6]=hi.z; s[7]=hi.w;
    }
    for (int p = a; p < b; p++){
      uint4 q = *(const uint4*)&VS[(size_t)(p - p0)*3712 + (size_t)g*8];
      const u16* qp = (const u16*)&q;
      #pragma unroll
      for (int j = 0; j < 8; j++) s[j] += bf2f(qp[j]);
    }
    float4 lo, hi;
    lo.x=s[0]; lo.y=s[1]; lo.z=s[2]; lo.w=s[3];
    hi.x=s[4]; hi.y=s[5]; hi.z=s[6]; hi.w=s[7];
    *(float4*)&agg[obase] = lo;
    *(float4*)&agg[obase + 4] = hi;
  }
}

// ---------------- node init ----------------
__global__ __launch_bounds__(128) void k_init(const float* __restrict__ pos, const float* __restrict__ table,
                                              const float* __restrict__ Yb, const float* __restrict__ radd,
                                              const int* __restrict__ rowptr, const int* __restrict__ eid,
                                              float* __restrict__ x){
  int n = blockIdx.x;
  int c = threadIdx.x;
  const float DLO = -3.26267f;
  const float DRG = (float)(3.295396 - (-3.26267));
  float p0 = pos[n*3+0], p1 = pos[n*3+1], p2 = pos[n*3+2];
  int t0 = min(127, max(0, (int)rintf((p0 - DLO)/DRG*128.f - 0.5f)));
  int t1 = min(127, max(0, (int)rintf((p1 - DLO)/DRG*128.f - 0.5f)));
  int t2 = min(127, max(0, (int)rintf((p2 - DLO)/DRG*128.f - 0.5f)));
  float emb = table[t0*CD + c] + table[t1*CD + c] + table[t2*CD + c];
  __shared__ float Yl[49];
  __shared__ float rl[896];
  float acc[NCO];
  #pragma unroll
  for (int k = 0; k < NCO; k++) acc[k] = 0.f;
  int pA = rowptr[n], pB = rowptr[n+1];
  for (int p = pA; p < pB; p++){
    int e = eid[p];
    if (c < 49) Yl[c] = Yb[(size_t)e*49 + c];
    #pragma unroll
    for (int q = 0; q < 7; q++) rl[q*128 + c] = radd[(size_t)e*896 + q*128 + c];
    __syncthreads();
    #pragma unroll
    for (int k = 0; k < NCO; k++){
      acc[k] += Yl[k]*rl[deg_of(k)*128 + c];
    }
    __syncthreads();
  }
  size_t base = (size_t)n*NCO*CD;
  x[base + c] = emb + acc[0]*(1.f/3.f);
  #pragma unroll
  for (int k = 1; k < NCO; k++) x[base + k*CD + c] = acc[k]*(1.f/3.f);
}

// ---------------- degree-grouped RMS norm, bf16 out (full 49 rows, for FFN) ----------------
__global__ __launch_bounds__(128) void k_rmsnorm(const float* __restrict__ x, const float* __restrict__ w,
                                                 u16* __restrict__ out){
  int n = blockIdx.x;
  int c = threadIdx.x;
  const float* xb = x + (size_t)n*NCO*CD;
  float vals[NCO];
  float ss[7] = {0,0,0,0,0,0,0};
  #pragma unroll
  for (int k = 0; k < NCO; k++){
    float v = xb[k*CD + c];
    vals[k] = v;
    ss[deg_of(k)] += v*v;
  }
  __shared__ float red[7][128];
  #pragma unroll
  for (int l = 0; l < 7; l++) red[l][c] = ss[l];
  __syncthreads();
  __shared__ float inv[7];
  if (c < 7){
    float s = 0.f;
    for (int i = 0; i < 128; i++) s += red[c][i];
    float ms = s / ((float)(2*c + 1)*128.f);
    inv[c] = 1.f / sqrtf(ms + 1e-6f);
  }
  __syncthreads();
  size_t base = (size_t)n*NCO*CD;
  #pragma unroll
  for (int k = 0; k < NCO; k++){
    int l = deg_of(k);
    out[base + k*CD + c] = f2bf(vals[k]*inv[l]*w[l*CD + c]);
  }
}

// ---------------- RMS norm writing restricted 29 rows, bf16 out ----------------
__global__ __launch_bounds__(128) void k_rmsnormR(const float* __restrict__ x, const float* __restrict__ w,
                                                  u16* __restrict__ hr){
  int n = blockIdx.x;
  int c = threadIdx.x;
  const float* xb = x + (size_t)n*NCO*CD;
  float vals[NCO];
  float ss[7] = {0,0,0,0,0,0,0};
  #pragma unroll
  for (int k = 0; k < NCO; k++){
    float v = xb[k*CD + c];
    vals[k] = v;
    ss[deg_of(k)] += v*v;
  }
  __shared__ float red[7][128];
  #pragma unroll
  for (int l = 0; l < 7; l++) red[l][c] = ss[l];
  __syncthreads();
  __shared__ float inv[7];
  if (c < 7){
    float s = 0.f;
    for (int i = 0; i < 128; i++) s += red[c][i];
    float ms = s / ((float)(2*c + 1)*128.f);
    inv[c] = 1.f / sqrtf(ms + 1e-6f);
  }
  __syncthreads();
  size_t base = (size_t)n*NRr*CD;
  #pragma unroll
  for (int kr = 0; kr < NRr; kr++){
    int k = d_RES[kr];
    int l = deg_of(k);
    hr[base + kr*CD + c] = f2bf(vals[k]*inv[l]*w[l*CD + c]);
  }
}

// ---------------- fused attention: logits + segment softmax + alpha ----------------
__global__ __launch_bounds__(256) void k_attn(
    const u16* __restrict__ XST, const float* __restrict__ rad, const float* __restrict__ avec,
    const int* __restrict__ src, const int* __restrict__ rowptr, const int* __restrict__ eid,
    float* __restrict__ AL)
{
  int n = blockIdx.x;
  int p0 = rowptr[n], p1 = rowptr[n+1];
  int deg = p1 - p0;
  if (deg == 0) return;
  __shared__ float lgs[64][8];
  __shared__ float xt0[128];
  __shared__ float av[128];
  __shared__ float mxs[8], dens[8];
  int tid = threadIdx.x;
  if (tid < 128){
    xt0[tid] = bf2f(XST[(size_t)n*NRr*256 + 128 + tid]);
    av[tid] = avec[tid];
  }
  __syncthreads();
  for (int pair = tid; pair < deg*8; pair += 256){
    int pl = pair >> 3, h = pair & 7;
    int e = eid[p0 + pl];
    int s = src[e];
    const u16* xs = &XST[(size_t)s*NRr*256 + h*16];
    uint4 q0 = *(const uint4*)xs;
    uint4 q1 = *(const uint4*)(xs + 8);
    const u16* x0 = (const u16*)&q0;
    const u16* x1 = (const u16*)&q1;
    const float* rd = &rad[(size_t)e*128 + h*16];
    float4 r0 = *(const float4*)(rd + 0);
    float4 r1 = *(const float4*)(rd + 4);
    float4 r2 = *(const float4*)(rd + 8);
    float4 r3 = *(const float4*)(rd + 12);
    float rr[16] = {r0.x,r0.y,r0.z,r0.w, r1.x,r1.y,r1.z,r1.w,
                    r2.x,r2.y,r2.z,r2.w, r3.x,r3.y,r3.z,r3.w};
    float acc = 0.f;
    #pragma unroll
    for (int d = 0; d < 8; d++){
      float m = (bf2f(x0[d]) + xt0[h*16 + d]) * rr[d];
      acc += siluf(m) * av[h*16 + d];
    }
    #pragma unroll
    for (int d = 0; d < 8; d++){
      float m = (bf2f(x1[d]) + xt0[h*16 + 8 + d]) * rr[8 + d];
      acc += siluf(m) * av[h*16 + 8 + d];
    }
    lgs[pl][h] = acc;
  }
  __syncthreads();
  if (tid < 8){
    float m = -1e30f;
    for (int pl = 0; pl < deg; pl++) m = fmaxf(m, lgs[pl][tid]);
    float sden = 0.f;
    for (int pl = 0; pl < deg; pl++) sden += expf(lgs[pl][tid] - m);
    mxs[tid] = m; dens[tid] = sden;
  }
  __syncthreads();
  for (int pair = tid; pair < deg*8; pair += 256){
    int pl = pair >> 3, h = pair & 7;
    int e = eid[p0 + pl];
    AL[e*8 + h] = expf(lgs[pl][h] - mxs[h]) / fmaxf(dens[h], 1e-9f);
  }
}

// ---------------- pooling ----------------
__global__ void k_pool(const float* __restrict__ orr, const int* __restrict__ gs, float* __restrict__ out){
  int i = blockIdx.x*blockDim.x + threadIdx.x;
  if (i >= NG*NCO*CD) return;
  int c = i & 127;
  int k = (i >> 7) % 49;
  int g = i / (49*128);
  int kr = c_rinv[k];
  float v = 0.f;
  if (kr >= 0){
    int a = gs[g], b = gs[g+1];
    float s = 0.f;
    for (int n = a; n < b; n++) s += orr[((size_t)n*29 + kr)*128 + c];
    int cnt = b - a;
    v = s / (float)(cnt > 0 ? cnt : 1);
  }
  out[i] = v;
}

extern "C" void kernel_launch(void* const* d_in, const int* in_sizes, int n_in,
                              void* d_out, int out_size, void* d_ws, size_t ws_size,
                              hipStream_t stream){
  const float* pos    = (const float*)d_in[0];
  const float* evec   = (const float*)d_in[1];
  const int*   eidx   = (const int*)  d_in[2];
  const int*   batch  = (const int*)  d_in[3];
  const float* table  = (const float*)d_in[4];
  const float* deg_w1 = (const float*)d_in[5];
  const float* deg_b1 = (const float*)d_in[6];
  const float* deg_w2 = (const float*)d_in[7];
  const float* deg_b2 = (const float*)d_in[8];
  const float* deg_w3 = (const float*)d_in[9];
  const float* attn_nw= (const float*)d_in[10];
  const float* w_src  = (const float*)d_in[11];
  const float* w_tgt  = (const float*)d_in[12];
  const float* rad_w1 = (const float*)d_in[13];
  const float* rad_b1 = (const float*)d_in[14];
  const float* rad_w2 = (const float*)d_in[15];
  const float* avec   = (const float*)d_in[16];
  const float* w_val  = (const float*)d_in[17];
  const float* w_proj = (const float*)d_in[18];
  const float* ffn_nw = (const float*)d_in[19];
  const float* ffn_w1 = (const float*)d_in[20];
  const float* ffn_w2 = (const float*)d_in[21];
  const float* fin_nw = (const float*)d_in[22];
  const float* lw_src = (const float*)d_in[23];
  const float* lw_tgt = (const float*)d_in[24];
  const float* lrad_w1= (const float*)d_in[25];
  const float* lrad_b1= (const float*)d_in[26];
  const float* lrad_w2= (const float*)d_in[27];
  const float* lavec  = (const float*)d_in[28];
  const float* lw_val = (const float*)d_in[29];
  const float* lw_proj= (const float*)d_in[30];

  const int* srcp = eidx;
  const int* dstp = eidx + NE;

  float* W = (float*)d_ws;
  size_t o = 0;
  float* X    = W + o; o += (size_t)NN*49*128;
  float* Hb   = W + o; o += (size_t)NN*49*128;   // RADD, VS chunks, latent proj out, FFN rmsnorm(bf16)
  float* HR   = W + o; o += (size_t)NN*29*128;   // rmsnormR(bf16) out, AG
  float* XSTf = W + o; o += (size_t)NN*29*256/2; // XST bf16 region (u16)
  float* R1   = W + o; o += (size_t)NE*128;
  float* R2   = W + o; o += (size_t)NE*128;
  float* Yb   = W + o; o += (size_t)NE*49;
  float* DV   = W + o; o += (size_t)NE;
  float* LG   = W + o; o += (size_t)NE*8;
  float* AL   = W + o; o += (size_t)NE*8;
  float* MX   = W + o; o += (size_t)NN*8;
  float* DEN  = W + o; o += (size_t)NN*8;
  float* SG   = W + o; o += (size_t)NN*512;
  int* CNT = (int*)(W + o); o += NN;
  int* RP  = (int*)(W + o); o += NN + 1;
  int* EID = (int*)(W + o); o += NE;
  int* GS  = (int*)(W + o); o += NG + 1;
  int* CH  = (int*)(W + o); o += 4*NN;
  // bf16 transposed weights
  u16* WB = (u16*)(W + o);
  size_t wo = 0;
  u16* T_degw2 = WB + wo; wo += 16384;
  u16* T_degw3 = WB + wo; wo += 114688;
  u16* T_wst[3]; u16* T_wv[3]; u16* T_wp[3]; u16* T_rw2[3];
  for (int i = 0; i < 3; i++){ T_wst[i] = WB + wo; wo += 32768; }   // [256][128]
  for (int i = 0; i < 3; i++){ T_wv[i] = WB + wo; wo += 16384; }
  for (int i = 0; i < 3; i++){ T_wp[i] = WB + wo; wo += 16384; }
  for (int i = 0; i < 3; i++){ T_rw2[i] = WB + wo; wo += 16384; }
  u16* T_f1[2]; u16* T_f2[2];
  for (int i = 0; i < 2; i++){ T_f1[i] = WB + wo; wo += 65536; }
  for (int i = 0; i < 2; i++){ T_f2[i] = WB + wo; wo += 65536; }
  (void)ws_size; (void)in_sizes; (void)n_in; (void)out_size; (void)LG; (void)MX; (void)DEN;

  u16*  XSTw = (u16*)XSTf;                        // [NN][29][256] bf16
  u16*  HRw  = (u16*)HR;                          // rmsnormR bf16 out
  u16*  Hbw  = (u16*)Hb;                          // FFN rmsnorm bf16 out (first half of Hb)
  float* RADD = Hb;                               // E*896 <= Hb; free before layers
  u16*  VS    = (u16*)Hb;                         // VCH_E*29*128 u16 <= Hb
  float* AG   = HR;
  float* OR_  = Hb;                               // latent proj out (after aggseg done)

  // ---- all weight casts in one launch ----
  {
    CastJobs J;
    int idx = 0, acc = 0;
    auto add = [&](const float* s, u16* d, int K, int N){
      J.src[idx] = s; J.dst[idx] = d; J.K[idx] = K; J.N[idx] = N; J.start[idx] = acc;
      acc += K*N; idx++;
    };
    add(deg_w2, T_degw2, 128, 128);
    add(deg_w3, T_degw3, 128, 896);
    for (int i = 0; i < 3; i++){
      add((i < 2) ? w_src  + (size_t)i*16384 : lw_src,  T_wst[i],          128, 128);
      add((i < 2) ? w_tgt  + (size_t)i*16384 : lw_tgt,  T_wst[i] + 16384,  128, 128);
      add((i < 2) ? w_val  + (size_t)i*16384 : lw_val,  T_wv[i], 128, 128);
      add((i < 2) ? w_proj + (size_t)i*16384 : lw_proj, T_wp[i], 128, 128);
      add((i < 2) ? rad_w2 + (size_t)i*16384 : lrad_w2, T_rw2[i], 128, 128);
    }
    for (int i = 0; i < 2; i++){
      add(ffn_w1 + (size_t)i*65536, T_f1[i], 128, 512);
      add(ffn_w2 + (size_t)i*65536, T_f2[i], 512, 128);
    }
    J.start[idx] = acc; J.total = acc;
    k_castall<<<(acc + 255)/256, 256, 0, stream>>>(J);
  }

  // CSR + groups
  k_hist4<<<1, 1024, 0, stream>>>(dstp, CNT, CH);
  k_scan2<<<1, 1024, 0, stream>>>(CNT, RP);
  k_fillw4<<<NN, 256, 0, stream>>>(dstp, RP, CH, EID);
  k_gstart<<<1, 32, 0, stream>>>(batch, GS);

  // geometry
  k_geom<<<48, 256, 0, stream>>>(evec, Yb, DV);

  // degree embedding MLP: 600->128 (silu) -> 128 (silu) -> 896
  k_rad1<<<NE, 128, 0, stream>>>(DV, deg_w1, deg_b1, R1);
  k_mgemm<0,1,2><<<dim3(1, NE/64), 256, 0, stream>>>(R1, T_degw2, deg_b2, R2, NE, 128, 128, 128,
                                                     nullptr, nullptr, nullptr, nullptr, nullptr, 0);
  k_mgemm<0,0,2><<<dim3(7, NE/64), 256, 0, stream>>>(R2, T_degw3, nullptr, RADD, NE, 896, 128, 128,
                                                     nullptr, nullptr, nullptr, nullptr, nullptr, 0);
  k_init<<<NN, 128, 0, stream>>>(pos, table, Yb, RADD, RP, EID, X);

  for (int i = 0; i < 3; i++){
    const float* nw  = (i < 2) ? attn_nw + (size_t)i*896   : fin_nw;
    const float* rw1 = (i < 2) ? rad_w1 + (size_t)i*76800 : lrad_w1;
    const float* rb1 = (i < 2) ? rad_b1 + (size_t)i*128   : lrad_b1;
    const float* av  = (i < 2) ? avec   + (size_t)i*128   : lavec;

    k_rmsnormR<<<NN, 128, 0, stream>>>(X, nw, HRw);
    // combined XS|XT projection, bf16 output
    k_mgemm<2,6,4><<<dim3(1, NN*NRr/64), 256, 0, stream>>>(HRw, T_wst[i], nullptr, XSTw, NN*NRr, 256, 128, 128,
                                                           nullptr, nullptr, nullptr, nullptr, nullptr, 0);
    k_rad1<<<NE, 128, 0, stream>>>(DV, rw1, rb1, R1);
    k_mgemm<0,0,2><<<dim3(1, NE/64), 256, 0, stream>>>(R1, T_rw2[i], nullptr, R2, NE, 128, 128, 128,
                                                       nullptr, nullptr, nullptr, nullptr, nullptr, 0);
    // fused logits + softmax + alpha
    k_attn<<<NN, 256, 0, stream>>>(XSTw, R2, av, srcp, RP, EID, AL);
    // V in CSR-permuted order, alpha-fused epilogue, then contiguous segment-sum
    for (int ch = 0; ch < NE/VCH_E; ch++){
      int p0 = ch*VCH_E;
      k_mgemm<3,7,2><<<dim3(1, VCH_E*NRr/64), 256, 0, stream>>>(R2, T_wv[i], nullptr, VS,
                                                                VCH_E*NRr, 128, 128, 128,
                                                                (const float*)XSTw, srcp, dstp, EID, AL, p0);
      k_aggseg<<<NN, 256, 0, stream>>>(VS, RP, p0, p0 + VCH_E, ch == 0, AG);
    }
    if (i < 2){
      // projection with fused scatter-accumulate into X
      k_mgemm<0,3,2><<<dim3(1, NN*NRr/64), 256, 0, stream>>>(AG, T_wp[i], nullptr, X, NN*NRr, 128, 128, 128,
                                                             nullptr, nullptr, nullptr, nullptr, nullptr, 0);
      // FFN: gate from row0, hidden kept in LDS (fused GEMM1+gate+GEMM2, 8-wave M=128)
      k_rmsnorm<<<NN, 128, 0, stream>>>(X, ffn_nw + (size_t)i*896, Hbw);
      k_mgemm<2,4,1><<<dim3(8, NN/64), 256, 0, stream>>>(Hbw, T_f1[i], nullptr, SG, NN, 512, 128, NCO*CD,
                                                         nullptr, nullptr, nullptr, nullptr, nullptr, 0);
      k_ffn<<<NN*NCO/128, 512, 0, stream>>>(Hbw, T_f1[i], T_f2[i], SG, X);
    } else {
      k_mgemm<0,0,2><<<dim3(1, NN*NRr/64), 256, 0, stream>>>(AG, T_wp[i], nullptr, OR_, NN*NRr, 128, 128, 128,
                                                             nullptr, nullptr, nullptr, nullptr, nullptr, 0);
      k_pool<<<(NG*NCO*CD + 255)/256, 256, 0, stream>>>(OR_, GS, (float*)d_out);
    }
  }
}

// Round 19
// 927.276 us; speedup vs baseline: 1.1413x; 1.0078x over previous
//
#include <hip/hip_runtime.h>
#include <math.h>

#define NN 2048
#define NE 12288
#define NCO 49
#define NRr 29
#define CD 128
#define NG 16
#define NJOBS 21
#define VCH_E 6144   // edges per V chunk (permuted positions)

typedef unsigned short u16;
typedef short bhalf8 __attribute__((ext_vector_type(8)));
typedef float fvec4 __attribute__((ext_vector_type(4)));

// RESTRICT: indices k (0..48) with |m|<=2.
__constant__ int c_res[29] = {0,1,2,3,4,5,6,7,8,10,11,12,13,14,18,19,20,21,22,28,29,30,31,32,40,41,42,43,44};
__constant__ int c_rinv[49] = {0,1,2,3,4,5,6,7,8,-1,9,10,11,12,13,-1,-1,-1,14,15,16,17,18,-1,-1,-1,-1,-1,19,20,21,22,23,-1,-1,-1,-1,-1,-1,-1,24,25,26,27,28,-1,-1,-1,-1};
__device__ constexpr int d_RES[29] = {0,1,2,3,4,5,6,7,8,10,11,12,13,14,18,19,20,21,22,28,29,30,31,32,40,41,42,43,44};

__device__ __forceinline__ constexpr int deg_of(int k){
  return (k<1)?0:(k<4)?1:(k<9)?2:(k<16)?3:(k<25)?4:(k<36)?5:6;
}
__device__ __forceinline__ float siluf(float x){ return x / (1.f + expf(-x)); }
__device__ __forceinline__ u16 f2bf(float f){
  unsigned int u = __float_as_uint(f);
  unsigned int r = (u + 0x7FFFu + ((u >> 16) & 1u)) >> 16;
  return (u16)r;
}
__device__ __forceinline__ float bf2f(u16 b){
  return __uint_as_float(((unsigned int)b) << 16);
}
__device__ __forceinline__ unsigned int pk(u16 lo, u16 hi){ return (unsigned int)lo | ((unsigned int)hi << 16); }

// ---------------- CSR build (deterministic, parallel) ----------------
__global__ __launch_bounds__(1024) void k_hist4(const int* __restrict__ dst, int* __restrict__ cnt,
                                                int* __restrict__ CH){
  __shared__ int h[4*NN];
  for (int i = threadIdx.x; i < 4*NN; i += 1024) h[i] = 0;
  __syncthreads();
  const int QE = NE/4;
  for (int e = threadIdx.x; e < NE; e += 1024){
    int q = e / QE;
    atomicAdd(&h[q*NN + dst[e]], 1);
  }
  __syncthreads();
  for (int n = threadIdx.x; n < NN; n += 1024){
    int s = 0;
    #pragma unroll
    for (int q = 0; q < 4; q++){ int v = h[q*NN + n]; CH[q*NN + n] = v; s += v; }
    cnt[n] = s;
  }
}
__global__ __launch_bounds__(1024) void k_scan2(const int* __restrict__ cnt, int* __restrict__ rowptr){
  __shared__ int a[NN], b[NN];
  int t = threadIdx.x;
  for (int i = t; i < NN; i += 1024) a[i] = cnt[i];
  __syncthreads();
  int* pin = a; int* pout = b;
  for (int off = 1; off < NN; off <<= 1){
    for (int i = t; i < NN; i += 1024)
      pout[i] = pin[i] + ((i >= off) ? pin[i - off] : 0);
    __syncthreads();
    int* tmp = pin; pin = pout; pout = tmp;
  }
  for (int i = t; i < NN; i += 1024) rowptr[i + 1] = pin[i];
  if (t == 0) rowptr[0] = 0;
}
__global__ __launch_bounds__(256) void k_fillw4(const int* __restrict__ dst, const int* __restrict__ rowptr,
                                                const int* __restrict__ CH, int* __restrict__ eid){
  int q = threadIdx.x >> 6, lane = threadIdx.x & 63;
  int n = blockIdx.x;
  int base = rowptr[n];
  for (int qq = 0; qq < q; qq++) base += CH[qq*NN + n];
  const int QE = NE/4;
  for (int e0 = q*QE; e0 < (q+1)*QE; e0 += 64){
    int e = e0 + lane;
    bool m = (dst[e] == n);
    unsigned long long mask = __ballot(m);
    if (m) eid[base + __popcll(mask & ((1ull << lane) - 1ull))] = e;
    base += __popcll(mask);
  }
}
__global__ void k_gstart(const int* __restrict__ batch, int* __restrict__ gs){
  int g = threadIdx.x;
  if (g > NG) return;
  int lo = 0, hi = NN;
  while (lo < hi){ int mid = (lo + hi) >> 1; if (batch[mid] < g) lo = mid + 1; else hi = mid; }
  gs[g] = lo;
}

// ---------------- all weight casts in one launch: [K][N] f32 -> [N][K] bf16 ----------------
struct CastJobs {
  const float* src[NJOBS];
  u16* dst[NJOBS];
  int K[NJOBS], N[NJOBS];
  int start[NJOBS + 1];
  int total;
};
__global__ void k_castall(CastJobs J){
  int i = blockIdx.x*blockDim.x + threadIdx.x;
  if (i >= J.total) return;
  int j = 0;
  while (i >= J.start[j + 1]) j++;
  int local = i - J.start[j];
  int K = J.K[j], N = J.N[j];
  int n = local / K, k = local - n*K;
  J.dst[j][local] = f2bf(J.src[j][(size_t)k*N + n]);
}

// ---------------- geometry ----------------
__global__ void k_geom(const float* __restrict__ ev, float* __restrict__ Y, float* __restrict__ dv){
  int e = blockIdx.x*blockDim.x + threadIdx.x;
  if (e >= NE) return;
  float x = ev[e*3+0], y = ev[e*3+1], z = ev[e*3+2];
  float r = sqrtf(x*x + y*y + z*z);
  dv[e] = r;
  float rn = fmaxf(r, 1e-8f);
  float ux = x/rn, uy = y/rn, uz = z/rn;
  float ct = fminf(fmaxf(uz, -1.f), 1.f);
  float st = sqrtf(fminf(fmaxf(1.f - ct*ct, 1e-12f), 1.f));
  float phi = atan2f(uy, ux);
  float P[7][7];
  P[0][0] = 1.f;
  #pragma unroll
  for (int m = 1; m <= 6; m++) P[m][m] = -(2.f*m - 1.f)*st*P[m-1][m-1];
  #pragma unroll
  for (int m = 0; m <= 5; m++) P[m+1][m] = (2.f*m + 1.f)*ct*P[m][m];
  #pragma unroll
  for (int m = 0; m <= 6; m++){
    #pragma unroll
    for (int l = m+2; l <= 6; l++)
      P[l][m] = ((2.f*l - 1.f)*ct*P[l-1][m] - (float)(l+m-1)*P[l-2][m]) / (float)(l-m);
  }
  float cmv[7], smv[7];
  #pragma unroll
  for (int m = 0; m <= 6; m++){ cmv[m] = cosf((float)m*phi); smv[m] = sinf((float)m*phi); }
  const double FOURPI = 12.566370614359172;
  int k = 0;
  #pragma unroll
  for (int l = 0; l <= 6; l++){
    #pragma unroll
    for (int mm = -l; mm <= l; mm++){
      int am = mm < 0 ? -mm : mm;
      double ratio = 1.0;
      for (int i = l-am+1; i <= l+am; i++) ratio /= (double)i;
      double nrm = sqrt((2.0*l + 1.0)/FOURPI*ratio);
      float v;
      if (mm == 0)      v = (float)nrm * P[l][0];
      else if (mm > 0)  v = (float)(1.4142135623730951*nrm) * P[l][am] * cmv[am];
      else              v = (float)(1.4142135623730951*nrm) * P[l][am] * smv[am];
      Y[(size_t)e*49 + k] = v; k++;
    }
  }
}

// ------------- layer-1 of radial MLPs (windowed gaussian, exact) -------------
__global__ __launch_bounds__(128) void k_rad1(const float* __restrict__ dv, const float* __restrict__ Wm,
                                              const float* __restrict__ bias, float* __restrict__ out){
  int e = blockIdx.x;
  int j = threadIdx.x;
  float d = dv[e];
  const float STEPF = (float)(5.0/599.0);
  const double step_d = (double)STEPF;
  const float GC = (float)(-0.5/((2.0*step_d)*(2.0*step_d)));
  __shared__ float g[64];
  int bc = (int)rintf(d / STEPF);
  int b0 = bc - 32;
  if (j < 64){
    int b = b0 + j;
    float gg = 0.f;
    if (b >= 0 && b < 600){
      float off = (float)((double)b * (5.0/599.0));
      float t = d - off;
      gg = expf(GC*t*t);
    }
    g[j] = gg;
  }
  __syncthreads();
  float acc = bias ? bias[j] : 0.f;
  #pragma unroll 8
  for (int i = 0; i < 64; i++){
    int b = b0 + i;
    if (b >= 0 && b < 600) acc += g[i]*Wm[b*CD + j];
  }
  out[(size_t)e*CD + j] = siluf(acc);
}

// ------------- batched layer-1 of the 3 attention radial MLPs -------------
__global__ __launch_bounds__(128) void k_rad1b(const float* __restrict__ dv,
                                               const float* __restrict__ W0, const float* __restrict__ W1,
                                               const float* __restrict__ W2,
                                               const float* __restrict__ b0p, const float* __restrict__ b1p,
                                               const float* __restrict__ b2p,
                                               float* __restrict__ out){
  int e = blockIdx.x;
  int l = blockIdx.y;
  int j = threadIdx.x;
  const float* Wm = (l == 0) ? W0 : (l == 1) ? W1 : W2;
  const float* bias = (l == 0) ? b0p : (l == 1) ? b1p : b2p;
  float d = dv[e];
  const float STEPF = (float)(5.0/599.0);
  const double step_d = (double)STEPF;
  const float GC = (float)(-0.5/((2.0*step_d)*(2.0*step_d)));
  __shared__ float g[64];
  int bc = (int)rintf(d / STEPF);
  int b0 = bc - 32;
  if (j < 64){
    int b = b0 + j;
    float gg = 0.f;
    if (b >= 0 && b < 600){
      float off = (float)((double)b * (5.0/599.0));
      float t = d - off;
      gg = expf(GC*t*t);
    }
    g[j] = gg;
  }
  __syncthreads();
  float acc = bias[j];
  #pragma unroll 8
  for (int i = 0; i < 64; i++){
    int b = b0 + i;
    if (b >= 0 && b < 600) acc += g[i]*Wm[b*CD + j];
  }
  out[((size_t)l*NE + e)*CD + j] = siluf(acc);
}

// ---------------- MFMA bf16 GEMM with NT column-tiles per block ----------------
// AMODE: 0 = f32 A (runtime lda); 2 = bf16 A (runtime lda);
//        3 = permuted fused-message A.
// EPI:   0 store(+bias); 1 silu(+bias); 2 accumulate; 3 scatter-accum into X;
//        4 sigmoid store; 5 gate-mul (P0=SG) then bf16 store; 6 bf16 store;
//        7 alpha-scale (ALp, permuted via eidp) then bf16 store (VS).
template<int AMODE, int EPI, int NT>
__global__ __launch_bounds__(256) void k_mgemm(
    const void* __restrict__ Av, const u16* __restrict__ Bt,
    const float* __restrict__ bias, void* __restrict__ Cv,
    int M, int N, int K, int lda,
    const float* __restrict__ P0,
    const int* __restrict__ src, const int* __restrict__ dstp,
    const int* __restrict__ eidp, const float* __restrict__ ALp, int e0)
{
  __shared__ __align__(16) u16 Asl[64*64];
  __shared__ __align__(16) u16 Bsl[NT][64*64];
  int tid = threadIdx.x;
  int bm = blockIdx.y*64;
  int bn0 = blockIdx.x*NT*64;
  int wid = tid >> 6, lane = tid & 63;
  int wr = wid >> 1, wc = wid & 1;
  int lr = lane & 15, lk = lane >> 4;
  fvec4 acc[NT][2][2] = {};
  for (int k0 = 0; k0 < K; k0 += 64){
    #pragma unroll
    for (int h = 0; h < 2; h++){
      int lin = tid + h*256;          // 0..511: 64 rows x 8 k-groups
      int row = lin >> 3, kg = lin & 7;
      uint4 q;
      if (AMODE == 3){
        int gr = bm + row;
        int el = gr / 29, kq = gr - el*29;
        int p = e0 + el;
        int e = eidp[p];
        int s = src[e], t = dstp[e];
        const u16* xst = (const u16*)P0;
        uint4 xs8 = *(const uint4*)&xst[((size_t)s*29 + kq)*256 + k0 + kg*8];
        uint4 xt8 = *(const uint4*)&xst[((size_t)t*29 + kq)*256 + 128 + k0 + kg*8];
        const float* rd = (const float*)Av + (size_t)e*128 + k0 + kg*8;
        const u16* xsp = (const u16*)&xs8;
        const u16* xtp = (const u16*)&xt8;
        u16 ov[8];
        #pragma unroll
        for (int j = 0; j < 8; j++)
          ov[j] = f2bf((bf2f(xsp[j]) + bf2f(xtp[j])) * rd[j]);
        q.x = pk(ov[0], ov[1]); q.y = pk(ov[2], ov[3]);
        q.z = pk(ov[4], ov[5]); q.w = pk(ov[6], ov[7]);
      } else if (AMODE == 2){
        const u16* ap = (const u16*)Av + (size_t)(bm + row)*lda + k0 + kg*8;
        q = *(const uint4*)ap;
      } else {
        const float* ap = (const float*)Av + (size_t)(bm + row)*lda + k0 + kg*8;
        float v[8];
        #pragma unroll
        for (int j = 0; j < 8; j++) v[j] = ap[j];
        q.x = pk(f2bf(v[0]), f2bf(v[1]));
        q.y = pk(f2bf(v[2]), f2bf(v[3]));
        q.z = pk(f2bf(v[4]), f2bf(v[5]));
        q.w = pk(f2bf(v[6]), f2bf(v[7]));
      }
      *(uint4*)&Asl[row*64 + ((kg*8) ^ ((row & 7)*8))] = q;
    }
    #pragma unroll
    for (int t = 0; t < NT; t++){
      #pragma unroll
      for (int h = 0; h < 2; h++){
        int lin = tid + h*256;
        int row = lin >> 3, kg = lin & 7;
        const u16* bp = Bt + (size_t)(bn0 + t*64 + row)*K + k0 + kg*8;
        *(uint4*)&Bsl[t][row*64 + ((kg*8) ^ ((row & 7)*8))] = *(const uint4*)bp;
      }
    }
    __syncthreads();
    #pragma unroll
    for (int ks = 0; ks < 2; ks++){
      int kg = ks*4 + lk;
      bhalf8 af[2];
      #pragma unroll
      for (int mi = 0; mi < 2; mi++){
        int ar = wr*32 + mi*16 + lr;
        af[mi] = *(const bhalf8*)&Asl[ar*64 + ((kg*8) ^ ((ar & 7)*8))];
      }
      #pragma unroll
      for (int t = 0; t < NT; t++){
        bhalf8 bfr[2];
        #pragma unroll
        for (int ni = 0; ni < 2; ni++){
          int br = wc*32 + ni*16 + lr;
          bfr[ni] = *(const bhalf8*)&Bsl[t][br*64 + ((kg*8) ^ ((br & 7)*8))];
        }
        #pragma unroll
        for (int mi = 0; mi < 2; mi++)
          #pragma unroll
          for (int ni = 0; ni < 2; ni++)
            acc[t][mi][ni] = __builtin_amdgcn_mfma_f32_16x16x32_bf16(af[mi], bfr[ni], acc[t][mi][ni], 0, 0, 0);
      }
    }
    __syncthreads();
  }
  #pragma unroll
  for (int t = 0; t < NT; t++){
    #pragma unroll
    for (int mi = 0; mi < 2; mi++){
      #pragma unroll
      for (int ni = 0; ni < 2; ni++){
        #pragma unroll
        for (int j = 0; j < 4; j++){
          int row = bm + wr*32 + mi*16 + lk*4 + j;
          int col = bn0 + t*64 + wc*32 + ni*16 + lr;
          float v = acc[t][mi][ni][j];
          if (EPI == 0){
            if (bias) v += bias[col];
            ((float*)Cv)[(size_t)row*N + col] = v;
          } else if (EPI == 1){
            if (bias) v += bias[col];
            ((float*)Cv)[(size_t)row*N + col] = siluf(v);
          } else if (EPI == 2){
            ((float*)Cv)[(size_t)row*N + col] += v;
          } else if (EPI == 3){
            int n = row / 29, kr = row - n*29;
            ((float*)Cv)[((size_t)n*49 + c_res[kr])*128 + col] += v;
          } else if (EPI == 4){
            ((float*)Cv)[(size_t)row*N + col] = 1.f/(1.f + expf(-v));
          } else if (EPI == 5){
            float g = P0[(size_t)(row/49)*N + col];
            ((u16*)Cv)[(size_t)row*N + col] = f2bf(v*g);
          } else if (EPI == 6){
            ((u16*)Cv)[(size_t)row*N + col] = f2bf(v);
          } else {
            int p = e0 + row/29;
            int e = eidp[p];
            float a = ALp[e*8 + (col >> 4)];
            ((u16*)Cv)[(size_t)row*N + col] = f2bf(v*a);
          }
        }
      }
    }
  }
}

// ---------------- batched radial layer-2 GEMM (z = layer) ----------------
__global__ __launch_bounds__(256) void k_rgemm(
    const float* __restrict__ A, const u16* __restrict__ B0, const u16* __restrict__ B1,
    const u16* __restrict__ B2, float* __restrict__ C)
{
  __shared__ __align__(16) u16 Asl[64*64];
  __shared__ __align__(16) u16 Bsl[2][64*64];
  int tid = threadIdx.x;
  int l = blockIdx.z;
  int bm = blockIdx.y*64;
  const u16* Bt = (l == 0) ? B0 : (l == 1) ? B1 : B2;
  const float* Al = A + (size_t)l*NE*128;
  float* Cl = C + (size_t)l*NE*128;
  int wid = tid >> 6, lane = tid & 63;
  int wr = wid >> 1, wc = wid & 1;
  int lr = lane & 15, lk = lane >> 4;
  fvec4 acc[2][2][2] = {};
  for (int k0 = 0; k0 < 128; k0 += 64){
    #pragma unroll
    for (int h = 0; h < 2; h++){
      int lin = tid + h*256;
      int row = lin >> 3, kg = lin & 7;
      const float* ap = Al + (size_t)(bm + row)*128 + k0 + kg*8;
      float v[8];
      #pragma unroll
      for (int j = 0; j < 8; j++) v[j] = ap[j];
      uint4 q;
      q.x = pk(f2bf(v[0]), f2bf(v[1]));
      q.y = pk(f2bf(v[2]), f2bf(v[3]));
      q.z = pk(f2bf(v[4]), f2bf(v[5]));
      q.w = pk(f2bf(v[6]), f2bf(v[7]));
      *(uint4*)&Asl[row*64 + ((kg*8) ^ ((row & 7)*8))] = q;
    }
    #pragma unroll
    for (int t = 0; t < 2; t++){
      #pragma unroll
      for (int h = 0; h < 2; h++){
        int lin = tid + h*256;
        int row = lin >> 3, kg = lin & 7;
        const u16* bp = Bt + (size_t)(t*64 + row)*128 + k0 + kg*8;
        *(uint4*)&Bsl[t][row*64 + ((kg*8) ^ ((row & 7)*8))] = *(const uint4*)bp;
      }
    }
    __syncthreads();
    #pragma unroll
    for (int ks = 0; ks < 2; ks++){
      int kg = ks*4 + lk;
      bhalf8 af[2];
      #pragma unroll
      for (int mi = 0; mi < 2; mi++){
        int ar = wr*32 + mi*16 + lr;
        af[mi] = *(const bhalf8*)&Asl[ar*64 + ((kg*8) ^ ((ar & 7)*8))];
      }
      #pragma unroll
      for (int t = 0; t < 2; t++){
        bhalf8 bfr[2];
        #pragma unroll
        for (int ni = 0; ni < 2; ni++){
          int br = wc*32 + ni*16 + lr;
          bfr[ni] = *(const bhalf8*)&Bsl[t][br*64 + ((kg*8) ^ ((br & 7)*8))];
        }
        #pragma unroll
        for (int mi = 0; mi < 2; mi++)
          #pragma unroll
          for (int ni = 0; ni < 2; ni++)
            acc[t][mi][ni] = __builtin_amdgcn_mfma_f32_16x16x32_bf16(af[mi], bfr[ni], acc[t][mi][ni], 0, 0, 0);
      }
    }
    __syncthreads();
  }
  #pragma unroll
  for (int t = 0; t < 2; t++)
    #pragma unroll
    for (int mi = 0; mi < 2; mi++)
      #pragma unroll
      for (int ni = 0; ni < 2; ni++)
        #pragma unroll
        for (int j = 0; j < 4; j++){
          int row = bm + wr*32 + mi*16 + lk*4 + j;
          int col = t*64 + wc*32 + ni*16 + lr;
          Cl[(size_t)row*128 + col] = acc[t][mi][ni][j];
        }
}

// ---------------- fused FFN, 8-wave M=128: X += ((bf16(A@W1)*gate)@W2) ----------------
__global__ __launch_bounds__(512) void k_ffn(
    const u16* __restrict__ A, const u16* __restrict__ W1, const u16* __restrict__ W2,
    const float* __restrict__ SGp, float* __restrict__ Xp)
{
  __shared__ __align__(16) u16 Asl[128*128];  // 32 KB
  __shared__ __align__(16) u16 W1s[64*128];   // 16 KB
  __shared__ __align__(16) u16 W2s[128*64];   // 16 KB
  __shared__ __align__(16) u16 Hs[128*64];    // 16 KB
  int tid = threadIdx.x;
  int bm = blockIdx.x*128;
  int wid = tid >> 6, lane = tid & 63;
  int wr = wid >> 1, wc = wid & 1;
  int lr = lane & 15, lk = lane >> 4;
  for (int g = tid; g < 2048; g += 512){
    int row = g >> 4, kg = g & 15;
    *(uint4*)&Asl[row*128 + ((kg*8) ^ ((row & 7)*16))] = *(const uint4*)&A[(size_t)(bm + row)*128 + kg*8];
  }
  fvec4 o[2][4] = {};
  for (int h0 = 0; h0 < 512; h0 += 64){
    for (int g = tid; g < 1024; g += 512){
      int row = g >> 4, kg = g & 15;
      *(uint4*)&W1s[row*128 + ((kg*8) ^ ((row & 7)*16))] = *(const uint4*)&W1[(size_t)(h0 + row)*128 + kg*8];
    }
    for (int g = tid; g < 1024; g += 512){
      int row = g >> 3, kg = g & 7;
      *(uint4*)&W2s[row*64 + ((kg*8) ^ ((row & 7)*8))] = *(const uint4*)&W2[(size_t)row*512 + h0 + kg*8];
    }
    __syncthreads();
    fvec4 hid[2][2] = {};
    #pragma unroll
    for (int kk = 0; kk < 4; kk++){
      int kg = kk*4 + lk;
      bhalf8 af[2], bf[2];
      #pragma unroll
      for (int mi = 0; mi < 2; mi++){
        int ar = wr*32 + mi*16 + lr;
        af[mi] = *(const bhalf8*)&Asl[ar*128 + ((kg*8) ^ ((ar & 7)*16))];
      }
      #pragma unroll
      for (int ni = 0; ni < 2; ni++){
        int br = wc*32 + ni*16 + lr;
        bf[ni] = *(const bhalf8*)&W1s[br*128 + ((kg*8) ^ ((br & 7)*16))];
      }
      #pragma unroll
      for (int mi = 0; mi < 2; mi++)
        #pragma unroll
        for (int ni = 0; ni < 2; ni++)
          hid[mi][ni] = __builtin_amdgcn_mfma_f32_16x16x32_bf16(af[mi], bf[ni], hid[mi][ni], 0, 0, 0);
    }
    #pragma unroll
    for (int mi = 0; mi < 2; mi++){
      #pragma unroll
      for (int j = 0; j < 4; j++){
        int row = wr*32 + mi*16 + lk*4 + j;
        int node = (bm + row)/49;
        const float* sgrow = &SGp[(size_t)node*512 + h0];
        #pragma unroll
        for (int ni = 0; ni < 2; ni++){
          int col = wc*32 + ni*16 + lr;
          Hs[row*64 + (col ^ ((row & 7)*8))] = f2bf(hid[mi][ni][j]*sgrow[col]);
        }
      }
    }
    __syncthreads();
    #pragma unroll
    for (int kk2 = 0; kk2 < 2; kk2++){
      int kg = kk2*4 + lk;
      bhalf8 af2[2], bf2[4];
      #pragma unroll
      for (int mi = 0; mi < 2; mi++){
        int ar = wr*32 + mi*16 + lr;
        af2[mi] = *(const bhalf8*)&Hs[ar*64 + ((kg*8) ^ ((ar & 7)*8))];
      }
      #pragma unroll
      for (int ni = 0; ni < 4; ni++){
        int br = wc*64 + ni*16 + lr;
        bf2[ni] = *(const bhalf8*)&W2s[br*64 + ((kg*8) ^ ((br & 7)*8))];
      }
      #pragma unroll
      for (int mi = 0; mi < 2; mi++)
        #pragma unroll
        for (int ni = 0; ni < 4; ni++)
          o[mi][ni] = __builtin_amdgcn_mfma_f32_16x16x32_bf16(af2[mi], bf2[ni], o[mi][ni], 0, 0, 0);
    }
    __syncthreads();
  }
  #pragma unroll
  for (int mi = 0; mi < 2; mi++)
    #pragma unroll
    for (int ni = 0; ni < 4; ni++)
      #pragma unroll
      for (int j = 0; j < 4; j++){
        int row = bm + wr*32 + mi*16 + lk*4 + j;
        int col = wc*64 + ni*16 + lr;
        Xp[(size_t)row*128 + col] += o[mi][ni][j];
      }
}

// ---------------- contiguous segment-sum of permuted VS rows (vectorized) ----------------
__global__ __launch_bounds__(256) void k_aggseg(const u16* __restrict__ VS, const int* __restrict__ rowptr,
                                                int p0, int p1, int first, float* __restrict__ agg){
  int n = blockIdx.x;
  int a = rowptr[n], b = rowptr[n+1];
  if (a < p0) a = p0;
  if (b > p1) b = p1;
  int tid = threadIdx.x;
  for (int g = tid; g < 464; g += 256){          // 29*128/8 = 464 groups of 8
    size_t obase = (size_t)n*29*128 + (size_t)g*8;
    float s[8];
    if (first){
      #pragma unroll
      for (int j = 0; j < 8; j++) s[j] = 0.f;
    } else {
      float4 lo = *(const float4*)&agg[obase];
      float4 hi = *(const float4*)&agg[obase + 4];
      s[0]=lo.x; s[1]=lo.y; s[2]=lo.z; s[3]=lo.w;
      s[4]=hi.x; s[5]=hi.y; s[6]=hi.z; s[7]=hi.w;
    }
    for (int p = a; p < b; p++){
      uint4 q = *(const uint4*)&VS[(size_t)(p - p0)*3712 + (size_t)g*8];
      const u16* qp = (const u16*)&q;
      #pragma unroll
      for (int j = 0; j < 8; j++) s[j] += bf2f(qp[j]);
    }
    float4 lo, hi;
    lo.x=s[0]; lo.y=s[1]; lo.z=s[2]; lo.w=s[3];
    hi.x=s[4]; hi.y=s[5]; hi.z=s[6]; hi.w=s[7];
    *(float4*)&agg[obase] = lo;
    *(float4*)&agg[obase + 4] = hi;
  }
}

// ---------------- node init ----------------
__global__ __launch_bounds__(128) void k_init(const float* __restrict__ pos, const float* __restrict__ table,
                                              const float* __restrict__ Yb, const float* __restrict__ radd,
                                              const int* __restrict__ rowptr, const int* __restrict__ eid,
                                              float* __restrict__ x){
  int n = blockIdx.x;
  int c = threadIdx.x;
  const float DLO = -3.26267f;
  const float DRG = (float)(3.295396 - (-3.26267));
  float p0 = pos[n*3+0], p1 = pos[n*3+1], p2 = pos[n*3+2];
  int t0 = min(127, max(0, (int)rintf((p0 - DLO)/DRG*128.f - 0.5f)));
  int t1 = min(127, max(0, (int)rintf((p1 - DLO)/DRG*128.f - 0.5f)));
  int t2 = min(127, max(0, (int)rintf((p2 - DLO)/DRG*128.f - 0.5f)));
  float emb = table[t0*CD + c] + table[t1*CD + c] + table[t2*CD + c];
  __shared__ float Yl[49];
  __shared__ float rl[896];
  float acc[NCO];
  #pragma unroll
  for (int k = 0; k < NCO; k++) acc[k] = 0.f;
  int pA = rowptr[n], pB = rowptr[n+1];
  for (int p = pA; p < pB; p++){
    int e = eid[p];
    if (c < 49) Yl[c] = Yb[(size_t)e*49 + c];
    #pragma unroll
    for (int q = 0; q < 7; q++) rl[q*128 + c] = radd[(size_t)e*896 + q*128 + c];
    __syncthreads();
    #pragma unroll
    for (int k = 0; k < NCO; k++){
      acc[k] += Yl[k]*rl[deg_of(k)*128 + c];
    }
    __syncthreads();
  }
  size_t base = (size_t)n*NCO*CD;
  x[base + c] = emb + acc[0]*(1.f/3.f);
  #pragma unroll
  for (int k = 1; k < NCO; k++) x[base + k*CD + c] = acc[k]*(1.f/3.f);
}

// ---------------- degree-grouped RMS norm, bf16 out (full 49 rows, for FFN) ----------------
__global__ __launch_bounds__(128) void k_rmsnorm(const float* __restrict__ x, const float* __restrict__ w,
                                                 u16* __restrict__ out){
  int n = blockIdx.x;
  int c = threadIdx.x;
  const float* xb = x + (size_t)n*NCO*CD;
  float vals[NCO];
  float ss[7] = {0,0,0,0,0,0,0};
  #pragma unroll
  for (int k = 0; k < NCO; k++){
    float v = xb[k*CD + c];
    vals[k] = v;
    ss[deg_of(k)] += v*v;
  }
  __shared__ float red[7][128];
  #pragma unroll
  for (int l = 0; l < 7; l++) red[l][c] = ss[l];
  __syncthreads();
  __shared__ float inv[7];
  if (c < 7){
    float s = 0.f;
    for (int i = 0; i < 128; i++) s += red[c][i];
    float ms = s / ((float)(2*c + 1)*128.f);
    inv[c] = 1.f / sqrtf(ms + 1e-6f);
  }
  __syncthreads();
  size_t base = (size_t)n*NCO*CD;
  #pragma unroll
  for (int k = 0; k < NCO; k++){
    int l = deg_of(k);
    out[base + k*CD + c] = f2bf(vals[k]*inv[l]*w[l*CD + c]);
  }
}

// ---------------- RMS norm writing restricted 29 rows, bf16 out ----------------
__global__ __launch_bounds__(128) void k_rmsnormR(const float* __restrict__ x, const float* __restrict__ w,
                                                  u16* __restrict__ hr){
  int n = blockIdx.x;
  int c = threadIdx.x;
  const float* xb = x + (size_t)n*NCO*CD;
  float vals[NCO];
  float ss[7] = {0,0,0,0,0,0,0};
  #pragma unroll
  for (int k = 0; k < NCO; k++){
    float v = xb[k*CD + c];
    vals[k] = v;
    ss[deg_of(k)] += v*v;
  }
  __shared__ float red[7][128];
  #pragma unroll
  for (int l = 0; l < 7; l++) red[l][c] = ss[l];
  __syncthreads();
  __shared__ float inv[7];
  if (c < 7){
    float s = 0.f;
    for (int i = 0; i < 128; i++) s += red[c][i];
    float ms = s / ((float)(2*c + 1)*128.f);
    inv[c] = 1.f / sqrtf(ms + 1e-6f);
  }
  __syncthreads();
  size_t base = (size_t)n*NRr*CD;
  #pragma unroll
  for (int kr = 0; kr < NRr; kr++){
    int k = d_RES[kr];
    int l = deg_of(k);
    hr[base + kr*CD + c] = f2bf(vals[k]*inv[l]*w[l*CD + c]);
  }
}

// ---------------- fused attention: logits + segment softmax + alpha ----------------
__global__ __launch_bounds__(256) void k_attn(
    const u16* __restrict__ XST, const float* __restrict__ rad, const float* __restrict__ avec,
    const int* __restrict__ src, const int* __restrict__ rowptr, const int* __restrict__ eid,
    float* __restrict__ AL)
{
  int n = blockIdx.x;
  int p0 = rowptr[n], p1 = rowptr[n+1];
  int deg = p1 - p0;
  if (deg == 0) return;
  __shared__ float lgs[64][8];
  __shared__ float xt0[128];
  __shared__ float av[128];
  __shared__ float mxs[8], dens[8];
  int tid = threadIdx.x;
  if (tid < 128){
    xt0[tid] = bf2f(XST[(size_t)n*NRr*256 + 128 + tid]);
    av[tid] = avec[tid];
  }
  __syncthreads();
  for (int pair = tid; pair < deg*8; pair += 256){
    int pl = pair >> 3, h = pair & 7;
    int e = eid[p0 + pl];
    int s = src[e];
    const u16* xs = &XST[(size_t)s*NRr*256 + h*16];
    uint4 q0 = *(const uint4*)xs;
    uint4 q1 = *(const uint4*)(xs + 8);
    const u16* x0 = (const u16*)&q0;
    const u16* x1 = (const u16*)&q1;
    const float* rd = &rad[(size_t)e*128 + h*16];
    float4 r0 = *(const float4*)(rd + 0);
    float4 r1 = *(const float4*)(rd + 4);
    float4 r2 = *(const float4*)(rd + 8);
    float4 r3 = *(const float4*)(rd + 12);
    float rr[16] = {r0.x,r0.y,r0.z,r0.w, r1.x,r1.y,r1.z,r1.w,
                    r2.x,r2.y,r2.z,r2.w, r3.x,r3.y,r3.z,r3.w};
    float acc = 0.f;
    #pragma unroll
    for (int d = 0; d < 8; d++){
      float m = (bf2f(x0[d]) + xt0[h*16 + d]) * rr[d];
      acc += siluf(m) * av[h*16 + d];
    }
    #pragma unroll
    for (int d = 0; d < 8; d++){
      float m = (bf2f(x1[d]) + xt0[h*16 + 8 + d]) * rr[8 + d];
      acc += siluf(m) * av[h*16 + 8 + d];
    }
    lgs[pl][h] = acc;
  }
  __syncthreads();
  if (tid < 8){
    float m = -1e30f;
    for (int pl = 0; pl < deg; pl++) m = fmaxf(m, lgs[pl][tid]);
    float sden = 0.f;
    for (int pl = 0; pl < deg; pl++) sden += expf(lgs[pl][tid] - m);
    mxs[tid] = m; dens[tid] = sden;
  }
  __syncthreads();
  for (int pair = tid; pair < deg*8; pair += 256){
    int pl = pair >> 3, h = pair & 7;
    int e = eid[p0 + pl];
    AL[e*8 + h] = expf(lgs[pl][h] - mxs[h]) / fmaxf(dens[h], 1e-9f);
  }
}

// ---------------- pooling ----------------
__global__ void k_pool(const float* __restrict__ orr, const int* __restrict__ gs, float* __restrict__ out){
  int i = blockIdx.x*blockDim.x + threadIdx.x;
  if (i >= NG*NCO*CD) return;
  int c = i & 127;
  int k = (i >> 7) % 49;
  int g = i / (49*128);
  int kr = c_rinv[k];
  float v = 0.f;
  if (kr >= 0){
    int a = gs[g], b = gs[g+1];
    float s = 0.f;
    for (int n = a; n < b; n++) s += orr[((size_t)n*29 + kr)*128 + c];
    int cnt = b - a;
    v = s / (float)(cnt > 0 ? cnt : 1);
  }
  out[i] = v;
}

extern "C" void kernel_launch(void* const* d_in, const int* in_sizes, int n_in,
                              void* d_out, int out_size, void* d_ws, size_t ws_size,
                              hipStream_t stream){
  const float* pos    = (const float*)d_in[0];
  const float* evec   = (const float*)d_in[1];
  const int*   eidx   = (const int*)  d_in[2];
  const int*   batch  = (const int*)  d_in[3];
  const float* table  = (const float*)d_in[4];
  const float* deg_w1 = (const float*)d_in[5];
  const float* deg_b1 = (const float*)d_in[6];
  const float* deg_w2 = (const float*)d_in[7];
  const float* deg_b2 = (const float*)d_in[8];
  const float* deg_w3 = (const float*)d_in[9];
  const float* attn_nw= (const float*)d_in[10];
  const float* w_src  = (const float*)d_in[11];
  const float* w_tgt  = (const float*)d_in[12];
  const float* rad_w1 = (const float*)d_in[13];
  const float* rad_b1 = (const float*)d_in[14];
  const float* rad_w2 = (const float*)d_in[15];
  const float* avec   = (const float*)d_in[16];
  const float* w_val  = (const float*)d_in[17];
  const float* w_proj = (const float*)d_in[18];
  const float* ffn_nw = (const float*)d_in[19];
  const float* ffn_w1 = (const float*)d_in[20];
  const float* ffn_w2 = (const float*)d_in[21];
  const float* fin_nw = (const float*)d_in[22];
  const float* lw_src = (const float*)d_in[23];
  const float* lw_tgt = (const float*)d_in[24];
  const float* lrad_w1= (const float*)d_in[25];
  const float* lrad_b1= (const float*)d_in[26];
  const float* lrad_w2= (const float*)d_in[27];
  const float* lavec  = (const float*)d_in[28];
  const float* lw_val = (const float*)d_in[29];
  const float* lw_proj= (const float*)d_in[30];

  const int* srcp = eidx;
  const int* dstp = eidx + NE;

  // ws budget: 256 MiB = 67.1M f32-slots. Layout below totals ~56M (audited).
  float* W = (float*)d_ws;
  size_t o = 0;
  float* X    = W + o; o += (size_t)NN*49*128;   // 12.85M
  float* Hb   = W + o; o += (size_t)NN*49*128;   // 12.85M: RADD, VS chunks, latent proj out, FFN rmsnorm(bf16)
  float* HR   = W + o; o += (size_t)NN*29*128;   // 7.60M: rmsnormR(bf16) out, AG
  float* XSTf = W + o; o += (size_t)NN*29*256/2; // 7.60M: XST bf16 (u16)
  float* R1   = W + o; o += (size_t)NE*128;      // 1.57M
  float* R2   = W + o; o += (size_t)NE*128;      // 1.57M
  float* Yb   = W + o; o += (size_t)NE*49;       // 0.60M
  float* DV   = W + o; o += (size_t)NE;
  float* AL   = W + o; o += (size_t)NE*8;
  float* SG   = W + o; o += (size_t)NN*512;      // 1.05M
  int* CNT = (int*)(W + o); o += NN;
  int* RP  = (int*)(W + o); o += NN + 1;
  int* EID = (int*)(W + o); o += NE;
  int* GS  = (int*)(W + o); o += NG + 1;
  int* CH  = (int*)(W + o); o += 4*NN;
  float* R1A = W + o; o += (size_t)3*NE*128;     // 4.72M: batched radial layer-1
  float* R2A = W + o; o += (size_t)3*NE*128;     // 4.72M: batched radial layer-2
  // bf16 transposed weights (~0.32M f32-slots)
  u16* WB = (u16*)(W + o);
  size_t wo = 0;
  u16* T_degw2 = WB + wo; wo += 16384;
  u16* T_degw3 = WB + wo; wo += 114688;
  u16* T_wst[3]; u16* T_wv[3]; u16* T_wp[3]; u16* T_rw2[3];
  for (int i = 0; i < 3; i++){ T_wst[i] = WB + wo; wo += 32768; }   // [256][128]
  for (int i = 0; i < 3; i++){ T_wv[i] = WB + wo; wo += 16384; }
  for (int i = 0; i < 3; i++){ T_wp[i] = WB + wo; wo += 16384; }
  for (int i = 0; i < 3; i++){ T_rw2[i] = WB + wo; wo += 16384; }
  u16* T_f1[2]; u16* T_f2[2];
  for (int i = 0; i < 2; i++){ T_f1[i] = WB + wo; wo += 65536; }
  for (int i = 0; i < 2; i++){ T_f2[i] = WB + wo; wo += 65536; }
  (void)ws_size; (void)in_sizes; (void)n_in; (void)out_size;

  u16*  XSTw = (u16*)XSTf;                        // [NN][29][256] bf16
  u16*  HRw  = (u16*)HR;                          // rmsnormR bf16 out
  u16*  Hbw  = (u16*)Hb;                          // FFN rmsnorm bf16 out (first half of Hb)
  float* RADD = Hb;                               // E*896 <= Hb; free before layers
  u16*  VS    = (u16*)Hb;                         // VCH_E*29*128 u16 = 11.4M f32 <= Hb
  float* AG   = HR;
  float* OR_  = Hb;                               // latent proj out (after aggseg done)

  // ---- all weight casts in one launch ----
  {
    CastJobs J;
    int idx = 0, acc = 0;
    auto add = [&](const float* s, u16* d, int K, int N){
      J.src[idx] = s; J.dst[idx] = d; J.K[idx] = K; J.N[idx] = N; J.start[idx] = acc;
      acc += K*N; idx++;
    };
    add(deg_w2, T_degw2, 128, 128);
    add(deg_w3, T_degw3, 128, 896);
    for (int i = 0; i < 3; i++){
      add((i < 2) ? w_src  + (size_t)i*16384 : lw_src,  T_wst[i],          128, 128);
      add((i < 2) ? w_tgt  + (size_t)i*16384 : lw_tgt,  T_wst[i] + 16384,  128, 128);
      add((i < 2) ? w_val  + (size_t)i*16384 : lw_val,  T_wv[i], 128, 128);
      add((i < 2) ? w_proj + (size_t)i*16384 : lw_proj, T_wp[i], 128, 128);
      add((i < 2) ? rad_w2 + (size_t)i*16384 : lrad_w2, T_rw2[i], 128, 128);
    }
    for (int i = 0; i < 2; i++){
      add(ffn_w1 + (size_t)i*65536, T_f1[i], 128, 512);
      add(ffn_w2 + (size_t)i*65536, T_f2[i], 512, 128);
    }
    J.start[idx] = acc; J.total = acc;
    k_castall<<<(acc + 255)/256, 256, 0, stream>>>(J);
  }

  // CSR + groups
  k_hist4<<<1, 1024, 0, stream>>>(dstp, CNT, CH);
  k_scan2<<<1, 1024, 0, stream>>>(CNT, RP);
  k_fillw4<<<NN, 256, 0, stream>>>(dstp, RP, CH, EID);
  k_gstart<<<1, 32, 0, stream>>>(batch, GS);

  // geometry
  k_geom<<<48, 256, 0, stream>>>(evec, Yb, DV);

  // batched attention radial MLPs (all 3 layers, independent of X)
  k_rad1b<<<dim3(NE, 3), 128, 0, stream>>>(DV,
      rad_w1, rad_w1 + 76800, lrad_w1,
      rad_b1, rad_b1 + 128,   lrad_b1, R1A);
  k_rgemm<<<dim3(1, NE/64, 3), 256, 0, stream>>>(R1A, T_rw2[0], T_rw2[1], T_rw2[2], R2A);

  // degree embedding MLP: 600->128 (silu) -> 128 (silu) -> 896
  k_rad1<<<NE, 128, 0, stream>>>(DV, deg_w1, deg_b1, R1);
  k_mgemm<0,1,2><<<dim3(1, NE/64), 256, 0, stream>>>(R1, T_degw2, deg_b2, R2, NE, 128, 128, 128,
                                                     nullptr, nullptr, nullptr, nullptr, nullptr, 0);
  k_mgemm<0,0,2><<<dim3(7, NE/64), 256, 0, stream>>>(R2, T_degw3, nullptr, RADD, NE, 896, 128, 128,
                                                     nullptr, nullptr, nullptr, nullptr, nullptr, 0);
  k_init<<<NN, 128, 0, stream>>>(pos, table, Yb, RADD, RP, EID, X);

  for (int i = 0; i < 3; i++){
    const float* nw  = (i < 2) ? attn_nw + (size_t)i*896 : fin_nw;
    const float* av  = (i < 2) ? avec   + (size_t)i*128  : lavec;
    const float* R2L = R2A + (size_t)i*NE*128;

    k_rmsnormR<<<NN, 128, 0, stream>>>(X, nw, HRw);
    // combined XS|XT projection, bf16 output
    k_mgemm<2,6,4><<<dim3(1, NN*NRr/64), 256, 0, stream>>>(HRw, T_wst[i], nullptr, XSTw, NN*NRr, 256, 128, 128,
                                                           nullptr, nullptr, nullptr, nullptr, nullptr, 0);
    // fused logits + softmax + alpha
    k_attn<<<NN, 256, 0, stream>>>(XSTw, R2L, av, srcp, RP, EID, AL);
    // V in CSR-permuted order, alpha-fused epilogue, then contiguous segment-sum
    for (int ch = 0; ch < NE/VCH_E; ch++){
      int p0 = ch*VCH_E;
      k_mgemm<3,7,2><<<dim3(1, VCH_E*NRr/64), 256, 0, stream>>>(R2L, T_wv[i], nullptr, VS,
                                                                VCH_E*NRr, 128, 128, 128,
                                                                (const float*)XSTw, srcp, dstp, EID, AL, p0);
      k_aggseg<<<NN, 256, 0, stream>>>(VS, RP, p0, p0 + VCH_E, ch == 0, AG);
    }
    if (i < 2){
      // projection with fused scatter-accumulate into X
      k_mgemm<0,3,2><<<dim3(1, NN*NRr/64), 256, 0, stream>>>(AG, T_wp[i], nullptr, X, NN*NRr, 128, 128, 128,
                                                             nullptr, nullptr, nullptr, nullptr, nullptr, 0);
      // FFN: gate from row0, hidden kept in LDS (fused GEMM1+gate+GEMM2, 8-wave M=128)
      k_rmsnorm<<<NN, 128, 0, stream>>>(X, ffn_nw + (size_t)i*896, Hbw);
      k_mgemm<2,4,1><<<dim3(8, NN/64), 256, 0, stream>>>(Hbw, T_f1[i], nullptr, SG, NN, 512, 128, NCO*CD,
                                                         nullptr, nullptr, nullptr, nullptr, nullptr, 0);
      k_ffn<<<NN*NCO/128, 512, 0, stream>>>(Hbw, T_f1[i], T_f2[i], SG, X);
    } else {
      k_mgemm<0,0,2><<<dim3(1, NN*NRr/64), 256, 0, stream>>>(AG, T_wp[i], nullptr, OR_, NN*NRr, 128, 128, 128,
                                                             nullptr, nullptr, nullptr, nullptr, nullptr, 0);
      k_pool<<<(NG*NCO*CD + 255)/256, 256, 0, stream>>>(OR_, GS, (float*)d_out);
    }
  }
}

// Round 20
// 850.503 us; speedup vs baseline: 1.2444x; 1.0903x over previous
//
#include <hip/hip_runtime.h>
#include <math.h>

#define NN 2048
#define NE 12288
#define NCO 49
#define NRr 29
#define CD 128
#define NG 16
#define NJOBS 21
#define VCH_E 6144   // edges per V chunk (permuted positions)

typedef unsigned short u16;
typedef short bhalf8 __attribute__((ext_vector_type(8)));
typedef float fvec4 __attribute__((ext_vector_type(4)));

// RESTRICT: indices k (0..48) with |m|<=2.
__constant__ int c_res[29] = {0,1,2,3,4,5,6,7,8,10,11,12,13,14,18,19,20,21,22,28,29,30,31,32,40,41,42,43,44};
__constant__ int c_rinv[49] = {0,1,2,3,4,5,6,7,8,-1,9,10,11,12,13,-1,-1,-1,14,15,16,17,18,-1,-1,-1,-1,-1,19,20,21,22,23,-1,-1,-1,-1,-1,-1,-1,24,25,26,27,28,-1,-1,-1,-1};
__device__ constexpr int d_RES[29] = {0,1,2,3,4,5,6,7,8,10,11,12,13,14,18,19,20,21,22,28,29,30,31,32,40,41,42,43,44};

__device__ __forceinline__ constexpr int deg_of(int k){
  return (k<1)?0:(k<4)?1:(k<9)?2:(k<16)?3:(k<25)?4:(k<36)?5:6;
}
__device__ __forceinline__ float siluf(float x){ return x / (1.f + expf(-x)); }
__device__ __forceinline__ u16 f2bf(float f){
  unsigned int u = __float_as_uint(f);
  unsigned int r = (u + 0x7FFFu + ((u >> 16) & 1u)) >> 16;
  return (u16)r;
}
__device__ __forceinline__ float bf2f(u16 b){
  return __uint_as_float(((unsigned int)b) << 16);
}
__device__ __forceinline__ unsigned int pk(u16 lo, u16 hi){ return (unsigned int)lo | ((unsigned int)hi << 16); }

// ---------------- CSR build (deterministic, parallel) ----------------
__global__ __launch_bounds__(1024) void k_hist4(const int* __restrict__ dst, int* __restrict__ cnt,
                                                int* __restrict__ CH){
  __shared__ int h[4*NN];
  for (int i = threadIdx.x; i < 4*NN; i += 1024) h[i] = 0;
  __syncthreads();
  const int QE = NE/4;
  for (int e = threadIdx.x; e < NE; e += 1024){
    int q = e / QE;
    atomicAdd(&h[q*NN + dst[e]], 1);
  }
  __syncthreads();
  for (int n = threadIdx.x; n < NN; n += 1024){
    int s = 0;
    #pragma unroll
    for (int q = 0; q < 4; q++){ int v = h[q*NN + n]; CH[q*NN + n] = v; s += v; }
    cnt[n] = s;
  }
}
__global__ __launch_bounds__(1024) void k_scan2(const int* __restrict__ cnt, int* __restrict__ rowptr){
  __shared__ int a[NN], b[NN];
  int t = threadIdx.x;
  for (int i = t; i < NN; i += 1024) a[i] = cnt[i];
  __syncthreads();
  int* pin = a; int* pout = b;
  for (int off = 1; off < NN; off <<= 1){
    for (int i = t; i < NN; i += 1024)
      pout[i] = pin[i] + ((i >= off) ? pin[i - off] : 0);
    __syncthreads();
    int* tmp = pin; pin = pout; pout = tmp;
  }
  for (int i = t; i < NN; i += 1024) rowptr[i + 1] = pin[i];
  if (t == 0) rowptr[0] = 0;
}
__global__ __launch_bounds__(256) void k_fillw4(const int* __restrict__ dst, const int* __restrict__ rowptr,
                                                const int* __restrict__ CH, int* __restrict__ eid){
  int q = threadIdx.x >> 6, lane = threadIdx.x & 63;
  int n = blockIdx.x;
  int base = rowptr[n];
  for (int qq = 0; qq < q; qq++) base += CH[qq*NN + n];
  const int QE = NE/4;
  for (int e0 = q*QE; e0 < (q+1)*QE; e0 += 64){
    int e = e0 + lane;
    bool m = (dst[e] == n);
    unsigned long long mask = __ballot(m);
    if (m) eid[base + __popcll(mask & ((1ull << lane) - 1ull))] = e;
    base += __popcll(mask);
  }
}
__global__ void k_gstart(const int* __restrict__ batch, int* __restrict__ gs){
  int g = threadIdx.x;
  if (g > NG) return;
  int lo = 0, hi = NN;
  while (lo < hi){ int mid = (lo + hi) >> 1; if (batch[mid] < g) lo = mid + 1; else hi = mid; }
  gs[g] = lo;
}

// ---------------- all weight casts in one launch: [K][N] f32 -> [N][K] bf16 ----------------
struct CastJobs {
  const float* src[NJOBS];
  u16* dst[NJOBS];
  int K[NJOBS], N[NJOBS];
  int start[NJOBS + 1];
  int total;
};
__global__ void k_castall(CastJobs J){
  int i = blockIdx.x*blockDim.x + threadIdx.x;
  if (i >= J.total) return;
  int j = 0;
  while (i >= J.start[j + 1]) j++;
  int local = i - J.start[j];
  int K = J.K[j], N = J.N[j];
  int n = local / K, k = local - n*K;
  J.dst[j][local] = f2bf(J.src[j][(size_t)k*N + n]);
}

// ---------------- geometry ----------------
__global__ void k_geom(const float* __restrict__ ev, float* __restrict__ Y, float* __restrict__ dv){
  int e = blockIdx.x*blockDim.x + threadIdx.x;
  if (e >= NE) return;
  float x = ev[e*3+0], y = ev[e*3+1], z = ev[e*3+2];
  float r = sqrtf(x*x + y*y + z*z);
  dv[e] = r;
  float rn = fmaxf(r, 1e-8f);
  float ux = x/rn, uy = y/rn, uz = z/rn;
  float ct = fminf(fmaxf(uz, -1.f), 1.f);
  float st = sqrtf(fminf(fmaxf(1.f - ct*ct, 1e-12f), 1.f));
  float phi = atan2f(uy, ux);
  float P[7][7];
  P[0][0] = 1.f;
  #pragma unroll
  for (int m = 1; m <= 6; m++) P[m][m] = -(2.f*m - 1.f)*st*P[m-1][m-1];
  #pragma unroll
  for (int m = 0; m <= 5; m++) P[m+1][m] = (2.f*m + 1.f)*ct*P[m][m];
  #pragma unroll
  for (int m = 0; m <= 6; m++){
    #pragma unroll
    for (int l = m+2; l <= 6; l++)
      P[l][m] = ((2.f*l - 1.f)*ct*P[l-1][m] - (float)(l+m-1)*P[l-2][m]) / (float)(l-m);
  }
  float cmv[7], smv[7];
  #pragma unroll
  for (int m = 0; m <= 6; m++){ cmv[m] = cosf((float)m*phi); smv[m] = sinf((float)m*phi); }
  const double FOURPI = 12.566370614359172;
  int k = 0;
  #pragma unroll
  for (int l = 0; l <= 6; l++){
    #pragma unroll
    for (int mm = -l; mm <= l; mm++){
      int am = mm < 0 ? -mm : mm;
      double ratio = 1.0;
      for (int i = l-am+1; i <= l+am; i++) ratio /= (double)i;
      double nrm = sqrt((2.0*l + 1.0)/FOURPI*ratio);
      float v;
      if (mm == 0)      v = (float)nrm * P[l][0];
      else if (mm > 0)  v = (float)(1.4142135623730951*nrm) * P[l][am] * cmv[am];
      else              v = (float)(1.4142135623730951*nrm) * P[l][am] * smv[am];
      Y[(size_t)e*49 + k] = v; k++;
    }
  }
}

// ------------- fused layer-1 of ALL FOUR radial MLPs (3 attn + degree) -------------
// g[] computed once per edge; bounds hoisted to a clamped range (bit-identical:
// excluded taps contributed exactly 0; included terms keep increasing-i order).
__global__ __launch_bounds__(128) void k_rad14(const float* __restrict__ dv,
    const float* __restrict__ W0, const float* __restrict__ W1,
    const float* __restrict__ W2, const float* __restrict__ W3,
    const float* __restrict__ bp0, const float* __restrict__ bp1,
    const float* __restrict__ bp2, const float* __restrict__ bp3,
    float* __restrict__ out){
  int e = blockIdx.x;
  int j = threadIdx.x;
  float d = dv[e];
  const float STEPF = (float)(5.0/599.0);
  const double step_d = (double)STEPF;
  const float GC = (float)(-0.5/((2.0*step_d)*(2.0*step_d)));
  __shared__ float g[64];
  int bc = (int)rintf(d / STEPF);
  int wb0 = bc - 32;
  if (j < 64){
    int b = wb0 + j;
    float gg = 0.f;
    if (b >= 0 && b < 600){
      float off = (float)((double)b * (5.0/599.0));
      float t = d - off;
      gg = expf(GC*t*t);
    }
    g[j] = gg;
  }
  __syncthreads();
  int lo = (wb0 < 0) ? -wb0 : 0;
  int hi = (wb0 > 536) ? (600 - wb0) : 64;
  float a0 = bp0[j], a1 = bp1[j], a2 = bp2[j], a3 = bp3[j];
  const float* w0 = W0 + (size_t)(wb0 + lo)*CD + j;
  const float* w1 = W1 + (size_t)(wb0 + lo)*CD + j;
  const float* w2 = W2 + (size_t)(wb0 + lo)*CD + j;
  const float* w3 = W3 + (size_t)(wb0 + lo)*CD + j;
  for (int i = lo; i < hi; i++){
    float gg = g[i];
    a0 += gg*(*w0); a1 += gg*(*w1); a2 += gg*(*w2); a3 += gg*(*w3);
    w0 += CD; w1 += CD; w2 += CD; w3 += CD;
  }
  out[((size_t)0*NE + e)*CD + j] = siluf(a0);
  out[((size_t)1*NE + e)*CD + j] = siluf(a1);
  out[((size_t)2*NE + e)*CD + j] = siluf(a2);
  out[((size_t)3*NE + e)*CD + j] = siluf(a3);
}

// ---------------- MFMA bf16 GEMM with NT column-tiles per block ----------------
// AMODE: 0 = f32 A (runtime lda); 2 = bf16 A (runtime lda);
//        3 = permuted fused-message A.
// EPI:   0 store(+bias); 1 silu(+bias); 2 accumulate; 3 scatter-accum into X;
//        4 sigmoid store; 5 gate-mul (P0=SG) then bf16 store; 6 bf16 store;
//        7 alpha-scale (ALp, permuted via eidp) then bf16 store (VS).
template<int AMODE, int EPI, int NT>
__global__ __launch_bounds__(256) void k_mgemm(
    const void* __restrict__ Av, const u16* __restrict__ Bt,
    const float* __restrict__ bias, void* __restrict__ Cv,
    int M, int N, int K, int lda,
    const float* __restrict__ P0,
    const int* __restrict__ src, const int* __restrict__ dstp,
    const int* __restrict__ eidp, const float* __restrict__ ALp, int e0)
{
  __shared__ __align__(16) u16 Asl[64*64];
  __shared__ __align__(16) u16 Bsl[NT][64*64];
  int tid = threadIdx.x;
  int bm = blockIdx.y*64;
  int bn0 = blockIdx.x*NT*64;
  int wid = tid >> 6, lane = tid & 63;
  int wr = wid >> 1, wc = wid & 1;
  int lr = lane & 15, lk = lane >> 4;
  fvec4 acc[NT][2][2] = {};
  for (int k0 = 0; k0 < K; k0 += 64){
    #pragma unroll
    for (int h = 0; h < 2; h++){
      int lin = tid + h*256;          // 0..511: 64 rows x 8 k-groups
      int row = lin >> 3, kg = lin & 7;
      uint4 q;
      if (AMODE == 3){
        int gr = bm + row;
        int el = gr / 29, kq = gr - el*29;
        int p = e0 + el;
        int e = eidp[p];
        int s = src[e], t = dstp[e];
        const u16* xst = (const u16*)P0;
        uint4 xs8 = *(const uint4*)&xst[((size_t)s*29 + kq)*256 + k0 + kg*8];
        uint4 xt8 = *(const uint4*)&xst[((size_t)t*29 + kq)*256 + 128 + k0 + kg*8];
        const float* rd = (const float*)Av + (size_t)e*128 + k0 + kg*8;
        const u16* xsp = (const u16*)&xs8;
        const u16* xtp = (const u16*)&xt8;
        u16 ov[8];
        #pragma unroll
        for (int j = 0; j < 8; j++)
          ov[j] = f2bf((bf2f(xsp[j]) + bf2f(xtp[j])) * rd[j]);
        q.x = pk(ov[0], ov[1]); q.y = pk(ov[2], ov[3]);
        q.z = pk(ov[4], ov[5]); q.w = pk(ov[6], ov[7]);
      } else if (AMODE == 2){
        const u16* ap = (const u16*)Av + (size_t)(bm + row)*lda + k0 + kg*8;
        q = *(const uint4*)ap;
      } else {
        const float* ap = (const float*)Av + (size_t)(bm + row)*lda + k0 + kg*8;
        float v[8];
        #pragma unroll
        for (int j = 0; j < 8; j++) v[j] = ap[j];
        q.x = pk(f2bf(v[0]), f2bf(v[1]));
        q.y = pk(f2bf(v[2]), f2bf(v[3]));
        q.z = pk(f2bf(v[4]), f2bf(v[5]));
        q.w = pk(f2bf(v[6]), f2bf(v[7]));
      }
      *(uint4*)&Asl[row*64 + ((kg*8) ^ ((row & 7)*8))] = q;
    }
    #pragma unroll
    for (int t = 0; t < NT; t++){
      #pragma unroll
      for (int h = 0; h < 2; h++){
        int lin = tid + h*256;
        int row = lin >> 3, kg = lin & 7;
        const u16* bp = Bt + (size_t)(bn0 + t*64 + row)*K + k0 + kg*8;
        *(uint4*)&Bsl[t][row*64 + ((kg*8) ^ ((row & 7)*8))] = *(const uint4*)bp;
      }
    }
    __syncthreads();
    #pragma unroll
    for (int ks = 0; ks < 2; ks++){
      int kg = ks*4 + lk;
      bhalf8 af[2];
      #pragma unroll
      for (int mi = 0; mi < 2; mi++){
        int ar = wr*32 + mi*16 + lr;
        af[mi] = *(const bhalf8*)&Asl[ar*64 + ((kg*8) ^ ((ar & 7)*8))];
      }
      #pragma unroll
      for (int t = 0; t < NT; t++){
        bhalf8 bfr[2];
        #pragma unroll
        for (int ni = 0; ni < 2; ni++){
          int br = wc*32 + ni*16 + lr;
          bfr[ni] = *(const bhalf8*)&Bsl[t][br*64 + ((kg*8) ^ ((br & 7)*8))];
        }
        #pragma unroll
        for (int mi = 0; mi < 2; mi++)
          #pragma unroll
          for (int ni = 0; ni < 2; ni++)
            acc[t][mi][ni] = __builtin_amdgcn_mfma_f32_16x16x32_bf16(af[mi], bfr[ni], acc[t][mi][ni], 0, 0, 0);
      }
    }
    __syncthreads();
  }
  #pragma unroll
  for (int t = 0; t < NT; t++){
    #pragma unroll
    for (int mi = 0; mi < 2; mi++){
      #pragma unroll
      for (int ni = 0; ni < 2; ni++){
        #pragma unroll
        for (int j = 0; j < 4; j++){
          int row = bm + wr*32 + mi*16 + lk*4 + j;
          int col = bn0 + t*64 + wc*32 + ni*16 + lr;
          float v = acc[t][mi][ni][j];
          if (EPI == 0){
            if (bias) v += bias[col];
            ((float*)Cv)[(size_t)row*N + col] = v;
          } else if (EPI == 1){
            if (bias) v += bias[col];
            ((float*)Cv)[(size_t)row*N + col] = siluf(v);
          } else if (EPI == 2){
            ((float*)Cv)[(size_t)row*N + col] += v;
          } else if (EPI == 3){
            int n = row / 29, kr = row - n*29;
            ((float*)Cv)[((size_t)n*49 + c_res[kr])*128 + col] += v;
          } else if (EPI == 4){
            ((float*)Cv)[(size_t)row*N + col] = 1.f/(1.f + expf(-v));
          } else if (EPI == 5){
            float g = P0[(size_t)(row/49)*N + col];
            ((u16*)Cv)[(size_t)row*N + col] = f2bf(v*g);
          } else if (EPI == 6){
            ((u16*)Cv)[(size_t)row*N + col] = f2bf(v);
          } else {
            int p = e0 + row/29;
            int e = eidp[p];
            float a = ALp[e*8 + (col >> 4)];
            ((u16*)Cv)[(size_t)row*N + col] = f2bf(v*a);
          }
        }
      }
    }
  }
}

// ---------------- batched radial layer-2 GEMM (z: 0..2 attn, 3 = degree w/bias+silu) ----------------
__global__ __launch_bounds__(256) void k_rgemm(
    const float* __restrict__ A, const u16* __restrict__ B0, const u16* __restrict__ B1,
    const u16* __restrict__ B2, const u16* __restrict__ B3,
    const float* __restrict__ degb2, float* __restrict__ C)
{
  __shared__ __align__(16) u16 Asl[64*64];
  __shared__ __align__(16) u16 Bsl[2][64*64];
  int tid = threadIdx.x;
  int l = blockIdx.z;
  int bm = blockIdx.y*64;
  const u16* Bt = (l == 0) ? B0 : (l == 1) ? B1 : (l == 2) ? B2 : B3;
  const float* Al = A + (size_t)l*NE*128;
  float* Cl = C + (size_t)l*NE*128;
  int wid = tid >> 6, lane = tid & 63;
  int wr = wid >> 1, wc = wid & 1;
  int lr = lane & 15, lk = lane >> 4;
  fvec4 acc[2][2][2] = {};
  for (int k0 = 0; k0 < 128; k0 += 64){
    #pragma unroll
    for (int h = 0; h < 2; h++){
      int lin = tid + h*256;
      int row = lin >> 3, kg = lin & 7;
      const float* ap = Al + (size_t)(bm + row)*128 + k0 + kg*8;
      float v[8];
      #pragma unroll
      for (int j = 0; j < 8; j++) v[j] = ap[j];
      uint4 q;
      q.x = pk(f2bf(v[0]), f2bf(v[1]));
      q.y = pk(f2bf(v[2]), f2bf(v[3]));
      q.z = pk(f2bf(v[4]), f2bf(v[5]));
      q.w = pk(f2bf(v[6]), f2bf(v[7]));
      *(uint4*)&Asl[row*64 + ((kg*8) ^ ((row & 7)*8))] = q;
    }
    #pragma unroll
    for (int t = 0; t < 2; t++){
      #pragma unroll
      for (int h = 0; h < 2; h++){
        int lin = tid + h*256;
        int row = lin >> 3, kg = lin & 7;
        const u16* bp = Bt + (size_t)(t*64 + row)*128 + k0 + kg*8;
        *(uint4*)&Bsl[t][row*64 + ((kg*8) ^ ((row & 7)*8))] = *(const uint4*)bp;
      }
    }
    __syncthreads();
    #pragma unroll
    for (int ks = 0; ks < 2; ks++){
      int kg = ks*4 + lk;
      bhalf8 af[2];
      #pragma unroll
      for (int mi = 0; mi < 2; mi++){
        int ar = wr*32 + mi*16 + lr;
        af[mi] = *(const bhalf8*)&Asl[ar*64 + ((kg*8) ^ ((ar & 7)*8))];
      }
      #pragma unroll
      for (int t = 0; t < 2; t++){
        bhalf8 bfr[2];
        #pragma unroll
        for (int ni = 0; ni < 2; ni++){
          int br = wc*32 + ni*16 + lr;
          bfr[ni] = *(const bhalf8*)&Bsl[t][br*64 + ((kg*8) ^ ((br & 7)*8))];
        }
        #pragma unroll
        for (int mi = 0; mi < 2; mi++)
          #pragma unroll
          for (int ni = 0; ni < 2; ni++)
            acc[t][mi][ni] = __builtin_amdgcn_mfma_f32_16x16x32_bf16(af[mi], bfr[ni], acc[t][mi][ni], 0, 0, 0);
      }
    }
    __syncthreads();
  }
  #pragma unroll
  for (int t = 0; t < 2; t++)
    #pragma unroll
    for (int mi = 0; mi < 2; mi++)
      #pragma unroll
      for (int ni = 0; ni < 2; ni++)
        #pragma unroll
        for (int j = 0; j < 4; j++){
          int row = bm + wr*32 + mi*16 + lk*4 + j;
          int col = t*64 + wc*32 + ni*16 + lr;
          float v = acc[t][mi][ni][j];
          if (l == 3){ v += degb2[col]; v = siluf(v); }
          Cl[(size_t)row*128 + col] = v;
        }
}

// ---------------- fused FFN, 8-wave M=128: X += ((bf16(A@W1)*gate)@W2) ----------------
__global__ __launch_bounds__(512) void k_ffn(
    const u16* __restrict__ A, const u16* __restrict__ W1, const u16* __restrict__ W2,
    const float* __restrict__ SGp, float* __restrict__ Xp)
{
  __shared__ __align__(16) u16 Asl[128*128];  // 32 KB
  __shared__ __align__(16) u16 W1s[64*128];   // 16 KB
  __shared__ __align__(16) u16 W2s[128*64];   // 16 KB
  __shared__ __align__(16) u16 Hs[128*64];    // 16 KB
  int tid = threadIdx.x;
  int bm = blockIdx.x*128;
  int wid = tid >> 6, lane = tid & 63;
  int wr = wid >> 1, wc = wid & 1;
  int lr = lane & 15, lk = lane >> 4;
  for (int g = tid; g < 2048; g += 512){
    int row = g >> 4, kg = g & 15;
    *(uint4*)&Asl[row*128 + ((kg*8) ^ ((row & 7)*16))] = *(const uint4*)&A[(size_t)(bm + row)*128 + kg*8];
  }
  fvec4 o[2][4] = {};
  for (int h0 = 0; h0 < 512; h0 += 64){
    for (int g = tid; g < 1024; g += 512){
      int row = g >> 4, kg = g & 15;
      *(uint4*)&W1s[row*128 + ((kg*8) ^ ((row & 7)*16))] = *(const uint4*)&W1[(size_t)(h0 + row)*128 + kg*8];
    }
    for (int g = tid; g < 1024; g += 512){
      int row = g >> 3, kg = g & 7;
      *(uint4*)&W2s[row*64 + ((kg*8) ^ ((row & 7)*8))] = *(const uint4*)&W2[(size_t)row*512 + h0 + kg*8];
    }
    __syncthreads();
    fvec4 hid[2][2] = {};
    #pragma unroll
    for (int kk = 0; kk < 4; kk++){
      int kg = kk*4 + lk;
      bhalf8 af[2], bf[2];
      #pragma unroll
      for (int mi = 0; mi < 2; mi++){
        int ar = wr*32 + mi*16 + lr;
        af[mi] = *(const bhalf8*)&Asl[ar*128 + ((kg*8) ^ ((ar & 7)*16))];
      }
      #pragma unroll
      for (int ni = 0; ni < 2; ni++){
        int br = wc*32 + ni*16 + lr;
        bf[ni] = *(const bhalf8*)&W1s[br*128 + ((kg*8) ^ ((br & 7)*16))];
      }
      #pragma unroll
      for (int mi = 0; mi < 2; mi++)
        #pragma unroll
        for (int ni = 0; ni < 2; ni++)
          hid[mi][ni] = __builtin_amdgcn_mfma_f32_16x16x32_bf16(af[mi], bf[ni], hid[mi][ni], 0, 0, 0);
    }
    #pragma unroll
    for (int mi = 0; mi < 2; mi++){
      #pragma unroll
      for (int j = 0; j < 4; j++){
        int row = wr*32 + mi*16 + lk*4 + j;
        int node = (bm + row)/49;
        const float* sgrow = &SGp[(size_t)node*512 + h0];
        #pragma unroll
        for (int ni = 0; ni < 2; ni++){
          int col = wc*32 + ni*16 + lr;
          Hs[row*64 + (col ^ ((row & 7)*8))] = f2bf(hid[mi][ni][j]*sgrow[col]);
        }
      }
    }
    __syncthreads();
    #pragma unroll
    for (int kk2 = 0; kk2 < 2; kk2++){
      int kg = kk2*4 + lk;
      bhalf8 af2[2], bf2[4];
      #pragma unroll
      for (int mi = 0; mi < 2; mi++){
        int ar = wr*32 + mi*16 + lr;
        af2[mi] = *(const bhalf8*)&Hs[ar*64 + ((kg*8) ^ ((ar & 7)*8))];
      }
      #pragma unroll
      for (int ni = 0; ni < 4; ni++){
        int br = wc*64 + ni*16 + lr;
        bf2[ni] = *(const bhalf8*)&W2s[br*64 + ((kg*8) ^ ((br & 7)*8))];
      }
      #pragma unroll
      for (int mi = 0; mi < 2; mi++)
        #pragma unroll
        for (int ni = 0; ni < 4; ni++)
          o[mi][ni] = __builtin_amdgcn_mfma_f32_16x16x32_bf16(af2[mi], bf2[ni], o[mi][ni], 0, 0, 0);
    }
    __syncthreads();
  }
  #pragma unroll
  for (int mi = 0; mi < 2; mi++)
    #pragma unroll
    for (int ni = 0; ni < 4; ni++)
      #pragma unroll
      for (int j = 0; j < 4; j++){
        int row = bm + wr*32 + mi*16 + lk*4 + j;
        int col = wc*64 + ni*16 + lr;
        Xp[(size_t)row*128 + col] += o[mi][ni][j];
      }
}

// ---------------- contiguous segment-sum of permuted VS rows (vectorized) ----------------
__global__ __launch_bounds__(256) void k_aggseg(const u16* __restrict__ VS, const int* __restrict__ rowptr,
                                                int p0, int p1, int first, float* __restrict__ agg){
  int n = blockIdx.x;
  int a = rowptr[n], b = rowptr[n+1];
  if (a < p0) a = p0;
  if (b > p1) b = p1;
  int tid = threadIdx.x;
  for (int g = tid; g < 464; g += 256){          // 29*128/8 = 464 groups of 8
    size_t obase = (size_t)n*29*128 + (size_t)g*8;
    float s[8];
    if (first){
      #pragma unroll
      for (int j = 0; j < 8; j++) s[j] = 0.f;
    } else {
      float4 lo = *(const float4*)&agg[obase];
      float4 hi = *(const float4*)&agg[obase + 4];
      s[0]=lo.x; s[1]=lo.y; s[2]=lo.z; s[3]=lo.w;
      s[4]=hi.x; s[5]=hi.y; s[6]=hi.z; s[7]=hi.w;
    }
    for (int p = a; p < b; p++){
      uint4 q = *(const uint4*)&VS[(size_t)(p - p0)*3712 + (size_t)g*8];
      const u16* qp = (const u16*)&q;
      #pragma unroll
      for (int j = 0; j < 8; j++) s[j] += bf2f(qp[j]);
    }
    float4 lo, hi;
    lo.x=s[0]; lo.y=s[1]; lo.z=s[2]; lo.w=s[3];
    hi.x=s[4]; hi.y=s[5]; hi.z=s[6]; hi.w=s[7];
    *(float4*)&agg[obase] = lo;
    *(float4*)&agg[obase + 4] = hi;
  }
}

// ---------------- node init ----------------
__global__ __launch_bounds__(128) void k_init(const float* __restrict__ pos, const float* __restrict__ table,
                                              const float* __restrict__ Yb, const float* __restrict__ radd,
                                              const int* __restrict__ rowptr, const int* __restrict__ eid,
                                              float* __restrict__ x){
  int n = blockIdx.x;
  int c = threadIdx.x;
  const float DLO = -3.26267f;
  const float DRG = (float)(3.295396 - (-3.26267));
  float p0 = pos[n*3+0], p1 = pos[n*3+1], p2 = pos[n*3+2];
  int t0 = min(127, max(0, (int)rintf((p0 - DLO)/DRG*128.f - 0.5f)));
  int t1 = min(127, max(0, (int)rintf((p1 - DLO)/DRG*128.f - 0.5f)));
  int t2 = min(127, max(0, (int)rintf((p2 - DLO)/DRG*128.f - 0.5f)));
  float emb = table[t0*CD + c] + table[t1*CD + c] + table[t2*CD + c];
  __shared__ float Yl[49];
  __shared__ float rl[896];
  float acc[NCO];
  #pragma unroll
  for (int k = 0; k < NCO; k++) acc[k] = 0.f;
  int pA = rowptr[n], pB = rowptr[n+1];
  for (int p = pA; p < pB; p++){
    int e = eid[p];
    if (c < 49) Yl[c] = Yb[(size_t)e*49 + c];
    #pragma unroll
    for (int q = 0; q < 7; q++) rl[q*128 + c] = radd[(size_t)e*896 + q*128 + c];
    __syncthreads();
    #pragma unroll
    for (int k = 0; k < NCO; k++){
      acc[k] += Yl[k]*rl[deg_of(k)*128 + c];
    }
    __syncthreads();
  }
  size_t base = (size_t)n*NCO*CD;
  x[base + c] = emb + acc[0]*(1.f/3.f);
  #pragma unroll
  for (int k = 1; k < NCO; k++) x[base + k*CD + c] = acc[k]*(1.f/3.f);
}

// ---------------- degree-grouped RMS norm, bf16 out (full 49 rows, for FFN) ----------------
__global__ __launch_bounds__(128) void k_rmsnorm(const float* __restrict__ x, const float* __restrict__ w,
                                                 u16* __restrict__ out){
  int n = blockIdx.x;
  int c = threadIdx.x;
  const float* xb = x + (size_t)n*NCO*CD;
  float vals[NCO];
  float ss[7] = {0,0,0,0,0,0,0};
  #pragma unroll
  for (int k = 0; k < NCO; k++){
    float v = xb[k*CD + c];
    vals[k] = v;
    ss[deg_of(k)] += v*v;
  }
  __shared__ float red[7][128];
  #pragma unroll
  for (int l = 0; l < 7; l++) red[l][c] = ss[l];
  __syncthreads();
  __shared__ float inv[7];
  if (c < 7){
    float s = 0.f;
    for (int i = 0; i < 128; i++) s += red[c][i];
    float ms = s / ((float)(2*c + 1)*128.f);
    inv[c] = 1.f / sqrtf(ms + 1e-6f);
  }
  __syncthreads();
  size_t base = (size_t)n*NCO*CD;
  #pragma unroll
  for (int k = 0; k < NCO; k++){
    int l = deg_of(k);
    out[base + k*CD + c] = f2bf(vals[k]*inv[l]*w[l*CD + c]);
  }
}

// ---------------- RMS norm writing restricted 29 rows, bf16 out ----------------
__global__ __launch_bounds__(128) void k_rmsnormR(const float* __restrict__ x, const float* __restrict__ w,
                                                  u16* __restrict__ hr){
  int n = blockIdx.x;
  int c = threadIdx.x;
  const float* xb = x + (size_t)n*NCO*CD;
  float vals[NCO];
  float ss[7] = {0,0,0,0,0,0,0};
  #pragma unroll
  for (int k = 0; k < NCO; k++){
    float v = xb[k*CD + c];
    vals[k] = v;
    ss[deg_of(k)] += v*v;
  }
  __shared__ float red[7][128];
  #pragma unroll
  for (int l = 0; l < 7; l++) red[l][c] = ss[l];
  __syncthreads();
  __shared__ float inv[7];
  if (c < 7){
    float s = 0.f;
    for (int i = 0; i < 128; i++) s += red[c][i];
    float ms = s / ((float)(2*c + 1)*128.f);
    inv[c] = 1.f / sqrtf(ms + 1e-6f);
  }
  __syncthreads();
  size_t base = (size_t)n*NRr*CD;
  #pragma unroll
  for (int kr = 0; kr < NRr; kr++){
    int k = d_RES[kr];
    int l = deg_of(k);
    hr[base + kr*CD + c] = f2bf(vals[k]*inv[l]*w[l*CD + c]);
  }
}

// ---------------- fused attention: logits + segment softmax + alpha ----------------
__global__ __launch_bounds__(256) void k_attn(
    const u16* __restrict__ XST, const float* __restrict__ rad, const float* __restrict__ avec,
    const int* __restrict__ src, const int* __restrict__ rowptr, const int* __restrict__ eid,
    float* __restrict__ AL)
{
  int n = blockIdx.x;
  int p0 = rowptr[n], p1 = rowptr[n+1];
  int deg = p1 - p0;
  if (deg == 0) return;
  __shared__ float lgs[64][8];
  __shared__ float xt0[128];
  __shared__ float av[128];
  __shared__ float mxs[8], dens[8];
  int tid = threadIdx.x;
  if (tid < 128){
    xt0[tid] = bf2f(XST[(size_t)n*NRr*256 + 128 + tid]);
    av[tid] = avec[tid];
  }
  __syncthreads();
  for (int pair = tid; pair < deg*8; pair += 256){
    int pl = pair >> 3, h = pair & 7;
    int e = eid[p0 + pl];
    int s = src[e];
    const u16* xs = &XST[(size_t)s*NRr*256 + h*16];
    uint4 q0 = *(const uint4*)xs;
    uint4 q1 = *(const uint4*)(xs + 8);
    const u16* x0 = (const u16*)&q0;
    const u16* x1 = (const u16*)&q1;
    const float* rd = &rad[(size_t)e*128 + h*16];
    float4 r0 = *(const float4*)(rd + 0);
    float4 r1 = *(const float4*)(rd + 4);
    float4 r2 = *(const float4*)(rd + 8);
    float4 r3 = *(const float4*)(rd + 12);
    float rr[16] = {r0.x,r0.y,r0.z,r0.w, r1.x,r1.y,r1.z,r1.w,
                    r2.x,r2.y,r2.z,r2.w, r3.x,r3.y,r3.z,r3.w};
    float acc = 0.f;
    #pragma unroll
    for (int d = 0; d < 8; d++){
      float m = (bf2f(x0[d]) + xt0[h*16 + d]) * rr[d];
      acc += siluf(m) * av[h*16 + d];
    }
    #pragma unroll
    for (int d = 0; d < 8; d++){
      float m = (bf2f(x1[d]) + xt0[h*16 + 8 + d]) * rr[8 + d];
      acc += siluf(m) * av[h*16 + 8 + d];
    }
    lgs[pl][h] = acc;
  }
  __syncthreads();
  if (tid < 8){
    float m = -1e30f;
    for (int pl = 0; pl < deg; pl++) m = fmaxf(m, lgs[pl][tid]);
    float sden = 0.f;
    for (int pl = 0; pl < deg; pl++) sden += expf(lgs[pl][tid] - m);
    mxs[tid] = m; dens[tid] = sden;
  }
  __syncthreads();
  for (int pair = tid; pair < deg*8; pair += 256){
    int pl = pair >> 3, h = pair & 7;
    int e = eid[p0 + pl];
    AL[e*8 + h] = expf(lgs[pl][h] - mxs[h]) / fmaxf(dens[h], 1e-9f);
  }
}

// ---------------- pooling ----------------
__global__ void k_pool(const float* __restrict__ orr, const int* __restrict__ gs, float* __restrict__ out){
  int i = blockIdx.x*blockDim.x + threadIdx.x;
  if (i >= NG*NCO*CD) return;
  int c = i & 127;
  int k = (i >> 7) % 49;
  int g = i / (49*128);
  int kr = c_rinv[k];
  float v = 0.f;
  if (kr >= 0){
    int a = gs[g], b = gs[g+1];
    float s = 0.f;
    for (int n = a; n < b; n++) s += orr[((size_t)n*29 + kr)*128 + c];
    int cnt = b - a;
    v = s / (float)(cnt > 0 ? cnt : 1);
  }
  out[i] = v;
}

extern "C" void kernel_launch(void* const* d_in, const int* in_sizes, int n_in,
                              void* d_out, int out_size, void* d_ws, size_t ws_size,
                              hipStream_t stream){
  const float* pos    = (const float*)d_in[0];
  const float* evec   = (const float*)d_in[1];
  const int*   eidx   = (const int*)  d_in[2];
  const int*   batch  = (const int*)  d_in[3];
  const float* table  = (const float*)d_in[4];
  const float* deg_w1 = (const float*)d_in[5];
  const float* deg_b1 = (const float*)d_in[6];
  const float* deg_w2 = (const float*)d_in[7];
  const float* deg_b2 = (const float*)d_in[8];
  const float* deg_w3 = (const float*)d_in[9];
  const float* attn_nw= (const float*)d_in[10];
  const float* w_src  = (const float*)d_in[11];
  const float* w_tgt  = (const float*)d_in[12];
  const float* rad_w1 = (const float*)d_in[13];
  const float* rad_b1 = (const float*)d_in[14];
  const float* rad_w2 = (const float*)d_in[15];
  const float* avec   = (const float*)d_in[16];
  const float* w_val  = (const float*)d_in[17];
  const float* w_proj = (const float*)d_in[18];
  const float* ffn_nw = (const float*)d_in[19];
  const float* ffn_w1 = (const float*)d_in[20];
  const float* ffn_w2 = (const float*)d_in[21];
  const float* fin_nw = (const float*)d_in[22];
  const float* lw_src = (const float*)d_in[23];
  const float* lw_tgt = (const float*)d_in[24];
  const float* lrad_w1= (const float*)d_in[25];
  const float* lrad_b1= (const float*)d_in[26];
  const float* lrad_w2= (const float*)d_in[27];
  const float* lavec  = (const float*)d_in[28];
  const float* lw_val = (const float*)d_in[29];
  const float* lw_proj= (const float*)d_in[30];

  const int* srcp = eidx;
  const int* dstp = eidx + NE;

  // ws budget: 256 MiB = 67.1M f32-slots. Layout below totals ~56M (audited).
  float* W = (float*)d_ws;
  size_t o = 0;
  float* X    = W + o; o += (size_t)NN*49*128;   // 12.85M
  float* Hb   = W + o; o += (size_t)NN*49*128;   // 12.85M: RADD, VS chunks, latent proj out, FFN rmsnorm(bf16)
  float* HR   = W + o; o += (size_t)NN*29*128;   // 7.60M: rmsnormR(bf16) out, AG
  float* XSTf = W + o; o += (size_t)NN*29*256/2; // 7.60M: XST bf16 (u16)
  float* Yb   = W + o; o += (size_t)NE*49;       // 0.60M
  float* DV   = W + o; o += (size_t)NE;
  float* AL   = W + o; o += (size_t)NE*8;
  float* SG   = W + o; o += (size_t)NN*512;      // 1.05M
  int* CNT = (int*)(W + o); o += NN;
  int* RP  = (int*)(W + o); o += NN + 1;
  int* EID = (int*)(W + o); o += NE;
  int* GS  = (int*)(W + o); o += NG + 1;
  int* CH  = (int*)(W + o); o += 4*NN;
  float* R1A = W + o; o += (size_t)4*NE*128;     // 6.29M: batched radial layer-1 (3 attn + deg)
  float* R2A = W + o; o += (size_t)4*NE*128;     // 6.29M: batched radial layer-2
  // bf16 transposed weights (~0.32M f32-slots)
  u16* WB = (u16*)(W + o);
  size_t wo = 0;
  u16* T_degw2 = WB + wo; wo += 16384;
  u16* T_degw3 = WB + wo; wo += 114688;
  u16* T_wst[3]; u16* T_wv[3]; u16* T_wp[3]; u16* T_rw2[3];
  for (int i = 0; i < 3; i++){ T_wst[i] = WB + wo; wo += 32768; }   // [256][128]
  for (int i = 0; i < 3; i++){ T_wv[i] = WB + wo; wo += 16384; }
  for (int i = 0; i < 3; i++){ T_wp[i] = WB + wo; wo += 16384; }
  for (int i = 0; i < 3; i++){ T_rw2[i] = WB + wo; wo += 16384; }
  u16* T_f1[2]; u16* T_f2[2];
  for (int i = 0; i < 2; i++){ T_f1[i] = WB + wo; wo += 65536; }
  for (int i = 0; i < 2; i++){ T_f2[i] = WB + wo; wo += 65536; }
  (void)ws_size; (void)in_sizes; (void)n_in; (void)out_size;

  u16*  XSTw = (u16*)XSTf;                        // [NN][29][256] bf16
  u16*  HRw  = (u16*)HR;                          // rmsnormR bf16 out
  u16*  Hbw  = (u16*)Hb;                          // FFN rmsnorm bf16 out (first half of Hb)
  float* RADD = Hb;                               // E*896 = 11.0M <= Hb; free before layers
  u16*  VS    = (u16*)Hb;                         // VCH_E*29*128 u16 = 11.4M f32 <= Hb
  float* AG   = HR;
  float* OR_  = Hb;                               // latent proj out (after aggseg done)

  // ---- all weight casts in one launch ----
  {
    CastJobs J;
    int idx = 0, acc = 0;
    auto add = [&](const float* s, u16* d, int K, int N){
      J.src[idx] = s; J.dst[idx] = d; J.K[idx] = K; J.N[idx] = N; J.start[idx] = acc;
      acc += K*N; idx++;
    };
    add(deg_w2, T_degw2, 128, 128);
    add(deg_w3, T_degw3, 128, 896);
    for (int i = 0; i < 3; i++){
      add((i < 2) ? w_src  + (size_t)i*16384 : lw_src,  T_wst[i],          128, 128);
      add((i < 2) ? w_tgt  + (size_t)i*16384 : lw_tgt,  T_wst[i] + 16384,  128, 128);
      add((i < 2) ? w_val  + (size_t)i*16384 : lw_val,  T_wv[i], 128, 128);
      add((i < 2) ? w_proj + (size_t)i*16384 : lw_proj, T_wp[i], 128, 128);
      add((i < 2) ? rad_w2 + (size_t)i*16384 : lrad_w2, T_rw2[i], 128, 128);
    }
    for (int i = 0; i < 2; i++){
      add(ffn_w1 + (size_t)i*65536, T_f1[i], 128, 512);
      add(ffn_w2 + (size_t)i*65536, T_f2[i], 512, 128);
    }
    J.start[idx] = acc; J.total = acc;
    k_castall<<<(acc + 255)/256, 256, 0, stream>>>(J);
  }

  // CSR + groups
  k_hist4<<<1, 1024, 0, stream>>>(dstp, CNT, CH);
  k_scan2<<<1, 1024, 0, stream>>>(CNT, RP);
  k_fillw4<<<NN, 256, 0, stream>>>(dstp, RP, CH, EID);
  k_gstart<<<1, 32, 0, stream>>>(batch, GS);

  // geometry
  k_geom<<<48, 256, 0, stream>>>(evec, Yb, DV);

  // fused radial layer-1 for all 4 MLPs (3 attn + degree), then batched layer-2
  k_rad14<<<NE, 128, 0, stream>>>(DV,
      rad_w1, rad_w1 + 76800, lrad_w1, deg_w1,
      rad_b1, rad_b1 + 128,   lrad_b1, deg_b1, R1A);
  k_rgemm<<<dim3(1, NE/64, 4), 256, 0, stream>>>(R1A, T_rw2[0], T_rw2[1], T_rw2[2], T_degw2, deg_b2, R2A);

  // degree embedding layer-3 (896-wide) + node init
  k_mgemm<0,0,2><<<dim3(7, NE/64), 256, 0, stream>>>(R2A + (size_t)3*NE*128, T_degw3, nullptr, RADD,
                                                     NE, 896, 128, 128,
                                                     nullptr, nullptr, nullptr, nullptr, nullptr, 0);
  k_init<<<NN, 128, 0, stream>>>(pos, table, Yb, RADD, RP, EID, X);

  for (int i = 0; i < 3; i++){
    const float* nw  = (i < 2) ? attn_nw + (size_t)i*896 : fin_nw;
    const float* av  = (i < 2) ? avec   + (size_t)i*128  : lavec;
    const float* R2L = R2A + (size_t)i*NE*128;

    k_rmsnormR<<<NN, 128, 0, stream>>>(X, nw, HRw);
    // combined XS|XT projection, bf16 output
    k_mgemm<2,6,4><<<dim3(1, NN*NRr/64), 256, 0, stream>>>(HRw, T_wst[i], nullptr, XSTw, NN*NRr, 256, 128, 128,
                                                           nullptr, nullptr, nullptr, nullptr, nullptr, 0);
    // fused logits + softmax + alpha
    k_attn<<<NN, 256, 0, stream>>>(XSTw, R2L, av, srcp, RP, EID, AL);
    // V in CSR-permuted order, alpha-fused epilogue, then contiguous segment-sum
    for (int ch = 0; ch < NE/VCH_E; ch++){
      int p0 = ch*VCH_E;
      k_mgemm<3,7,2><<<dim3(1, VCH_E*NRr/64), 256, 0, stream>>>(R2L, T_wv[i], nullptr, VS,
                                                                VCH_E*NRr, 128, 128, 128,
                                                                (const float*)XSTw, srcp, dstp, EID, AL, p0);
      k_aggseg<<<NN, 256, 0, stream>>>(VS, RP, p0, p0 + VCH_E, ch == 0, AG);
    }
    if (i < 2){
      // projection with fused scatter-accumulate into X
      k_mgemm<0,3,2><<<dim3(1, NN*NRr/64), 256, 0, stream>>>(AG, T_wp[i], nullptr, X, NN*NRr, 128, 128, 128,
                                                             nullptr, nullptr, nullptr, nullptr, nullptr, 0);
      // FFN: gate from row0, hidden kept in LDS (fused GEMM1+gate+GEMM2, 8-wave M=128)
      k_rmsnorm<<<NN, 128, 0, stream>>>(X, ffn_nw + (size_t)i*896, Hbw);
      k_mgemm<2,4,1><<<dim3(8, NN/64), 256, 0, stream>>>(Hbw, T_f1[i], nullptr, SG, NN, 512, 128, NCO*CD,
                                                         nullptr, nullptr, nullptr, nullptr, nullptr, 0);
      k_ffn<<<NN*NCO/128, 512, 0, stream>>>(Hbw, T_f1[i], T_f2[i], SG, X);
    } else {
      k_mgemm<0,0,2><<<dim3(1, NN*NRr/64), 256, 0, stream>>>(AG, T_wp[i], nullptr, OR_, NN*NRr, 128, 128, 128,
                                                             nullptr, nullptr, nullptr, nullptr, nullptr, 0);
      k_pool<<<(NG*NCO*CD + 255)/256, 256, 0, stream>>>(OR_, GS, (float*)d_out);
    }
  }
}

// Round 21
// 843.683 us; speedup vs baseline: 1.2544x; 1.0081x over previous
//
#include <hip/hip_runtime.h>
#include <math.h>

#define NN 2048
#define NE 12288
#define NCO 49
#define NRr 29
#define CD 128
#define NG 16
#define NJOBS 21
#define VCH_E 6144   // edges per V chunk (permuted positions)

typedef unsigned short u16;
typedef short bhalf8 __attribute__((ext_vector_type(8)));
typedef float fvec4 __attribute__((ext_vector_type(4)));

// RESTRICT: indices k (0..48) with |m|<=2.
__constant__ int c_res[29] = {0,1,2,3,4,5,6,7,8,10,11,12,13,14,18,19,20,21,22,28,29,30,31,32,40,41,42,43,44};
__constant__ int c_rinv[49] = {0,1,2,3,4,5,6,7,8,-1,9,10,11,12,13,-1,-1,-1,14,15,16,17,18,-1,-1,-1,-1,-1,19,20,21,22,23,-1,-1,-1,-1,-1,-1,-1,24,25,26,27,28,-1,-1,-1,-1};
__device__ constexpr int d_RES[29] = {0,1,2,3,4,5,6,7,8,10,11,12,13,14,18,19,20,21,22,28,29,30,31,32,40,41,42,43,44};

__device__ __forceinline__ constexpr int deg_of(int k){
  return (k<1)?0:(k<4)?1:(k<9)?2:(k<16)?3:(k<25)?4:(k<36)?5:6;
}
__device__ __forceinline__ float siluf(float x){ return x / (1.f + expf(-x)); }
__device__ __forceinline__ u16 f2bf(float f){
  unsigned int u = __float_as_uint(f);
  unsigned int r = (u + 0x7FFFu + ((u >> 16) & 1u)) >> 16;
  return (u16)r;
}
__device__ __forceinline__ float bf2f(u16 b){
  return __uint_as_float(((unsigned int)b) << 16);
}
__device__ __forceinline__ unsigned int pk(u16 lo, u16 hi){ return (unsigned int)lo | ((unsigned int)hi << 16); }

// ---------------- CSR build (deterministic, parallel) ----------------
__global__ __launch_bounds__(1024) void k_hist4(const int* __restrict__ dst, int* __restrict__ cnt,
                                                int* __restrict__ CH){
  __shared__ int h[4*NN];
  for (int i = threadIdx.x; i < 4*NN; i += 1024) h[i] = 0;
  __syncthreads();
  const int QE = NE/4;
  for (int e = threadIdx.x; e < NE; e += 1024){
    int q = e / QE;
    atomicAdd(&h[q*NN + dst[e]], 1);
  }
  __syncthreads();
  for (int n = threadIdx.x; n < NN; n += 1024){
    int s = 0;
    #pragma unroll
    for (int q = 0; q < 4; q++){ int v = h[q*NN + n]; CH[q*NN + n] = v; s += v; }
    cnt[n] = s;
  }
}
__global__ __launch_bounds__(1024) void k_scan2(const int* __restrict__ cnt, int* __restrict__ rowptr){
  __shared__ int a[NN], b[NN];
  int t = threadIdx.x;
  for (int i = t; i < NN; i += 1024) a[i] = cnt[i];
  __syncthreads();
  int* pin = a; int* pout = b;
  for (int off = 1; off < NN; off <<= 1){
    for (int i = t; i < NN; i += 1024)
      pout[i] = pin[i] + ((i >= off) ? pin[i - off] : 0);
    __syncthreads();
    int* tmp = pin; pin = pout; pout = tmp;
  }
  for (int i = t; i < NN; i += 1024) rowptr[i + 1] = pin[i];
  if (t == 0) rowptr[0] = 0;
}
__global__ __launch_bounds__(256) void k_fillw4(const int* __restrict__ dst, const int* __restrict__ rowptr,
                                                const int* __restrict__ CH, int* __restrict__ eid){
  int q = threadIdx.x >> 6, lane = threadIdx.x & 63;
  int n = blockIdx.x;
  int base = rowptr[n];
  for (int qq = 0; qq < q; qq++) base += CH[qq*NN + n];
  const int QE = NE/4;
  for (int e0 = q*QE; e0 < (q+1)*QE; e0 += 64){
    int e = e0 + lane;
    bool m = (dst[e] == n);
    unsigned long long mask = __ballot(m);
    if (m) eid[base + __popcll(mask & ((1ull << lane) - 1ull))] = e;
    base += __popcll(mask);
  }
}
__global__ void k_gstart(const int* __restrict__ batch, int* __restrict__ gs){
  int g = threadIdx.x;
  if (g > NG) return;
  int lo = 0, hi = NN;
  while (lo < hi){ int mid = (lo + hi) >> 1; if (batch[mid] < g) lo = mid + 1; else hi = mid; }
  gs[g] = lo;
}

// ---------------- all weight casts in one launch: [K][N] f32 -> [N][K] bf16 ----------------
struct CastJobs {
  const float* src[NJOBS];
  u16* dst[NJOBS];
  int K[NJOBS], N[NJOBS];
  int start[NJOBS + 1];
  int total;
};
__global__ void k_castall(CastJobs J){
  int i = blockIdx.x*blockDim.x + threadIdx.x;
  if (i >= J.total) return;
  int j = 0;
  while (i >= J.start[j + 1]) j++;
  int local = i - J.start[j];
  int K = J.K[j], N = J.N[j];
  int n = local / K, k = local - n*K;
  J.dst[j][local] = f2bf(J.src[j][(size_t)k*N + n]);
}

// ---------------- geometry ----------------
__global__ void k_geom(const float* __restrict__ ev, float* __restrict__ Y, float* __restrict__ dv){
  int e = blockIdx.x*blockDim.x + threadIdx.x;
  if (e >= NE) return;
  float x = ev[e*3+0], y = ev[e*3+1], z = ev[e*3+2];
  float r = sqrtf(x*x + y*y + z*z);
  dv[e] = r;
  float rn = fmaxf(r, 1e-8f);
  float ux = x/rn, uy = y/rn, uz = z/rn;
  float ct = fminf(fmaxf(uz, -1.f), 1.f);
  float st = sqrtf(fminf(fmaxf(1.f - ct*ct, 1e-12f), 1.f));
  float phi = atan2f(uy, ux);
  float P[7][7];
  P[0][0] = 1.f;
  #pragma unroll
  for (int m = 1; m <= 6; m++) P[m][m] = -(2.f*m - 1.f)*st*P[m-1][m-1];
  #pragma unroll
  for (int m = 0; m <= 5; m++) P[m+1][m] = (2.f*m + 1.f)*ct*P[m][m];
  #pragma unroll
  for (int m = 0; m <= 6; m++){
    #pragma unroll
    for (int l = m+2; l <= 6; l++)
      P[l][m] = ((2.f*l - 1.f)*ct*P[l-1][m] - (float)(l+m-1)*P[l-2][m]) / (float)(l-m);
  }
  float cmv[7], smv[7];
  #pragma unroll
  for (int m = 0; m <= 6; m++){ cmv[m] = cosf((float)m*phi); smv[m] = sinf((float)m*phi); }
  const double FOURPI = 12.566370614359172;
  int k = 0;
  #pragma unroll
  for (int l = 0; l <= 6; l++){
    #pragma unroll
    for (int mm = -l; mm <= l; mm++){
      int am = mm < 0 ? -mm : mm;
      double ratio = 1.0;
      for (int i = l-am+1; i <= l+am; i++) ratio /= (double)i;
      double nrm = sqrt((2.0*l + 1.0)/FOURPI*ratio);
      float v;
      if (mm == 0)      v = (float)nrm * P[l][0];
      else if (mm > 0)  v = (float)(1.4142135623730951*nrm) * P[l][am] * cmv[am];
      else              v = (float)(1.4142135623730951*nrm) * P[l][am] * smv[am];
      Y[(size_t)e*49 + k] = v; k++;
    }
  }
}

// ------------- fused layer-1 of ALL FOUR radial MLPs (3 attn + degree) -------------
__global__ __launch_bounds__(128) void k_rad14(const float* __restrict__ dv,
    const float* __restrict__ W0, const float* __restrict__ W1,
    const float* __restrict__ W2, const float* __restrict__ W3,
    const float* __restrict__ bp0, const float* __restrict__ bp1,
    const float* __restrict__ bp2, const float* __restrict__ bp3,
    float* __restrict__ out){
  int e = blockIdx.x;
  int j = threadIdx.x;
  float d = dv[e];
  const float STEPF = (float)(5.0/599.0);
  const double step_d = (double)STEPF;
  const float GC = (float)(-0.5/((2.0*step_d)*(2.0*step_d)));
  __shared__ float g[64];
  int bc = (int)rintf(d / STEPF);
  int wb0 = bc - 32;
  if (j < 64){
    int b = wb0 + j;
    float gg = 0.f;
    if (b >= 0 && b < 600){
      float off = (float)((double)b * (5.0/599.0));
      float t = d - off;
      gg = expf(GC*t*t);
    }
    g[j] = gg;
  }
  __syncthreads();
  int lo = (wb0 < 0) ? -wb0 : 0;
  int hi = (wb0 > 536) ? (600 - wb0) : 64;
  float a0 = bp0[j], a1 = bp1[j], a2 = bp2[j], a3 = bp3[j];
  const float* w0 = W0 + (size_t)(wb0 + lo)*CD + j;
  const float* w1 = W1 + (size_t)(wb0 + lo)*CD + j;
  const float* w2 = W2 + (size_t)(wb0 + lo)*CD + j;
  const float* w3 = W3 + (size_t)(wb0 + lo)*CD + j;
  for (int i = lo; i < hi; i++){
    float gg = g[i];
    a0 += gg*(*w0); a1 += gg*(*w1); a2 += gg*(*w2); a3 += gg*(*w3);
    w0 += CD; w1 += CD; w2 += CD; w3 += CD;
  }
  out[((size_t)0*NE + e)*CD + j] = siluf(a0);
  out[((size_t)1*NE + e)*CD + j] = siluf(a1);
  out[((size_t)2*NE + e)*CD + j] = siluf(a2);
  out[((size_t)3*NE + e)*CD + j] = siluf(a3);
}

// ---------------- MFMA bf16 GEMM with NT column-tiles per block ----------------
// AMODE: 0 = f32 A (runtime lda); 2 = bf16 A (runtime lda);
//        3 = permuted fused-message A.
// EPI:   0 store(+bias); 1 silu(+bias); 2 accumulate; 3 scatter-accum into X;
//        4 sigmoid store; 5 gate-mul (P0=SG) then bf16 store; 6 bf16 store;
//        7 alpha-scale (ALp, permuted via eidp) then bf16 store (VS).
template<int AMODE, int EPI, int NT>
__global__ __launch_bounds__(256) void k_mgemm(
    const void* __restrict__ Av, const u16* __restrict__ Bt,
    const float* __restrict__ bias, void* __restrict__ Cv,
    int M, int N, int K, int lda,
    const float* __restrict__ P0,
    const int* __restrict__ src, const int* __restrict__ dstp,
    const int* __restrict__ eidp, const float* __restrict__ ALp, int e0)
{
  __shared__ __align__(16) u16 Asl[64*64];
  __shared__ __align__(16) u16 Bsl[NT][64*64];
  int tid = threadIdx.x;
  int bm = blockIdx.y*64;
  int bn0 = blockIdx.x*NT*64;
  int wid = tid >> 6, lane = tid & 63;
  int wr = wid >> 1, wc = wid & 1;
  int lr = lane & 15, lk = lane >> 4;
  fvec4 acc[NT][2][2] = {};
  for (int k0 = 0; k0 < K; k0 += 64){
    #pragma unroll
    for (int h = 0; h < 2; h++){
      int lin = tid + h*256;          // 0..511: 64 rows x 8 k-groups
      int row = lin >> 3, kg = lin & 7;
      uint4 q;
      if (AMODE == 3){
        int gr = bm + row;
        int el = gr / 29, kq = gr - el*29;
        int p = e0 + el;
        int e = eidp[p];
        int s = src[e], t = dstp[e];
        const u16* xst = (const u16*)P0;
        uint4 xs8 = *(const uint4*)&xst[((size_t)s*29 + kq)*256 + k0 + kg*8];
        uint4 xt8 = *(const uint4*)&xst[((size_t)t*29 + kq)*256 + 128 + k0 + kg*8];
        const float* rd = (const float*)Av + (size_t)e*128 + k0 + kg*8;
        const u16* xsp = (const u16*)&xs8;
        const u16* xtp = (const u16*)&xt8;
        u16 ov[8];
        #pragma unroll
        for (int j = 0; j < 8; j++)
          ov[j] = f2bf((bf2f(xsp[j]) + bf2f(xtp[j])) * rd[j]);
        q.x = pk(ov[0], ov[1]); q.y = pk(ov[2], ov[3]);
        q.z = pk(ov[4], ov[5]); q.w = pk(ov[6], ov[7]);
      } else if (AMODE == 2){
        const u16* ap = (const u16*)Av + (size_t)(bm + row)*lda + k0 + kg*8;
        q = *(const uint4*)ap;
      } else {
        const float* ap = (const float*)Av + (size_t)(bm + row)*lda + k0 + kg*8;
        float v[8];
        #pragma unroll
        for (int j = 0; j < 8; j++) v[j] = ap[j];
        q.x = pk(f2bf(v[0]), f2bf(v[1]));
        q.y = pk(f2bf(v[2]), f2bf(v[3]));
        q.z = pk(f2bf(v[4]), f2bf(v[5]));
        q.w = pk(f2bf(v[6]), f2bf(v[7]));
      }
      *(uint4*)&Asl[row*64 + ((kg*8) ^ ((row & 7)*8))] = q;
    }
    #pragma unroll
    for (int t = 0; t < NT; t++){
      #pragma unroll
      for (int h = 0; h < 2; h++){
        int lin = tid + h*256;
        int row = lin >> 3, kg = lin & 7;
        const u16* bp = Bt + (size_t)(bn0 + t*64 + row)*K + k0 + kg*8;
        *(uint4*)&Bsl[t][row*64 + ((kg*8) ^ ((row & 7)*8))] = *(const uint4*)bp;
      }
    }
    __syncthreads();
    #pragma unroll
    for (int ks = 0; ks < 2; ks++){
      int kg = ks*4 + lk;
      bhalf8 af[2];
      #pragma unroll
      for (int mi = 0; mi < 2; mi++){
        int ar = wr*32 + mi*16 + lr;
        af[mi] = *(const bhalf8*)&Asl[ar*64 + ((kg*8) ^ ((ar & 7)*8))];
      }
      #pragma unroll
      for (int t = 0; t < NT; t++){
        bhalf8 bfr[2];
        #pragma unroll
        for (int ni = 0; ni < 2; ni++){
          int br = wc*32 + ni*16 + lr;
          bfr[ni] = *(const bhalf8*)&Bsl[t][br*64 + ((kg*8) ^ ((br & 7)*8))];
        }
        #pragma unroll
        for (int mi = 0; mi < 2; mi++)
          #pragma unroll
          for (int ni = 0; ni < 2; ni++)
            acc[t][mi][ni] = __builtin_amdgcn_mfma_f32_16x16x32_bf16(af[mi], bfr[ni], acc[t][mi][ni], 0, 0, 0);
      }
    }
    __syncthreads();
  }
  #pragma unroll
  for (int t = 0; t < NT; t++){
    #pragma unroll
    for (int mi = 0; mi < 2; mi++){
      #pragma unroll
      for (int ni = 0; ni < 2; ni++){
        #pragma unroll
        for (int j = 0; j < 4; j++){
          int row = bm + wr*32 + mi*16 + lk*4 + j;
          int col = bn0 + t*64 + wc*32 + ni*16 + lr;
          float v = acc[t][mi][ni][j];
          if (EPI == 0){
            if (bias) v += bias[col];
            ((float*)Cv)[(size_t)row*N + col] = v;
          } else if (EPI == 1){
            if (bias) v += bias[col];
            ((float*)Cv)[(size_t)row*N + col] = siluf(v);
          } else if (EPI == 2){
            ((float*)Cv)[(size_t)row*N + col] += v;
          } else if (EPI == 3){
            int n = row / 29, kr = row - n*29;
            ((float*)Cv)[((size_t)n*49 + c_res[kr])*128 + col] += v;
          } else if (EPI == 4){
            ((float*)Cv)[(size_t)row*N + col] = 1.f/(1.f + expf(-v));
          } else if (EPI == 5){
            float g = P0[(size_t)(row/49)*N + col];
            ((u16*)Cv)[(size_t)row*N + col] = f2bf(v*g);
          } else if (EPI == 6){
            ((u16*)Cv)[(size_t)row*N + col] = f2bf(v);
          } else {
            int p = e0 + row/29;
            int e = eidp[p];
            float a = ALp[e*8 + (col >> 4)];
            ((u16*)Cv)[(size_t)row*N + col] = f2bf(v*a);
          }
        }
      }
    }
  }
}

// ---------------- batched radial layer-2 GEMM (z: 0..2 attn, 3 = degree w/bias+silu) ----------------
__global__ __launch_bounds__(256) void k_rgemm(
    const float* __restrict__ A, const u16* __restrict__ B0, const u16* __restrict__ B1,
    const u16* __restrict__ B2, const u16* __restrict__ B3,
    const float* __restrict__ degb2, float* __restrict__ C)
{
  __shared__ __align__(16) u16 Asl[64*64];
  __shared__ __align__(16) u16 Bsl[2][64*64];
  int tid = threadIdx.x;
  int l = blockIdx.z;
  int bm = blockIdx.y*64;
  const u16* Bt = (l == 0) ? B0 : (l == 1) ? B1 : (l == 2) ? B2 : B3;
  const float* Al = A + (size_t)l*NE*128;
  float* Cl = C + (size_t)l*NE*128;
  int wid = tid >> 6, lane = tid & 63;
  int wr = wid >> 1, wc = wid & 1;
  int lr = lane & 15, lk = lane >> 4;
  fvec4 acc[2][2][2] = {};
  for (int k0 = 0; k0 < 128; k0 += 64){
    #pragma unroll
    for (int h = 0; h < 2; h++){
      int lin = tid + h*256;
      int row = lin >> 3, kg = lin & 7;
      const float* ap = Al + (size_t)(bm + row)*128 + k0 + kg*8;
      float v[8];
      #pragma unroll
      for (int j = 0; j < 8; j++) v[j] = ap[j];
      uint4 q;
      q.x = pk(f2bf(v[0]), f2bf(v[1]));
      q.y = pk(f2bf(v[2]), f2bf(v[3]));
      q.z = pk(f2bf(v[4]), f2bf(v[5]));
      q.w = pk(f2bf(v[6]), f2bf(v[7]));
      *(uint4*)&Asl[row*64 + ((kg*8) ^ ((row & 7)*8))] = q;
    }
    #pragma unroll
    for (int t = 0; t < 2; t++){
      #pragma unroll
      for (int h = 0; h < 2; h++){
        int lin = tid + h*256;
        int row = lin >> 3, kg = lin & 7;
        const u16* bp = Bt + (size_t)(t*64 + row)*128 + k0 + kg*8;
        *(uint4*)&Bsl[t][row*64 + ((kg*8) ^ ((row & 7)*8))] = *(const uint4*)bp;
      }
    }
    __syncthreads();
    #pragma unroll
    for (int ks = 0; ks < 2; ks++){
      int kg = ks*4 + lk;
      bhalf8 af[2];
      #pragma unroll
      for (int mi = 0; mi < 2; mi++){
        int ar = wr*32 + mi*16 + lr;
        af[mi] = *(const bhalf8*)&Asl[ar*64 + ((kg*8) ^ ((ar & 7)*8))];
      }
      #pragma unroll
      for (int t = 0; t < 2; t++){
        bhalf8 bfr[2];
        #pragma unroll
        for (int ni = 0; ni < 2; ni++){
          int br = wc*32 + ni*16 + lr;
          bfr[ni] = *(const bhalf8*)&Bsl[t][br*64 + ((kg*8) ^ ((br & 7)*8))];
        }
        #pragma unroll
        for (int mi = 0; mi < 2; mi++)
          #pragma unroll
          for (int ni = 0; ni < 2; ni++)
            acc[t][mi][ni] = __builtin_amdgcn_mfma_f32_16x16x32_bf16(af[mi], bfr[ni], acc[t][mi][ni], 0, 0, 0);
      }
    }
    __syncthreads();
  }
  #pragma unroll
  for (int t = 0; t < 2; t++)
    #pragma unroll
    for (int mi = 0; mi < 2; mi++)
      #pragma unroll
      for (int ni = 0; ni < 2; ni++)
        #pragma unroll
        for (int j = 0; j < 4; j++){
          int row = bm + wr*32 + mi*16 + lk*4 + j;
          int col = t*64 + wc*32 + ni*16 + lr;
          float v = acc[t][mi][ni][j];
          if (l == 3){ v += degb2[col]; v = siluf(v); }
          Cl[(size_t)row*128 + col] = v;
        }
}

// ---------------- fused FFN, 8-wave M=128: X += ((bf16(A@W1)*gate)@W2) ----------------
__global__ __launch_bounds__(512) void k_ffn(
    const u16* __restrict__ A, const u16* __restrict__ W1, const u16* __restrict__ W2,
    const float* __restrict__ SGp, float* __restrict__ Xp)
{
  __shared__ __align__(16) u16 Asl[128*128];  // 32 KB
  __shared__ __align__(16) u16 W1s[64*128];   // 16 KB
  __shared__ __align__(16) u16 W2s[128*64];   // 16 KB
  __shared__ __align__(16) u16 Hs[128*64];    // 16 KB
  int tid = threadIdx.x;
  int bm = blockIdx.x*128;
  int wid = tid >> 6, lane = tid & 63;
  int wr = wid >> 1, wc = wid & 1;
  int lr = lane & 15, lk = lane >> 4;
  for (int g = tid; g < 2048; g += 512){
    int row = g >> 4, kg = g & 15;
    *(uint4*)&Asl[row*128 + ((kg*8) ^ ((row & 7)*16))] = *(const uint4*)&A[(size_t)(bm + row)*128 + kg*8];
  }
  fvec4 o[2][4] = {};
  for (int h0 = 0; h0 < 512; h0 += 64){
    for (int g = tid; g < 1024; g += 512){
      int row = g >> 4, kg = g & 15;
      *(uint4*)&W1s[row*128 + ((kg*8) ^ ((row & 7)*16))] = *(const uint4*)&W1[(size_t)(h0 + row)*128 + kg*8];
    }
    for (int g = tid; g < 1024; g += 512){
      int row = g >> 3, kg = g & 7;
      *(uint4*)&W2s[row*64 + ((kg*8) ^ ((row & 7)*8))] = *(const uint4*)&W2[(size_t)row*512 + h0 + kg*8];
    }
    __syncthreads();
    fvec4 hid[2][2] = {};
    #pragma unroll
    for (int kk = 0; kk < 4; kk++){
      int kg = kk*4 + lk;
      bhalf8 af[2], bf[2];
      #pragma unroll
      for (int mi = 0; mi < 2; mi++){
        int ar = wr*32 + mi*16 + lr;
        af[mi] = *(const bhalf8*)&Asl[ar*128 + ((kg*8) ^ ((ar & 7)*16))];
      }
      #pragma unroll
      for (int ni = 0; ni < 2; ni++){
        int br = wc*32 + ni*16 + lr;
        bf[ni] = *(const bhalf8*)&W1s[br*128 + ((kg*8) ^ ((br & 7)*16))];
      }
      #pragma unroll
      for (int mi = 0; mi < 2; mi++)
        #pragma unroll
        for (int ni = 0; ni < 2; ni++)
          hid[mi][ni] = __builtin_amdgcn_mfma_f32_16x16x32_bf16(af[mi], bf[ni], hid[mi][ni], 0, 0, 0);
    }
    #pragma unroll
    for (int mi = 0; mi < 2; mi++){
      #pragma unroll
      for (int j = 0; j < 4; j++){
        int row = wr*32 + mi*16 + lk*4 + j;
        int node = (bm + row)/49;
        const float* sgrow = &SGp[(size_t)node*512 + h0];
        #pragma unroll
        for (int ni = 0; ni < 2; ni++){
          int col = wc*32 + ni*16 + lr;
          Hs[row*64 + (col ^ ((row & 7)*8))] = f2bf(hid[mi][ni][j]*sgrow[col]);
        }
      }
    }
    __syncthreads();
    #pragma unroll
    for (int kk2 = 0; kk2 < 2; kk2++){
      int kg = kk2*4 + lk;
      bhalf8 af2[2], bf2[4];
      #pragma unroll
      for (int mi = 0; mi < 2; mi++){
        int ar = wr*32 + mi*16 + lr;
        af2[mi] = *(const bhalf8*)&Hs[ar*64 + ((kg*8) ^ ((ar & 7)*8))];
      }
      #pragma unroll
      for (int ni = 0; ni < 4; ni++){
        int br = wc*64 + ni*16 + lr;
        bf2[ni] = *(const bhalf8*)&W2s[br*64 + ((kg*8) ^ ((br & 7)*8))];
      }
      #pragma unroll
      for (int mi = 0; mi < 2; mi++)
        #pragma unroll
        for (int ni = 0; ni < 4; ni++)
          o[mi][ni] = __builtin_amdgcn_mfma_f32_16x16x32_bf16(af2[mi], bf2[ni], o[mi][ni], 0, 0, 0);
    }
    __syncthreads();
  }
  #pragma unroll
  for (int mi = 0; mi < 2; mi++)
    #pragma unroll
    for (int ni = 0; ni < 4; ni++)
      #pragma unroll
      for (int j = 0; j < 4; j++){
        int row = bm + wr*32 + mi*16 + lk*4 + j;
        int col = wc*64 + ni*16 + lr;
        Xp[(size_t)row*128 + col] += o[mi][ni][j];
      }
}

// ---------------- contiguous segment-sum of permuted VS rows (vectorized) ----------------
__global__ __launch_bounds__(256) void k_aggseg(const u16* __restrict__ VS, const int* __restrict__ rowptr,
                                                int p0, int p1, int first, float* __restrict__ agg){
  int n = blockIdx.x;
  int a = rowptr[n], b = rowptr[n+1];
  if (a < p0) a = p0;
  if (b > p1) b = p1;
  int tid = threadIdx.x;
  for (int g = tid; g < 464; g += 256){          // 29*128/8 = 464 groups of 8
    size_t obase = (size_t)n*29*128 + (size_t)g*8;
    float s[8];
    if (first){
      #pragma unroll
      for (int j = 0; j < 8; j++) s[j] = 0.f;
    } else {
      float4 lo = *(const float4*)&agg[obase];
      float4 hi = *(const float4*)&agg[obase + 4];
      s[0]=lo.x; s[1]=lo.y; s[2]=lo.z; s[3]=lo.w;
      s[4]=hi.x; s[5]=hi.y; s[6]=hi.z; s[7]=hi.w;
    }
    for (int p = a; p < b; p++){
      uint4 q = *(const uint4*)&VS[(size_t)(p - p0)*3712 + (size_t)g*8];
      const u16* qp = (const u16*)&q;
      #pragma unroll
      for (int j = 0; j < 8; j++) s[j] += bf2f(qp[j]);
    }
    float4 lo, hi;
    lo.x=s[0]; lo.y=s[1]; lo.z=s[2]; lo.w=s[3];
    hi.x=s[4]; hi.y=s[5]; hi.z=s[6]; hi.w=s[7];
    *(float4*)&agg[obase] = lo;
    *(float4*)&agg[obase + 4] = hi;
  }
}

// ---------------- node init ----------------
__global__ __launch_bounds__(128) void k_init(const float* __restrict__ pos, const float* __restrict__ table,
                                              const float* __restrict__ Yb, const float* __restrict__ radd,
                                              const int* __restrict__ rowptr, const int* __restrict__ eid,
                                              float* __restrict__ x){
  int n = blockIdx.x;
  int c = threadIdx.x;
  const float DLO = -3.26267f;
  const float DRG = (float)(3.295396 - (-3.26267));
  float p0 = pos[n*3+0], p1 = pos[n*3+1], p2 = pos[n*3+2];
  int t0 = min(127, max(0, (int)rintf((p0 - DLO)/DRG*128.f - 0.5f)));
  int t1 = min(127, max(0, (int)rintf((p1 - DLO)/DRG*128.f - 0.5f)));
  int t2 = min(127, max(0, (int)rintf((p2 - DLO)/DRG*128.f - 0.5f)));
  float emb = table[t0*CD + c] + table[t1*CD + c] + table[t2*CD + c];
  __shared__ float Yl[49];
  __shared__ float rl[896];
  float acc[NCO];
  #pragma unroll
  for (int k = 0; k < NCO; k++) acc[k] = 0.f;
  int pA = rowptr[n], pB = rowptr[n+1];
  for (int p = pA; p < pB; p++){
    int e = eid[p];
    if (c < 49) Yl[c] = Yb[(size_t)e*49 + c];
    #pragma unroll
    for (int q = 0; q < 7; q++) rl[q*128 + c] = radd[(size_t)e*896 + q*128 + c];
    __syncthreads();
    #pragma unroll
    for (int k = 0; k < NCO; k++){
      acc[k] += Yl[k]*rl[deg_of(k)*128 + c];
    }
    __syncthreads();
  }
  size_t base = (size_t)n*NCO*CD;
  x[base + c] = emb + acc[0]*(1.f/3.f);
  #pragma unroll
  for (int k = 1; k < NCO; k++) x[base + k*CD + c] = acc[k]*(1.f/3.f);
}

// ---------------- degree-grouped RMS norm, bf16 out (full 49 rows, for FFN) ----------------
__global__ __launch_bounds__(128) void k_rmsnorm(const float* __restrict__ x, const float* __restrict__ w,
                                                 u16* __restrict__ out){
  int n = blockIdx.x;
  int c = threadIdx.x;
  const float* xb = x + (size_t)n*NCO*CD;
  float vals[NCO];
  float ss[7] = {0,0,0,0,0,0,0};
  #pragma unroll
  for (int k = 0; k < NCO; k++){
    float v = xb[k*CD + c];
    vals[k] = v;
    ss[deg_of(k)] += v*v;
  }
  __shared__ float red[7][128];
  #pragma unroll
  for (int l = 0; l < 7; l++) red[l][c] = ss[l];
  __syncthreads();
  __shared__ float inv[7];
  if (c < 7){
    float s = 0.f;
    for (int i = 0; i < 128; i++) s += red[c][i];
    float ms = s / ((float)(2*c + 1)*128.f);
    inv[c] = 1.f / sqrtf(ms + 1e-6f);
  }
  __syncthreads();
  size_t base = (size_t)n*NCO*CD;
  #pragma unroll
  for (int k = 0; k < NCO; k++){
    int l = deg_of(k);
    out[base + k*CD + c] = f2bf(vals[k]*inv[l]*w[l*CD + c]);
  }
}

// ---------------- RMS norm writing restricted 29 rows, bf16 out ----------------
__global__ __launch_bounds__(128) void k_rmsnormR(const float* __restrict__ x, const float* __restrict__ w,
                                                  u16* __restrict__ hr){
  int n = blockIdx.x;
  int c = threadIdx.x;
  const float* xb = x + (size_t)n*NCO*CD;
  float vals[NCO];
  float ss[7] = {0,0,0,0,0,0,0};
  #pragma unroll
  for (int k = 0; k < NCO; k++){
    float v = xb[k*CD + c];
    vals[k] = v;
    ss[deg_of(k)] += v*v;
  }
  __shared__ float red[7][128];
  #pragma unroll
  for (int l = 0; l < 7; l++) red[l][c] = ss[l];
  __syncthreads();
  __shared__ float inv[7];
  if (c < 7){
    float s = 0.f;
    for (int i = 0; i < 128; i++) s += red[c][i];
    float ms = s / ((float)(2*c + 1)*128.f);
    inv[c] = 1.f / sqrtf(ms + 1e-6f);
  }
  __syncthreads();
  size_t base = (size_t)n*NRr*CD;
  #pragma unroll
  for (int kr = 0; kr < NRr; kr++){
    int k = d_RES[kr];
    int l = deg_of(k);
    hr[base + kr*CD + c] = f2bf(vals[k]*inv[l]*w[l*CD + c]);
  }
}

// ---------------- fused attention: logits + segment softmax + alpha ----------------
__global__ __launch_bounds__(256) void k_attn(
    const u16* __restrict__ XST, const float* __restrict__ rad, const float* __restrict__ avec,
    const int* __restrict__ src, const int* __restrict__ rowptr, const int* __restrict__ eid,
    float* __restrict__ AL)
{
  int n = blockIdx.x;
  int p0 = rowptr[n], p1 = rowptr[n+1];
  int deg = p1 - p0;
  if (deg == 0) return;
  __shared__ float lgs[64][8];
  __shared__ float xt0[128];
  __shared__ float av[128];
  __shared__ float mxs[8], dens[8];
  int tid = threadIdx.x;
  if (tid < 128){
    xt0[tid] = bf2f(XST[(size_t)n*NRr*256 + 128 + tid]);
    av[tid] = avec[tid];
  }
  __syncthreads();
  for (int pair = tid; pair < deg*8; pair += 256){
    int pl = pair >> 3, h = pair & 7;
    int e = eid[p0 + pl];
    int s = src[e];
    const u16* xs = &XST[(size_t)s*NRr*256 + h*16];
    uint4 q0 = *(const uint4*)xs;
    uint4 q1 = *(const uint4*)(xs + 8);
    const u16* x0 = (const u16*)&q0;
    const u16* x1 = (const u16*)&q1;
    const float* rd = &rad[(size_t)e*128 + h*16];
    float4 r0 = *(const float4*)(rd + 0);
    float4 r1 = *(const float4*)(rd + 4);
    float4 r2 = *(const float4*)(rd + 8);
    float4 r3 = *(const float4*)(rd + 12);
    float rr[16] = {r0.x,r0.y,r0.z,r0.w, r1.x,r1.y,r1.z,r1.w,
                    r2.x,r2.y,r2.z,r2.w, r3.x,r3.y,r3.z,r3.w};
    float acc = 0.f;
    #pragma unroll
    for (int d = 0; d < 8; d++){
      float m = (bf2f(x0[d]) + xt0[h*16 + d]) * rr[d];
      acc += siluf(m) * av[h*16 + d];
    }
    #pragma unroll
    for (int d = 0; d < 8; d++){
      float m = (bf2f(x1[d]) + xt0[h*16 + 8 + d]) * rr[8 + d];
      acc += siluf(m) * av[h*16 + 8 + d];
    }
    lgs[pl][h] = acc;
  }
  __syncthreads();
  if (tid < 8){
    float m = -1e30f;
    for (int pl = 0; pl < deg; pl++) m = fmaxf(m, lgs[pl][tid]);
    float sden = 0.f;
    for (int pl = 0; pl < deg; pl++) sden += expf(lgs[pl][tid] - m);
    mxs[tid] = m; dens[tid] = sden;
  }
  __syncthreads();
  for (int pair = tid; pair < deg*8; pair += 256){
    int pl = pair >> 3, h = pair & 7;
    int e = eid[p0 + pl];
    AL[e*8 + h] = expf(lgs[pl][h] - mxs[h]) / fmaxf(dens[h], 1e-9f);
  }
}

// ---------------- latent: per-group sum of AG rows (pre-projection) ----------------
// AGP[row][c], row = g*29+kr for g<16 (rows 464..511 zero-padded for the GEMM).
__global__ __launch_bounds__(256) void k_poolpre(const float* __restrict__ AG, const int* __restrict__ gs,
                                                 float* __restrict__ AGP){
  int i = blockIdx.x*blockDim.x + threadIdx.x;   // 512*128
  if (i >= 512*128) return;
  int c = i & 127;
  int row = i >> 7;
  float s = 0.f;
  if (row < NG*NRr){
    int g = row / NRr, kr = row - g*NRr;
    int a = gs[g], b = gs[g+1];
    for (int n = a; n < b; n++) s += AG[((size_t)n*NRr + kr)*128 + c];
  }
  AGP[(size_t)row*128 + c] = s;
}

// ---------------- latent: write pooled output with /cnt and c_rinv scatter ----------------
__global__ void k_outw(const float* __restrict__ OUTP, const int* __restrict__ gs, float* __restrict__ out){
  int i = blockIdx.x*blockDim.x + threadIdx.x;
  if (i >= NG*NCO*CD) return;
  int c = i & 127;
  int k = (i >> 7) % 49;
  int g = i / (49*128);
  int kr = c_rinv[k];
  float v = 0.f;
  if (kr >= 0){
    int cnt = gs[g+1] - gs[g];
    v = OUTP[((size_t)(g*NRr + kr))*128 + c] / (float)(cnt > 0 ? cnt : 1);
  }
  out[i] = v;
}

extern "C" void kernel_launch(void* const* d_in, const int* in_sizes, int n_in,
                              void* d_out, int out_size, void* d_ws, size_t ws_size,
                              hipStream_t stream){
  const float* pos    = (const float*)d_in[0];
  const float* evec   = (const float*)d_in[1];
  const int*   eidx   = (const int*)  d_in[2];
  const int*   batch  = (const int*)  d_in[3];
  const float* table  = (const float*)d_in[4];
  const float* deg_w1 = (const float*)d_in[5];
  const float* deg_b1 = (const float*)d_in[6];
  const float* deg_w2 = (const float*)d_in[7];
  const float* deg_b2 = (const float*)d_in[8];
  const float* deg_w3 = (const float*)d_in[9];
  const float* attn_nw= (const float*)d_in[10];
  const float* w_src  = (const float*)d_in[11];
  const float* w_tgt  = (const float*)d_in[12];
  const float* rad_w1 = (const float*)d_in[13];
  const float* rad_b1 = (const float*)d_in[14];
  const float* rad_w2 = (const float*)d_in[15];
  const float* avec   = (const float*)d_in[16];
  const float* w_val  = (const float*)d_in[17];
  const float* w_proj = (const float*)d_in[18];
  const float* ffn_nw = (const float*)d_in[19];
  const float* ffn_w1 = (const float*)d_in[20];
  const float* ffn_w2 = (const float*)d_in[21];
  const float* fin_nw = (const float*)d_in[22];
  const float* lw_src = (const float*)d_in[23];
  const float* lw_tgt = (const float*)d_in[24];
  const float* lrad_w1= (const float*)d_in[25];
  const float* lrad_b1= (const float*)d_in[26];
  const float* lrad_w2= (const float*)d_in[27];
  const float* lavec  = (const float*)d_in[28];
  const float* lw_val = (const float*)d_in[29];
  const float* lw_proj= (const float*)d_in[30];

  const int* srcp = eidx;
  const int* dstp = eidx + NE;

  // ws budget: 256 MiB = 67.1M f32-slots. Layout below totals ~56.3M (audited).
  float* W = (float*)d_ws;
  size_t o = 0;
  float* X    = W + o; o += (size_t)NN*49*128;   // 12.85M
  float* Hb   = W + o; o += (size_t)NN*49*128;   // 12.85M: RADD, VS chunks, FFN rmsnorm(bf16)
  float* HR   = W + o; o += (size_t)NN*29*128;   // 7.60M: rmsnormR(bf16) out, AG
  float* XSTf = W + o; o += (size_t)NN*29*256/2; // 7.60M: XST bf16 (u16)
  float* Yb   = W + o; o += (size_t)NE*49;       // 0.60M
  float* DV   = W + o; o += (size_t)NE;
  float* AL   = W + o; o += (size_t)NE*8;
  float* SG   = W + o; o += (size_t)NN*512;      // 1.05M
  int* CNT = (int*)(W + o); o += NN;
  int* RP  = (int*)(W + o); o += NN + 1;
  int* EID = (int*)(W + o); o += NE;
  int* GS  = (int*)(W + o); o += NG + 1;
  int* CH  = (int*)(W + o); o += 4*NN;
  float* R1A = W + o; o += (size_t)4*NE*128;     // 6.29M: batched radial layer-1 (3 attn + deg)
  float* R2A = W + o; o += (size_t)4*NE*128;     // 6.29M: batched radial layer-2
  float* AGP = W + o; o += (size_t)512*128;      // pooled AG (padded to 512 rows)
  float* OUTP= W + o; o += (size_t)512*128;      // pooled projection
  // bf16 transposed weights (~0.32M f32-slots)
  u16* WB = (u16*)(W + o);
  size_t wo = 0;
  u16* T_degw2 = WB + wo; wo += 16384;
  u16* T_degw3 = WB + wo; wo += 114688;
  u16* T_wst[3]; u16* T_wv[3]; u16* T_wp[3]; u16* T_rw2[3];
  for (int i = 0; i < 3; i++){ T_wst[i] = WB + wo; wo += 32768; }   // [256][128]
  for (int i = 0; i < 3; i++){ T_wv[i] = WB + wo; wo += 16384; }
  for (int i = 0; i < 3; i++){ T_wp[i] = WB + wo; wo += 16384; }
  for (int i = 0; i < 3; i++){ T_rw2[i] = WB + wo; wo += 16384; }
  u16* T_f1[2]; u16* T_f2[2];
  for (int i = 0; i < 2; i++){ T_f1[i] = WB + wo; wo += 65536; }
  for (int i = 0; i < 2; i++){ T_f2[i] = WB + wo; wo += 65536; }
  (void)ws_size; (void)in_sizes; (void)n_in; (void)out_size;

  u16*  XSTw = (u16*)XSTf;                        // [NN][29][256] bf16
  u16*  HRw  = (u16*)HR;                          // rmsnormR bf16 out
  u16*  Hbw  = (u16*)Hb;                          // FFN rmsnorm bf16 out (first half of Hb)
  float* RADD = Hb;                               // E*896 = 11.0M <= Hb; free before layers
  u16*  VS    = (u16*)Hb;                         // VCH_E*29*128 u16 = 11.4M f32 <= Hb
  float* AG   = HR;

  // ---- all weight casts in one launch ----
  {
    CastJobs J;
    int idx = 0, acc = 0;
    auto add = [&](const float* s, u16* d, int K, int N){
      J.src[idx] = s; J.dst[idx] = d; J.K[idx] = K; J.N[idx] = N; J.start[idx] = acc;
      acc += K*N; idx++;
    };
    add(deg_w2, T_degw2, 128, 128);
    add(deg_w3, T_degw3, 128, 896);
    for (int i = 0; i < 3; i++){
      add((i < 2) ? w_src  + (size_t)i*16384 : lw_src,  T_wst[i],          128, 128);
      add((i < 2) ? w_tgt  + (size_t)i*16384 : lw_tgt,  T_wst[i] + 16384,  128, 128);
      add((i < 2) ? w_val  + (size_t)i*16384 : lw_val,  T_wv[i], 128, 128);
      add((i < 2) ? w_proj + (size_t)i*16384 : lw_proj, T_wp[i], 128, 128);
      add((i < 2) ? rad_w2 + (size_t)i*16384 : lrad_w2, T_rw2[i], 128, 128);
    }
    for (int i = 0; i < 2; i++){
      add(ffn_w1 + (size_t)i*65536, T_f1[i], 128, 512);
      add(ffn_w2 + (size_t)i*65536, T_f2[i], 512, 128);
    }
    J.start[idx] = acc; J.total = acc;
    k_castall<<<(acc + 255)/256, 256, 0, stream>>>(J);
  }

  // CSR + groups
  k_hist4<<<1, 1024, 0, stream>>>(dstp, CNT, CH);
  k_scan2<<<1, 1024, 0, stream>>>(CNT, RP);
  k_fillw4<<<NN, 256, 0, stream>>>(dstp, RP, CH, EID);
  k_gstart<<<1, 32, 0, stream>>>(batch, GS);

  // geometry
  k_geom<<<48, 256, 0, stream>>>(evec, Yb, DV);

  // fused radial layer-1 for all 4 MLPs (3 attn + degree), then batched layer-2
  k_rad14<<<NE, 128, 0, stream>>>(DV,
      rad_w1, rad_w1 + 76800, lrad_w1, deg_w1,
      rad_b1, rad_b1 + 128,   lrad_b1, deg_b1, R1A);
  k_rgemm<<<dim3(1, NE/64, 4), 256, 0, stream>>>(R1A, T_rw2[0], T_rw2[1], T_rw2[2], T_degw2, deg_b2, R2A);

  // degree embedding layer-3 (896-wide) + node init
  k_mgemm<0,0,2><<<dim3(7, NE/64), 256, 0, stream>>>(R2A + (size_t)3*NE*128, T_degw3, nullptr, RADD,
                                                     NE, 896, 128, 128,
                                                     nullptr, nullptr, nullptr, nullptr, nullptr, 0);
  k_init<<<NN, 128, 0, stream>>>(pos, table, Yb, RADD, RP, EID, X);

  for (int i = 0; i < 3; i++){
    const float* nw  = (i < 2) ? attn_nw + (size_t)i*896 : fin_nw;
    const float* av  = (i < 2) ? avec   + (size_t)i*128  : lavec;
    const float* R2L = R2A + (size_t)i*NE*128;

    k_rmsnormR<<<NN, 128, 0, stream>>>(X, nw, HRw);
    // combined XS|XT projection, bf16 output
    k_mgemm<2,6,4><<<dim3(1, NN*NRr/64), 256, 0, stream>>>(HRw, T_wst[i], nullptr, XSTw, NN*NRr, 256, 128, 128,
                                                           nullptr, nullptr, nullptr, nullptr, nullptr, 0);
    // fused logits + softmax + alpha
    k_attn<<<NN, 256, 0, stream>>>(XSTw, R2L, av, srcp, RP, EID, AL);
    // V in CSR-permuted order, alpha-fused epilogue, then contiguous segment-sum
    for (int ch = 0; ch < NE/VCH_E; ch++){
      int p0 = ch*VCH_E;
      k_mgemm<3,7,2><<<dim3(1, VCH_E*NRr/64), 256, 0, stream>>>(R2L, T_wv[i], nullptr, VS,
                                                                VCH_E*NRr, 128, 128, 128,
                                                                (const float*)XSTw, srcp, dstp, EID, AL, p0);
      k_aggseg<<<NN, 256, 0, stream>>>(VS, RP, p0, p0 + VCH_E, ch == 0, AG);
    }
    if (i < 2){
      // projection with fused scatter-accumulate into X
      k_mgemm<0,3,2><<<dim3(1, NN*NRr/64), 256, 0, stream>>>(AG, T_wp[i], nullptr, X, NN*NRr, 128, 128, 128,
                                                             nullptr, nullptr, nullptr, nullptr, nullptr, 0);
      // FFN: gate from row0, hidden kept in LDS (fused GEMM1+gate+GEMM2, 8-wave M=128)
      k_rmsnorm<<<NN, 128, 0, stream>>>(X, ffn_nw + (size_t)i*896, Hbw);
      k_mgemm<2,4,1><<<dim3(8, NN/64), 256, 0, stream>>>(Hbw, T_f1[i], nullptr, SG, NN, 512, 128, NCO*CD,
                                                         nullptr, nullptr, nullptr, nullptr, nullptr, 0);
      k_ffn<<<NN*NCO/128, 512, 0, stream>>>(Hbw, T_f1[i], T_f2[i], SG, X);
    } else {
      // latent: pool AG per group first (linearity), then a tiny wp GEMM, then /cnt + scatter-out
      k_poolpre<<<(512*128)/256, 256, 0, stream>>>(AG, GS, AGP);
      k_mgemm<0,0,2><<<dim3(1, 8), 256, 0, stream>>>(AGP, T_wp[i], nullptr, OUTP, 512, 128, 128, 128,
                                                     nullptr, nullptr, nullptr, nullptr, nullptr, 0);
      k_outw<<<(NG*NCO*CD + 255)/256, 256, 0, stream>>>(OUTP, GS, (float*)d_out);
    }
  }
}

// Round 22
// 832.299 us; speedup vs baseline: 1.2716x; 1.0137x over previous
//
#include <hip/hip_runtime.h>
#include <math.h>

#define NN 2048
#define NE 12288
#define NCO 49
#define NRr 29
#define CD 128
#define NG 16
#define NJOBS 21
#define VCH_E 6144   // edges per V chunk (permuted positions)

typedef unsigned short u16;
typedef short bhalf8 __attribute__((ext_vector_type(8)));
typedef float fvec4 __attribute__((ext_vector_type(4)));

// RESTRICT: indices k (0..48) with |m|<=2.
__constant__ int c_res[29] = {0,1,2,3,4,5,6,7,8,10,11,12,13,14,18,19,20,21,22,28,29,30,31,32,40,41,42,43,44};
__constant__ int c_rinv[49] = {0,1,2,3,4,5,6,7,8,-1,9,10,11,12,13,-1,-1,-1,14,15,16,17,18,-1,-1,-1,-1,-1,19,20,21,22,23,-1,-1,-1,-1,-1,-1,-1,24,25,26,27,28,-1,-1,-1,-1};
__device__ constexpr int d_RES[29] = {0,1,2,3,4,5,6,7,8,10,11,12,13,14,18,19,20,21,22,28,29,30,31,32,40,41,42,43,44};

__device__ __forceinline__ constexpr int deg_of(int k){
  return (k<1)?0:(k<4)?1:(k<9)?2:(k<16)?3:(k<25)?4:(k<36)?5:6;
}
__device__ __forceinline__ float siluf(float x){ return x / (1.f + expf(-x)); }
__device__ __forceinline__ u16 f2bf(float f){
  unsigned int u = __float_as_uint(f);
  unsigned int r = (u + 0x7FFFu + ((u >> 16) & 1u)) >> 16;
  return (u16)r;
}
__device__ __forceinline__ float bf2f(u16 b){
  return __uint_as_float(((unsigned int)b) << 16);
}
__device__ __forceinline__ unsigned int pk(u16 lo, u16 hi){ return (unsigned int)lo | ((unsigned int)hi << 16); }

// ---------------- CSR build (deterministic, parallel) ----------------
__global__ __launch_bounds__(1024) void k_hist4(const int* __restrict__ dst, int* __restrict__ cnt,
                                                int* __restrict__ CH){
  __shared__ int h[4*NN];
  for (int i = threadIdx.x; i < 4*NN; i += 1024) h[i] = 0;
  __syncthreads();
  const int QE = NE/4;
  for (int e = threadIdx.x; e < NE; e += 1024){
    int q = e / QE;
    atomicAdd(&h[q*NN + dst[e]], 1);
  }
  __syncthreads();
  for (int n = threadIdx.x; n < NN; n += 1024){
    int s = 0;
    #pragma unroll
    for (int q = 0; q < 4; q++){ int v = h[q*NN + n]; CH[q*NN + n] = v; s += v; }
    cnt[n] = s;
  }
}
__global__ __launch_bounds__(1024) void k_scan2(const int* __restrict__ cnt, int* __restrict__ rowptr){
  __shared__ int a[NN], b[NN];
  int t = threadIdx.x;
  for (int i = t; i < NN; i += 1024) a[i] = cnt[i];
  __syncthreads();
  int* pin = a; int* pout = b;
  for (int off = 1; off < NN; off <<= 1){
    for (int i = t; i < NN; i += 1024)
      pout[i] = pin[i] + ((i >= off) ? pin[i - off] : 0);
    __syncthreads();
    int* tmp = pin; pin = pout; pout = tmp;
  }
  for (int i = t; i < NN; i += 1024) rowptr[i + 1] = pin[i];
  if (t == 0) rowptr[0] = 0;
}
__global__ __launch_bounds__(256) void k_fillw4(const int* __restrict__ dst, const int* __restrict__ rowptr,
                                                const int* __restrict__ CH, int* __restrict__ eid){
  int q = threadIdx.x >> 6, lane = threadIdx.x & 63;
  int n = blockIdx.x;
  int base = rowptr[n];
  for (int qq = 0; qq < q; qq++) base += CH[qq*NN + n];
  const int QE = NE/4;
  for (int e0 = q*QE; e0 < (q+1)*QE; e0 += 64){
    int e = e0 + lane;
    bool m = (dst[e] == n);
    unsigned long long mask = __ballot(m);
    if (m) eid[base + __popcll(mask & ((1ull << lane) - 1ull))] = e;
    base += __popcll(mask);
  }
}
__global__ void k_gstart(const int* __restrict__ batch, int* __restrict__ gs){
  int g = threadIdx.x;
  if (g > NG) return;
  int lo = 0, hi = NN;
  while (lo < hi){ int mid = (lo + hi) >> 1; if (batch[mid] < g) lo = mid + 1; else hi = mid; }
  gs[g] = lo;
}

// ---------------- all weight casts in one launch: [K][N] f32 -> [N][K] bf16 ----------------
struct CastJobs {
  const float* src[NJOBS];
  u16* dst[NJOBS];
  int K[NJOBS], N[NJOBS];
  int start[NJOBS + 1];
  int total;
};
__global__ void k_castall(CastJobs J){
  int i = blockIdx.x*blockDim.x + threadIdx.x;
  if (i >= J.total) return;
  int j = 0;
  while (i >= J.start[j + 1]) j++;
  int local = i - J.start[j];
  int K = J.K[j], N = J.N[j];
  int n = local / K, k = local - n*K;
  J.dst[j][local] = f2bf(J.src[j][(size_t)k*N + n]);
}

// ---------------- geometry ----------------
__global__ void k_geom(const float* __restrict__ ev, float* __restrict__ Y, float* __restrict__ dv){
  int e = blockIdx.x*blockDim.x + threadIdx.x;
  if (e >= NE) return;
  float x = ev[e*3+0], y = ev[e*3+1], z = ev[e*3+2];
  float r = sqrtf(x*x + y*y + z*z);
  dv[e] = r;
  float rn = fmaxf(r, 1e-8f);
  float ux = x/rn, uy = y/rn, uz = z/rn;
  float ct = fminf(fmaxf(uz, -1.f), 1.f);
  float st = sqrtf(fminf(fmaxf(1.f - ct*ct, 1e-12f), 1.f));
  float phi = atan2f(uy, ux);
  float P[7][7];
  P[0][0] = 1.f;
  #pragma unroll
  for (int m = 1; m <= 6; m++) P[m][m] = -(2.f*m - 1.f)*st*P[m-1][m-1];
  #pragma unroll
  for (int m = 0; m <= 5; m++) P[m+1][m] = (2.f*m + 1.f)*ct*P[m][m];
  #pragma unroll
  for (int m = 0; m <= 6; m++){
    #pragma unroll
    for (int l = m+2; l <= 6; l++)
      P[l][m] = ((2.f*l - 1.f)*ct*P[l-1][m] - (float)(l+m-1)*P[l-2][m]) / (float)(l-m);
  }
  float cmv[7], smv[7];
  #pragma unroll
  for (int m = 0; m <= 6; m++){ cmv[m] = cosf((float)m*phi); smv[m] = sinf((float)m*phi); }
  const double FOURPI = 12.566370614359172;
  int k = 0;
  #pragma unroll
  for (int l = 0; l <= 6; l++){
    #pragma unroll
    for (int mm = -l; mm <= l; mm++){
      int am = mm < 0 ? -mm : mm;
      double ratio = 1.0;
      for (int i = l-am+1; i <= l+am; i++) ratio /= (double)i;
      double nrm = sqrt((2.0*l + 1.0)/FOURPI*ratio);
      float v;
      if (mm == 0)      v = (float)nrm * P[l][0];
      else if (mm > 0)  v = (float)(1.4142135623730951*nrm) * P[l][am] * cmv[am];
      else              v = (float)(1.4142135623730951*nrm) * P[l][am] * smv[am];
      Y[(size_t)e*49 + k] = v; k++;
    }
  }
}

// ------------- fused layer-1 of ALL FOUR radial MLPs (3 attn + degree) -------------
__global__ __launch_bounds__(128) void k_rad14(const float* __restrict__ dv,
    const float* __restrict__ W0, const float* __restrict__ W1,
    const float* __restrict__ W2, const float* __restrict__ W3,
    const float* __restrict__ bp0, const float* __restrict__ bp1,
    const float* __restrict__ bp2, const float* __restrict__ bp3,
    float* __restrict__ out){
  int e = blockIdx.x;
  int j = threadIdx.x;
  float d = dv[e];
  const float STEPF = (float)(5.0/599.0);
  const double step_d = (double)STEPF;
  const float GC = (float)(-0.5/((2.0*step_d)*(2.0*step_d)));
  __shared__ float g[64];
  int bc = (int)rintf(d / STEPF);
  int wb0 = bc - 32;
  if (j < 64){
    int b = wb0 + j;
    float gg = 0.f;
    if (b >= 0 && b < 600){
      float off = (float)((double)b * (5.0/599.0));
      float t = d - off;
      gg = expf(GC*t*t);
    }
    g[j] = gg;
  }
  __syncthreads();
  int lo = (wb0 < 0) ? -wb0 : 0;
  int hi = (wb0 > 536) ? (600 - wb0) : 64;
  float a0 = bp0[j], a1 = bp1[j], a2 = bp2[j], a3 = bp3[j];
  const float* w0 = W0 + (size_t)(wb0 + lo)*CD + j;
  const float* w1 = W1 + (size_t)(wb0 + lo)*CD + j;
  const float* w2 = W2 + (size_t)(wb0 + lo)*CD + j;
  const float* w3 = W3 + (size_t)(wb0 + lo)*CD + j;
  for (int i = lo; i < hi; i++){
    float gg = g[i];
    a0 += gg*(*w0); a1 += gg*(*w1); a2 += gg*(*w2); a3 += gg*(*w3);
    w0 += CD; w1 += CD; w2 += CD; w3 += CD;
  }
  out[((size_t)0*NE + e)*CD + j] = siluf(a0);
  out[((size_t)1*NE + e)*CD + j] = siluf(a1);
  out[((size_t)2*NE + e)*CD + j] = siluf(a2);
  out[((size_t)3*NE + e)*CD + j] = siluf(a3);
}

// ---------------- MFMA bf16 GEMM with NT column-tiles per block ----------------
// AMODE: 0 = f32 A (runtime lda); 2 = bf16 A (runtime lda);
//        3 = permuted fused-message A.
// EPI:   0 store(+bias); 1 silu(+bias); 2 accumulate; 3 scatter-accum into X;
//        4 sigmoid store; 5 gate-mul (P0=SG) then bf16 store; 6 bf16 store;
//        7 alpha-scale (ALp, permuted via eidp) then bf16 store (VS).
template<int AMODE, int EPI, int NT>
__global__ __launch_bounds__(256) void k_mgemm(
    const void* __restrict__ Av, const u16* __restrict__ Bt,
    const float* __restrict__ bias, void* __restrict__ Cv,
    int M, int N, int K, int lda,
    const float* __restrict__ P0,
    const int* __restrict__ src, const int* __restrict__ dstp,
    const int* __restrict__ eidp, const float* __restrict__ ALp, int e0)
{
  __shared__ __align__(16) u16 Asl[64*64];
  __shared__ __align__(16) u16 Bsl[NT][64*64];
  int tid = threadIdx.x;
  int bm = blockIdx.y*64;
  int bn0 = blockIdx.x*NT*64;
  int wid = tid >> 6, lane = tid & 63;
  int wr = wid >> 1, wc = wid & 1;
  int lr = lane & 15, lk = lane >> 4;
  fvec4 acc[NT][2][2] = {};
  for (int k0 = 0; k0 < K; k0 += 64){
    #pragma unroll
    for (int h = 0; h < 2; h++){
      int lin = tid + h*256;          // 0..511: 64 rows x 8 k-groups
      int row = lin >> 3, kg = lin & 7;
      uint4 q;
      if (AMODE == 3){
        int gr = bm + row;
        int el = gr / 29, kq = gr - el*29;
        int p = e0 + el;
        int e = eidp[p];
        int s = src[e], t = dstp[e];
        const u16* xst = (const u16*)P0;
        uint4 xs8 = *(const uint4*)&xst[((size_t)s*29 + kq)*256 + k0 + kg*8];
        uint4 xt8 = *(const uint4*)&xst[((size_t)t*29 + kq)*256 + 128 + k0 + kg*8];
        const float* rd = (const float*)Av + (size_t)e*128 + k0 + kg*8;
        const u16* xsp = (const u16*)&xs8;
        const u16* xtp = (const u16*)&xt8;
        u16 ov[8];
        #pragma unroll
        for (int j = 0; j < 8; j++)
          ov[j] = f2bf((bf2f(xsp[j]) + bf2f(xtp[j])) * rd[j]);
        q.x = pk(ov[0], ov[1]); q.y = pk(ov[2], ov[3]);
        q.z = pk(ov[4], ov[5]); q.w = pk(ov[6], ov[7]);
      } else if (AMODE == 2){
        const u16* ap = (const u16*)Av + (size_t)(bm + row)*lda + k0 + kg*8;
        q = *(const uint4*)ap;
      } else {
        const float* ap = (const float*)Av + (size_t)(bm + row)*lda + k0 + kg*8;
        float v[8];
        #pragma unroll
        for (int j = 0; j < 8; j++) v[j] = ap[j];
        q.x = pk(f2bf(v[0]), f2bf(v[1]));
        q.y = pk(f2bf(v[2]), f2bf(v[3]));
        q.z = pk(f2bf(v[4]), f2bf(v[5]));
        q.w = pk(f2bf(v[6]), f2bf(v[7]));
      }
      *(uint4*)&Asl[row*64 + ((kg*8) ^ ((row & 7)*8))] = q;
    }
    #pragma unroll
    for (int t = 0; t < NT; t++){
      #pragma unroll
      for (int h = 0; h < 2; h++){
        int lin = tid + h*256;
        int row = lin >> 3, kg = lin & 7;
        const u16* bp = Bt + (size_t)(bn0 + t*64 + row)*K + k0 + kg*8;
        *(uint4*)&Bsl[t][row*64 + ((kg*8) ^ ((row & 7)*8))] = *(const uint4*)bp;
      }
    }
    __syncthreads();
    #pragma unroll
    for (int ks = 0; ks < 2; ks++){
      int kg = ks*4 + lk;
      bhalf8 af[2];
      #pragma unroll
      for (int mi = 0; mi < 2; mi++){
        int ar = wr*32 + mi*16 + lr;
        af[mi] = *(const bhalf8*)&Asl[ar*64 + ((kg*8) ^ ((ar & 7)*8))];
      }
      #pragma unroll
      for (int t = 0; t < NT; t++){
        bhalf8 bfr[2];
        #pragma unroll
        for (int ni = 0; ni < 2; ni++){
          int br = wc*32 + ni*16 + lr;
          bfr[ni] = *(const bhalf8*)&Bsl[t][br*64 + ((kg*8) ^ ((br & 7)*8))];
        }
        #pragma unroll
        for (int mi = 0; mi < 2; mi++)
          #pragma unroll
          for (int ni = 0; ni < 2; ni++)
            acc[t][mi][ni] = __builtin_amdgcn_mfma_f32_16x16x32_bf16(af[mi], bfr[ni], acc[t][mi][ni], 0, 0, 0);
      }
    }
    __syncthreads();
  }
  #pragma unroll
  for (int t = 0; t < NT; t++){
    #pragma unroll
    for (int mi = 0; mi < 2; mi++){
      #pragma unroll
      for (int ni = 0; ni < 2; ni++){
        #pragma unroll
        for (int j = 0; j < 4; j++){
          int row = bm + wr*32 + mi*16 + lk*4 + j;
          int col = bn0 + t*64 + wc*32 + ni*16 + lr;
          float v = acc[t][mi][ni][j];
          if (EPI == 0){
            if (bias) v += bias[col];
            ((float*)Cv)[(size_t)row*N + col] = v;
          } else if (EPI == 1){
            if (bias) v += bias[col];
            ((float*)Cv)[(size_t)row*N + col] = siluf(v);
          } else if (EPI == 2){
            ((float*)Cv)[(size_t)row*N + col] += v;
          } else if (EPI == 3){
            int n = row / 29, kr = row - n*29;
            ((float*)Cv)[((size_t)n*49 + c_res[kr])*128 + col] += v;
          } else if (EPI == 4){
            ((float*)Cv)[(size_t)row*N + col] = 1.f/(1.f + expf(-v));
          } else if (EPI == 5){
            float g = P0[(size_t)(row/49)*N + col];
            ((u16*)Cv)[(size_t)row*N + col] = f2bf(v*g);
          } else if (EPI == 6){
            ((u16*)Cv)[(size_t)row*N + col] = f2bf(v);
          } else {
            int p = e0 + row/29;
            int e = eidp[p];
            float a = ALp[e*8 + (col >> 4)];
            ((u16*)Cv)[(size_t)row*N + col] = f2bf(v*a);
          }
        }
      }
    }
  }
}

// ---------------- batched radial layer-2 GEMM (z: 0..2 attn, 3 = degree w/bias+silu) ----------------
__global__ __launch_bounds__(256) void k_rgemm(
    const float* __restrict__ A, const u16* __restrict__ B0, const u16* __restrict__ B1,
    const u16* __restrict__ B2, const u16* __restrict__ B3,
    const float* __restrict__ degb2, float* __restrict__ C)
{
  __shared__ __align__(16) u16 Asl[64*64];
  __shared__ __align__(16) u16 Bsl[2][64*64];
  int tid = threadIdx.x;
  int l = blockIdx.z;
  int bm = blockIdx.y*64;
  const u16* Bt = (l == 0) ? B0 : (l == 1) ? B1 : (l == 2) ? B2 : B3;
  const float* Al = A + (size_t)l*NE*128;
  float* Cl = C + (size_t)l*NE*128;
  int wid = tid >> 6, lane = tid & 63;
  int wr = wid >> 1, wc = wid & 1;
  int lr = lane & 15, lk = lane >> 4;
  fvec4 acc[2][2][2] = {};
  for (int k0 = 0; k0 < 128; k0 += 64){
    #pragma unroll
    for (int h = 0; h < 2; h++){
      int lin = tid + h*256;
      int row = lin >> 3, kg = lin & 7;
      const float* ap = Al + (size_t)(bm + row)*128 + k0 + kg*8;
      float v[8];
      #pragma unroll
      for (int j = 0; j < 8; j++) v[j] = ap[j];
      uint4 q;
      q.x = pk(f2bf(v[0]), f2bf(v[1]));
      q.y = pk(f2bf(v[2]), f2bf(v[3]));
      q.z = pk(f2bf(v[4]), f2bf(v[5]));
      q.w = pk(f2bf(v[6]), f2bf(v[7]));
      *(uint4*)&Asl[row*64 + ((kg*8) ^ ((row & 7)*8))] = q;
    }
    #pragma unroll
    for (int t = 0; t < 2; t++){
      #pragma unroll
      for (int h = 0; h < 2; h++){
        int lin = tid + h*256;
        int row = lin >> 3, kg = lin & 7;
        const u16* bp = Bt + (size_t)(t*64 + row)*128 + k0 + kg*8;
        *(uint4*)&Bsl[t][row*64 + ((kg*8) ^ ((row & 7)*8))] = *(const uint4*)bp;
      }
    }
    __syncthreads();
    #pragma unroll
    for (int ks = 0; ks < 2; ks++){
      int kg = ks*4 + lk;
      bhalf8 af[2];
      #pragma unroll
      for (int mi = 0; mi < 2; mi++){
        int ar = wr*32 + mi*16 + lr;
        af[mi] = *(const bhalf8*)&Asl[ar*64 + ((kg*8) ^ ((ar & 7)*8))];
      }
      #pragma unroll
      for (int t = 0; t < 2; t++){
        bhalf8 bfr[2];
        #pragma unroll
        for (int ni = 0; ni < 2; ni++){
          int br = wc*32 + ni*16 + lr;
          bfr[ni] = *(const bhalf8*)&Bsl[t][br*64 + ((kg*8) ^ ((br & 7)*8))];
        }
        #pragma unroll
        for (int mi = 0; mi < 2; mi++)
          #pragma unroll
          for (int ni = 0; ni < 2; ni++)
            acc[t][mi][ni] = __builtin_amdgcn_mfma_f32_16x16x32_bf16(af[mi], bfr[ni], acc[t][mi][ni], 0, 0, 0);
      }
    }
    __syncthreads();
  }
  #pragma unroll
  for (int t = 0; t < 2; t++)
    #pragma unroll
    for (int mi = 0; mi < 2; mi++)
      #pragma unroll
      for (int ni = 0; ni < 2; ni++)
        #pragma unroll
        for (int j = 0; j < 4; j++){
          int row = bm + wr*32 + mi*16 + lk*4 + j;
          int col = t*64 + wc*32 + ni*16 + lr;
          float v = acc[t][mi][ni][j];
          if (l == 3){ v += degb2[col]; v = siluf(v); }
          Cl[(size_t)row*128 + col] = v;
        }
}

// ---------------- fused FFN, 16-wave M=256: X += ((bf16(A@W1)*gate)@W2) ----------------
// 128 KB LDS, 1024 threads -> 1 block/CU = 16 waves/CU; 2x work per barrier vs M=128.
// Bit-identical per-element math (same MFMA K-sequence, same f2bf(v*g) rounding).
__global__ __launch_bounds__(1024) void k_ffn(
    const u16* __restrict__ A, const u16* __restrict__ W1, const u16* __restrict__ W2,
    const float* __restrict__ SGp, float* __restrict__ Xp)
{
  __shared__ __align__(16) u16 Asl[256*128];  // 64 KB
  __shared__ __align__(16) u16 W1s[64*128];   // 16 KB
  __shared__ __align__(16) u16 W2s[128*64];   // 16 KB
  __shared__ __align__(16) u16 Hs[256*64];    // 32 KB
  int tid = threadIdx.x;
  int bm = blockIdx.x*256;
  int wid = tid >> 6, lane = tid & 63;
  int wr = wid >> 1, wc = wid & 1;           // wr 0..7 (rows), wc 0..1 (cols)
  int lr = lane & 15, lk = lane >> 4;
  for (int g = tid; g < 4096; g += 1024){
    int row = g >> 4, kg = g & 15;
    *(uint4*)&Asl[row*128 + ((kg*8) ^ ((row & 7)*16))] = *(const uint4*)&A[(size_t)(bm + row)*128 + kg*8];
  }
  fvec4 o[2][4] = {};
  for (int h0 = 0; h0 < 512; h0 += 64){
    for (int g = tid; g < 1024; g += 1024){
      int row = g >> 4, kg = g & 15;
      *(uint4*)&W1s[row*128 + ((kg*8) ^ ((row & 7)*16))] = *(const uint4*)&W1[(size_t)(h0 + row)*128 + kg*8];
    }
    {
      int g = tid;
      int row = g >> 3, kg = g & 7;
      *(uint4*)&W2s[row*64 + ((kg*8) ^ ((row & 7)*8))] = *(const uint4*)&W2[(size_t)row*512 + h0 + kg*8];
    }
    __syncthreads();
    // GEMM1: per wave 32 rows x 32 hidden cols, K=128
    fvec4 hid[2][2] = {};
    #pragma unroll
    for (int kk = 0; kk < 4; kk++){
      int kg = kk*4 + lk;
      bhalf8 af[2], bf[2];
      #pragma unroll
      for (int mi = 0; mi < 2; mi++){
        int ar = wr*32 + mi*16 + lr;
        af[mi] = *(const bhalf8*)&Asl[ar*128 + ((kg*8) ^ ((ar & 7)*16))];
      }
      #pragma unroll
      for (int ni = 0; ni < 2; ni++){
        int br = wc*32 + ni*16 + lr;
        bf[ni] = *(const bhalf8*)&W1s[br*128 + ((kg*8) ^ ((br & 7)*16))];
      }
      #pragma unroll
      for (int mi = 0; mi < 2; mi++)
        #pragma unroll
        for (int ni = 0; ni < 2; ni++)
          hid[mi][ni] = __builtin_amdgcn_mfma_f32_16x16x32_bf16(af[mi], bf[ni], hid[mi][ni], 0, 0, 0);
    }
    // gate + bf16 round -> Hs
    #pragma unroll
    for (int mi = 0; mi < 2; mi++){
      #pragma unroll
      for (int j = 0; j < 4; j++){
        int row = wr*32 + mi*16 + lk*4 + j;
        int node = (bm + row)/49;
        const float* sgrow = &SGp[(size_t)node*512 + h0];
        #pragma unroll
        for (int ni = 0; ni < 2; ni++){
          int col = wc*32 + ni*16 + lr;
          Hs[row*64 + (col ^ ((row & 7)*8))] = f2bf(hid[mi][ni][j]*sgrow[col]);
        }
      }
    }
    __syncthreads();
    // GEMM2: per wave 32 rows x 64 out cols, K=64 this chunk
    #pragma unroll
    for (int kk2 = 0; kk2 < 2; kk2++){
      int kg = kk2*4 + lk;
      bhalf8 af2[2], bf2[4];
      #pragma unroll
      for (int mi = 0; mi < 2; mi++){
        int ar = wr*32 + mi*16 + lr;
        af2[mi] = *(const bhalf8*)&Hs[ar*64 + ((kg*8) ^ ((ar & 7)*8))];
      }
      #pragma unroll
      for (int ni = 0; ni < 4; ni++){
        int br = wc*64 + ni*16 + lr;
        bf2[ni] = *(const bhalf8*)&W2s[br*64 + ((kg*8) ^ ((br & 7)*8))];
      }
      #pragma unroll
      for (int mi = 0; mi < 2; mi++)
        #pragma unroll
        for (int ni = 0; ni < 4; ni++)
          o[mi][ni] = __builtin_amdgcn_mfma_f32_16x16x32_bf16(af2[mi], bf2[ni], o[mi][ni], 0, 0, 0);
    }
    __syncthreads();
  }
  #pragma unroll
  for (int mi = 0; mi < 2; mi++)
    #pragma unroll
    for (int ni = 0; ni < 4; ni++)
      #pragma unroll
      for (int j = 0; j < 4; j++){
        int row = bm + wr*32 + mi*16 + lk*4 + j;
        int col = wc*64 + ni*16 + lr;
        Xp[(size_t)row*128 + col] += o[mi][ni][j];
      }
}

// ---------------- contiguous segment-sum of permuted VS rows (vectorized) ----------------
__global__ __launch_bounds__(256) void k_aggseg(const u16* __restrict__ VS, const int* __restrict__ rowptr,
                                                int p0, int p1, int first, float* __restrict__ agg){
  int n = blockIdx.x;
  int a = rowptr[n], b = rowptr[n+1];
  if (a < p0) a = p0;
  if (b > p1) b = p1;
  int tid = threadIdx.x;
  for (int g = tid; g < 464; g += 256){          // 29*128/8 = 464 groups of 8
    size_t obase = (size_t)n*29*128 + (size_t)g*8;
    float s[8];
    if (first){
      #pragma unroll
      for (int j = 0; j < 8; j++) s[j] = 0.f;
    } else {
      float4 lo = *(const float4*)&agg[obase];
      float4 hi = *(const float4*)&agg[obase + 4];
      s[0]=lo.x; s[1]=lo.y; s[2]=lo.z; s[3]=lo.w;
      s[4]=hi.x; s[5]=hi.y; s[6]=hi.z; s[7]=hi.w;
    }
    for (int p = a; p < b; p++){
      uint4 q = *(const uint4*)&VS[(size_t)(p - p0)*3712 + (size_t)g*8];
      const u16* qp = (const u16*)&q;
      #pragma unroll
      for (int j = 0; j < 8; j++) s[j] += bf2f(qp[j]);
    }
    float4 lo, hi;
    lo.x=s[0]; lo.y=s[1]; lo.z=s[2]; lo.w=s[3];
    hi.x=s[4]; hi.y=s[5]; hi.z=s[6]; hi.w=s[7];
    *(float4*)&agg[obase] = lo;
    *(float4*)&agg[obase + 4] = hi;
  }
}

// ---------------- node init ----------------
__global__ __launch_bounds__(128) void k_init(const float* __restrict__ pos, const float* __restrict__ table,
                                              const float* __restrict__ Yb, const float* __restrict__ radd,
                                              const int* __restrict__ rowptr, const int* __restrict__ eid,
                                              float* __restrict__ x){
  int n = blockIdx.x;
  int c = threadIdx.x;
  const float DLO = -3.26267f;
  const float DRG = (float)(3.295396 - (-3.26267));
  float p0 = pos[n*3+0], p1 = pos[n*3+1], p2 = pos[n*3+2];
  int t0 = min(127, max(0, (int)rintf((p0 - DLO)/DRG*128.f - 0.5f)));
  int t1 = min(127, max(0, (int)rintf((p1 - DLO)/DRG*128.f - 0.5f)));
  int t2 = min(127, max(0, (int)rintf((p2 - DLO)/DRG*128.f - 0.5f)));
  float emb = table[t0*CD + c] + table[t1*CD + c] + table[t2*CD + c];
  __shared__ float Yl[49];
  __shared__ float rl[896];
  float acc[NCO];
  #pragma unroll
  for (int k = 0; k < NCO; k++) acc[k] = 0.f;
  int pA = rowptr[n], pB = rowptr[n+1];
  for (int p = pA; p < pB; p++){
    int e = eid[p];
    if (c < 49) Yl[c] = Yb[(size_t)e*49 + c];
    #pragma unroll
    for (int q = 0; q < 7; q++) rl[q*128 + c] = radd[(size_t)e*896 + q*128 + c];
    __syncthreads();
    #pragma unroll
    for (int k = 0; k < NCO; k++){
      acc[k] += Yl[k]*rl[deg_of(k)*128 + c];
    }
    __syncthreads();
  }
  size_t base = (size_t)n*NCO*CD;
  x[base + c] = emb + acc[0]*(1.f/3.f);
  #pragma unroll
  for (int k = 1; k < NCO; k++) x[base + k*CD + c] = acc[k]*(1.f/3.f);
}

// ---------------- degree-grouped RMS norm, bf16 out (full 49 rows, for FFN) ----------------
__global__ __launch_bounds__(128) void k_rmsnorm(const float* __restrict__ x, const float* __restrict__ w,
                                                 u16* __restrict__ out){
  int n = blockIdx.x;
  int c = threadIdx.x;
  const float* xb = x + (size_t)n*NCO*CD;
  float vals[NCO];
  float ss[7] = {0,0,0,0,0,0,0};
  #pragma unroll
  for (int k = 0; k < NCO; k++){
    float v = xb[k*CD + c];
    vals[k] = v;
    ss[deg_of(k)] += v*v;
  }
  __shared__ float red[7][128];
  #pragma unroll
  for (int l = 0; l < 7; l++) red[l][c] = ss[l];
  __syncthreads();
  __shared__ float inv[7];
  if (c < 7){
    float s = 0.f;
    for (int i = 0; i < 128; i++) s += red[c][i];
    float ms = s / ((float)(2*c + 1)*128.f);
    inv[c] = 1.f / sqrtf(ms + 1e-6f);
  }
  __syncthreads();
  size_t base = (size_t)n*NCO*CD;
  #pragma unroll
  for (int k = 0; k < NCO; k++){
    int l = deg_of(k);
    out[base + k*CD + c] = f2bf(vals[k]*inv[l]*w[l*CD + c]);
  }
}

// ---------------- RMS norm writing restricted 29 rows, bf16 out ----------------
__global__ __launch_bounds__(128) void k_rmsnormR(const float* __restrict__ x, const float* __restrict__ w,
                                                  u16* __restrict__ hr){
  int n = blockIdx.x;
  int c = threadIdx.x;
  const float* xb = x + (size_t)n*NCO*CD;
  float vals[NCO];
  float ss[7] = {0,0,0,0,0,0,0};
  #pragma unroll
  for (int k = 0; k < NCO; k++){
    float v = xb[k*CD + c];
    vals[k] = v;
    ss[deg_of(k)] += v*v;
  }
  __shared__ float red[7][128];
  #pragma unroll
  for (int l = 0; l < 7; l++) red[l][c] = ss[l];
  __syncthreads();
  __shared__ float inv[7];
  if (c < 7){
    float s = 0.f;
    for (int i = 0; i < 128; i++) s += red[c][i];
    float ms = s / ((float)(2*c + 1)*128.f);
    inv[c] = 1.f / sqrtf(ms + 1e-6f);
  }
  __syncthreads();
  size_t base = (size_t)n*NRr*CD;
  #pragma unroll
  for (int kr = 0; kr < NRr; kr++){
    int k = d_RES[kr];
    int l = deg_of(k);
    hr[base + kr*CD + c] = f2bf(vals[k]*inv[l]*w[l*CD + c]);
  }
}

// ---------------- fused attention: logits + segment softmax + alpha ----------------
__global__ __launch_bounds__(256) void k_attn(
    const u16* __restrict__ XST, const float* __restrict__ rad, const float* __restrict__ avec,
    const int* __restrict__ src, const int* __restrict__ rowptr, const int* __restrict__ eid,
    float* __restrict__ AL)
{
  int n = blockIdx.x;
  int p0 = rowptr[n], p1 = rowptr[n+1];
  int deg = p1 - p0;
  if (deg == 0) return;
  __shared__ float lgs[64][8];
  __shared__ float xt0[128];
  __shared__ float av[128];
  __shared__ float mxs[8], dens[8];
  int tid = threadIdx.x;
  if (tid < 128){
    xt0[tid] = bf2f(XST[(size_t)n*NRr*256 + 128 + tid]);
    av[tid] = avec[tid];
  }
  __syncthreads();
  for (int pair = tid; pair < deg*8; pair += 256){
    int pl = pair >> 3, h = pair & 7;
    int e = eid[p0 + pl];
    int s = src[e];
    const u16* xs = &XST[(size_t)s*NRr*256 + h*16];
    uint4 q0 = *(const uint4*)xs;
    uint4 q1 = *(const uint4*)(xs + 8);
    const u16* x0 = (const u16*)&q0;
    const u16* x1 = (const u16*)&q1;
    const float* rd = &rad[(size_t)e*128 + h*16];
    float4 r0 = *(const float4*)(rd + 0);
    float4 r1 = *(const float4*)(rd + 4);
    float4 r2 = *(const float4*)(rd + 8);
    float4 r3 = *(const float4*)(rd + 12);
    float rr[16] = {r0.x,r0.y,r0.z,r0.w, r1.x,r1.y,r1.z,r1.w,
                    r2.x,r2.y,r2.z,r2.w, r3.x,r3.y,r3.z,r3.w};
    float acc = 0.f;
    #pragma unroll
    for (int d = 0; d < 8; d++){
      float m = (bf2f(x0[d]) + xt0[h*16 + d]) * rr[d];
      acc += siluf(m) * av[h*16 + d];
    }
    #pragma unroll
    for (int d = 0; d < 8; d++){
      float m = (bf2f(x1[d]) + xt0[h*16 + 8 + d]) * rr[8 + d];
      acc += siluf(m) * av[h*16 + 8 + d];
    }
    lgs[pl][h] = acc;
  }
  __syncthreads();
  if (tid < 8){
    float m = -1e30f;
    for (int pl = 0; pl < deg; pl++) m = fmaxf(m, lgs[pl][tid]);
    float sden = 0.f;
    for (int pl = 0; pl < deg; pl++) sden += expf(lgs[pl][tid] - m);
    mxs[tid] = m; dens[tid] = sden;
  }
  __syncthreads();
  for (int pair = tid; pair < deg*8; pair += 256){
    int pl = pair >> 3, h = pair & 7;
    int e = eid[p0 + pl];
    AL[e*8 + h] = expf(lgs[pl][h] - mxs[h]) / fmaxf(dens[h], 1e-9f);
  }
}

// ---------------- latent: per-group sum of AG rows (pre-projection) ----------------
__global__ __launch_bounds__(256) void k_poolpre(const float* __restrict__ AG, const int* __restrict__ gs,
                                                 float* __restrict__ AGP){
  int i = blockIdx.x*blockDim.x + threadIdx.x;   // 512*128
  if (i >= 512*128) return;
  int c = i & 127;
  int row = i >> 7;
  float s = 0.f;
  if (row < NG*NRr){
    int g = row / NRr, kr = row - g*NRr;
    int a = gs[g], b = gs[g+1];
    for (int n = a; n < b; n++) s += AG[((size_t)n*NRr + kr)*128 + c];
  }
  AGP[(size_t)row*128 + c] = s;
}

// ---------------- latent: write pooled output with /cnt and c_rinv scatter ----------------
__global__ void k_outw(const float* __restrict__ OUTP, const int* __restrict__ gs, float* __restrict__ out){
  int i = blockIdx.x*blockDim.x + threadIdx.x;
  if (i >= NG*NCO*CD) return;
  int c = i & 127;
  int k = (i >> 7) % 49;
  int g = i / (49*128);
  int kr = c_rinv[k];
  float v = 0.f;
  if (kr >= 0){
    int cnt = gs[g+1] - gs[g];
    v = OUTP[((size_t)(g*NRr + kr))*128 + c] / (float)(cnt > 0 ? cnt : 1);
  }
  out[i] = v;
}

extern "C" void kernel_launch(void* const* d_in, const int* in_sizes, int n_in,
                              void* d_out, int out_size, void* d_ws, size_t ws_size,
                              hipStream_t stream){
  const float* pos    = (const float*)d_in[0];
  const float* evec   = (const float*)d_in[1];
  const int*   eidx   = (const int*)  d_in[2];
  const int*   batch  = (const int*)  d_in[3];
  const float* table  = (const float*)d_in[4];
  const float* deg_w1 = (const float*)d_in[5];
  const float* deg_b1 = (const float*)d_in[6];
  const float* deg_w2 = (const float*)d_in[7];
  const float* deg_b2 = (const float*)d_in[8];
  const float* deg_w3 = (const float*)d_in[9];
  const float* attn_nw= (const float*)d_in[10];
  const float* w_src  = (const float*)d_in[11];
  const float* w_tgt  = (const float*)d_in[12];
  const float* rad_w1 = (const float*)d_in[13];
  const float* rad_b1 = (const float*)d_in[14];
  const float* rad_w2 = (const float*)d_in[15];
  const float* avec   = (const float*)d_in[16];
  const float* w_val  = (const float*)d_in[17];
  const float* w_proj = (const float*)d_in[18];
  const float* ffn_nw = (const float*)d_in[19];
  const float* ffn_w1 = (const float*)d_in[20];
  const float* ffn_w2 = (const float*)d_in[21];
  const float* fin_nw = (const float*)d_in[22];
  const float* lw_src = (const float*)d_in[23];
  const float* lw_tgt = (const float*)d_in[24];
  const float* lrad_w1= (const float*)d_in[25];
  const float* lrad_b1= (const float*)d_in[26];
  const float* lrad_w2= (const float*)d_in[27];
  const float* lavec  = (const float*)d_in[28];
  const float* lw_val = (const float*)d_in[29];
  const float* lw_proj= (const float*)d_in[30];

  const int* srcp = eidx;
  const int* dstp = eidx + NE;

  // ws budget: 256 MiB = 67.1M f32-slots. Layout below totals ~56.3M (audited).
  float* W = (float*)d_ws;
  size_t o = 0;
  float* X    = W + o; o += (size_t)NN*49*128;   // 12.85M
  float* Hb   = W + o; o += (size_t)NN*49*128;   // 12.85M: RADD, VS chunks, FFN rmsnorm(bf16)
  float* HR   = W + o; o += (size_t)NN*29*128;   // 7.60M: rmsnormR(bf16) out, AG
  float* XSTf = W + o; o += (size_t)NN*29*256/2; // 7.60M: XST bf16 (u16)
  float* Yb   = W + o; o += (size_t)NE*49;       // 0.60M
  float* DV   = W + o; o += (size_t)NE;
  float* AL   = W + o; o += (size_t)NE*8;
  float* SG   = W + o; o += (size_t)NN*512;      // 1.05M
  int* CNT = (int*)(W + o); o += NN;
  int* RP  = (int*)(W + o); o += NN + 1;
  int* EID = (int*)(W + o); o += NE;
  int* GS  = (int*)(W + o); o += NG + 1;
  int* CH  = (int*)(W + o); o += 4*NN;
  float* R1A = W + o; o += (size_t)4*NE*128;     // 6.29M: batched radial layer-1 (3 attn + deg)
  float* R2A = W + o; o += (size_t)4*NE*128;     // 6.29M: batched radial layer-2
  float* AGP = W + o; o += (size_t)512*128;      // pooled AG (padded to 512 rows)
  float* OUTP= W + o; o += (size_t)512*128;      // pooled projection
  // bf16 transposed weights (~0.32M f32-slots)
  u16* WB = (u16*)(W + o);
  size_t wo = 0;
  u16* T_degw2 = WB + wo; wo += 16384;
  u16* T_degw3 = WB + wo; wo += 114688;
  u16* T_wst[3]; u16* T_wv[3]; u16* T_wp[3]; u16* T_rw2[3];
  for (int i = 0; i < 3; i++){ T_wst[i] = WB + wo; wo += 32768; }   // [256][128]
  for (int i = 0; i < 3; i++){ T_wv[i] = WB + wo; wo += 16384; }
  for (int i = 0; i < 3; i++){ T_wp[i] = WB + wo; wo += 16384; }
  for (int i = 0; i < 3; i++){ T_rw2[i] = WB + wo; wo += 16384; }
  u16* T_f1[2]; u16* T_f2[2];
  for (int i = 0; i < 2; i++){ T_f1[i] = WB + wo; wo += 65536; }
  for (int i = 0; i < 2; i++){ T_f2[i] = WB + wo; wo += 65536; }
  (void)ws_size; (void)in_sizes; (void)n_in; (void)out_size;

  u16*  XSTw = (u16*)XSTf;                        // [NN][29][256] bf16
  u16*  HRw  = (u16*)HR;                          // rmsnormR bf16 out
  u16*  Hbw  = (u16*)Hb;                          // FFN rmsnorm bf16 out (first half of Hb)
  float* RADD = Hb;                               // E*896 = 11.0M <= Hb; free before layers
  u16*  VS    = (u16*)Hb;                         // VCH_E*29*128 u16 = 11.4M f32 <= Hb
  float* AG   = HR;

  // ---- all weight casts in one launch ----
  {
    CastJobs J;
    int idx = 0, acc = 0;
    auto add = [&](const float* s, u16* d, int K, int N){
      J.src[idx] = s; J.dst[idx] = d; J.K[idx] = K; J.N[idx] = N; J.start[idx] = acc;
      acc += K*N; idx++;
    };
    add(deg_w2, T_degw2, 128, 128);
    add(deg_w3, T_degw3, 128, 896);
    for (int i = 0; i < 3; i++){
      add((i < 2) ? w_src  + (size_t)i*16384 : lw_src,  T_wst[i],          128, 128);
      add((i < 2) ? w_tgt  + (size_t)i*16384 : lw_tgt,  T_wst[i] + 16384,  128, 128);
      add((i < 2) ? w_val  + (size_t)i*16384 : lw_val,  T_wv[i], 128, 128);
      add((i < 2) ? w_proj + (size_t)i*16384 : lw_proj, T_wp[i], 128, 128);
      add((i < 2) ? rad_w2 + (size_t)i*16384 : lrad_w2, T_rw2[i], 128, 128);
    }
    for (int i = 0; i < 2; i++){
      add(ffn_w1 + (size_t)i*65536, T_f1[i], 128, 512);
      add(ffn_w2 + (size_t)i*65536, T_f2[i], 512, 128);
    }
    J.start[idx] = acc; J.total = acc;
    k_castall<<<(acc + 255)/256, 256, 0, stream>>>(J);
  }

  // CSR + groups
  k_hist4<<<1, 1024, 0, stream>>>(dstp, CNT, CH);
  k_scan2<<<1, 1024, 0, stream>>>(CNT, RP);
  k_fillw4<<<NN, 256, 0, stream>>>(dstp, RP, CH, EID);
  k_gstart<<<1, 32, 0, stream>>>(batch, GS);

  // geometry
  k_geom<<<48, 256, 0, stream>>>(evec, Yb, DV);

  // fused radial layer-1 for all 4 MLPs (3 attn + degree), then batched layer-2
  k_rad14<<<NE, 128, 0, stream>>>(DV,
      rad_w1, rad_w1 + 76800, lrad_w1, deg_w1,
      rad_b1, rad_b1 + 128,   lrad_b1, deg_b1, R1A);
  k_rgemm<<<dim3(1, NE/64, 4), 256, 0, stream>>>(R1A, T_rw2[0], T_rw2[1], T_rw2[2], T_degw2, deg_b2, R2A);

  // degree embedding layer-3 (896-wide) + node init
  k_mgemm<0,0,2><<<dim3(7, NE/64), 256, 0, stream>>>(R2A + (size_t)3*NE*128, T_degw3, nullptr, RADD,
                                                     NE, 896, 128, 128,
                                                     nullptr, nullptr, nullptr, nullptr, nullptr, 0);
  k_init<<<NN, 128, 0, stream>>>(pos, table, Yb, RADD, RP, EID, X);

  for (int i = 0; i < 3; i++){
    const float* nw  = (i < 2) ? attn_nw + (size_t)i*896 : fin_nw;
    const float* av  = (i < 2) ? avec   + (size_t)i*128  : lavec;
    const float* R2L = R2A + (size_t)i*NE*128;

    k_rmsnormR<<<NN, 128, 0, stream>>>(X, nw, HRw);
    // combined XS|XT projection, bf16 output
    k_mgemm<2,6,4><<<dim3(1, NN*NRr/64), 256, 0, stream>>>(HRw, T_wst[i], nullptr, XSTw, NN*NRr, 256, 128, 128,
                                                           nullptr, nullptr, nullptr, nullptr, nullptr, 0);
    // fused logits + softmax + alpha
    k_attn<<<NN, 256, 0, stream>>>(XSTw, R2L, av, srcp, RP, EID, AL);
    // V in CSR-permuted order, alpha-fused epilogue, then contiguous segment-sum
    for (int ch = 0; ch < NE/VCH_E; ch++){
      int p0 = ch*VCH_E;
      k_mgemm<3,7,2><<<dim3(1, VCH_E*NRr/64), 256, 0, stream>>>(R2L, T_wv[i], nullptr, VS,
                                                                VCH_E*NRr, 128, 128, 128,
                                                                (const float*)XSTw, srcp, dstp, EID, AL, p0);
      k_aggseg<<<NN, 256, 0, stream>>>(VS, RP, p0, p0 + VCH_E, ch == 0, AG);
    }
    if (i < 2){
      // projection with fused scatter-accumulate into X
      k_mgemm<0,3,2><<<dim3(1, NN*NRr/64), 256, 0, stream>>>(AG, T_wp[i], nullptr, X, NN*NRr, 128, 128, 128,
                                                             nullptr, nullptr, nullptr, nullptr, nullptr, 0);
      // FFN: gate from row0, hidden kept in LDS (fused GEMM1+gate+GEMM2, 16-wave M=256)
      k_rmsnorm<<<NN, 128, 0, stream>>>(X, ffn_nw + (size_t)i*896, Hbw);
      k_mgemm<2,4,1><<<dim3(8, NN/64), 256, 0, stream>>>(Hbw, T_f1[i], nullptr, SG, NN, 512, 128, NCO*CD,
                                                         nullptr, nullptr, nullptr, nullptr, nullptr, 0);
      k_ffn<<<NN*NCO/256, 1024, 0, stream>>>(Hbw, T_f1[i], T_f2[i], SG, X);
    } else {
      // latent: pool AG per group first (linearity), then a tiny wp GEMM, then /cnt + scatter-out
      k_poolpre<<<(512*128)/256, 256, 0, stream>>>(AG, GS, AGP);
      k_mgemm<0,0,2><<<dim3(1, 8), 256, 0, stream>>>(AGP, T_wp[i], nullptr, OUTP, 512, 128, 128, 128,
                                                     nullptr, nullptr, nullptr, nullptr, nullptr, 0);
      k_outw<<<(NG*NCO*CD + 255)/256, 256, 0, stream>>>(OUTP, GS, (float*)d_out);
    }
  }
}